// Round 1
// baseline (3698.411 us; speedup 1.0000x reference)
//
#include <hip/hip_runtime.h>
#include <math.h>

// Problem constants
#define BB   128
#define NN   128
#define LL   248
#define DD   768
#define HH   8
#define HDh  96
#define HIDN 256
#define MROWS (BB*NN)   // 16384

// ---------------------------------------------------------------------------
// Block reductions (deterministic order)
// ---------------------------------------------------------------------------
template<int NT>
__device__ __forceinline__ float breduce_sum(float v, float* red) {
    const int tid = threadIdx.x;
    red[tid] = v; __syncthreads();
#pragma unroll
    for (int o = NT / 2; o > 0; o >>= 1) {
        if (tid < o) red[tid] += red[tid + o];
        __syncthreads();
    }
    float r = red[0]; __syncthreads();
    return r;
}

template<int NT>
__device__ __forceinline__ float breduce_max(float v, float* red) {
    const int tid = threadIdx.x;
    red[tid] = v; __syncthreads();
#pragma unroll
    for (int o = NT / 2; o > 0; o >>= 1) {
        if (tid < o) red[tid] = fmaxf(red[tid], red[tid + o]);
        __syncthreads();
    }
    float r = red[0]; __syncthreads();
    return r;
}

__device__ __forceinline__ double breduce_sum_d256(double v, double* red) {
    const int tid = threadIdx.x;
    red[tid] = v; __syncthreads();
#pragma unroll
    for (int o = 128; o > 0; o >>= 1) {
        if (tid < o) red[tid] += red[tid + o];
        __syncthreads();
    }
    double r = red[0]; __syncthreads();
    return r;
}

// ---------------------------------------------------------------------------
// Generic tiled fp32 GEMM:  C[M x N] = op(A)[M x K] @ W[K x N] + bias
// AMODE: 0 = plain A (lda), 1 = A row * valid_flag, 2 = fused ctx gather
// MASK_OUT: multiply whole output row (incl. bias) by valid flag
// Tiles: 64x64x16, 256 threads, 4x4 micro-tile per thread.
// All dims assumed multiples of tile sizes (true for this problem).
// ---------------------------------------------------------------------------
template<int AMODE, bool MASK_OUT>
__global__ __launch_bounds__(256)
void gemm_kernel(const float* __restrict__ A, int lda,
                 const float* __restrict__ W, int ldw,
                 const float* __restrict__ bias,
                 float* __restrict__ C, int ldc,
                 int K,
                 const float* __restrict__ text,
                 const int* __restrict__ wpos) {
    __shared__ float As[16][68];
    __shared__ float Bs[16][64];

    const int tid  = threadIdx.x;
    const int tx   = tid & 15;        // 0..15  (cols)
    const int ty   = tid >> 4;        // 0..15  (rows)
    const int arow = tid >> 2;        // 0..63
    const int acol = (tid & 3) << 2;  // 0,4,8,12
    const int brow = tid >> 4;        // 0..15
    const int bcol = (tid & 15) << 2; // 0..60

    const int gm0 = blockIdx.y * 64;
    const int gn0 = blockIdx.x * 64;
    const int gr  = gm0 + arow;       // A row this thread loads

    float vf = 1.f;
    int   bidx = 0, wpc = 0;
    if (AMODE == 1) {
        vf = (wpos[gr] != -1) ? 1.f : 0.f;
    } else if (AMODE == 2) {
        bidx = gr >> 7;
        int wr = wpos[gr];
        wpc = wr < 0 ? 0 : (wr > LL - 1 ? LL - 1 : wr);
    }

    float acc[4][4] = {};

    const int nk = K >> 4;
    for (int kt = 0; kt < nk; ++kt) {
        const int k0 = kt << 4;
        float4 av;
        if (AMODE == 2) {
            int k = k0 + acol;
            int w = k / DD;                 // window slot 0..2 (constant over 4 elems)
            int d = k - w * DD;
            int pos = wpc + w - 1;
            pos = pos < 0 ? 0 : (pos > LL - 1 ? LL - 1 : pos);
            av = *(const float4*)(text + ((size_t)bidx * LL + pos) * DD + d);
        } else {
            av = *(const float4*)(A + (size_t)gr * lda + k0 + acol);
            if (AMODE == 1) { av.x *= vf; av.y *= vf; av.z *= vf; av.w *= vf; }
        }
        float4 bv = *(const float4*)(W + (size_t)(k0 + brow) * ldw + gn0 + bcol);

        __syncthreads();
        As[acol + 0][arow] = av.x;
        As[acol + 1][arow] = av.y;
        As[acol + 2][arow] = av.z;
        As[acol + 3][arow] = av.w;
        *(float4*)&Bs[brow][bcol] = bv;
        __syncthreads();

#pragma unroll
        for (int k = 0; k < 16; ++k) {
            float a_[4], b_[4];
#pragma unroll
            for (int i = 0; i < 4; ++i) a_[i] = As[k][ty * 4 + i];
#pragma unroll
            for (int j = 0; j < 4; ++j) b_[j] = Bs[k][tx * 4 + j];
#pragma unroll
            for (int i = 0; i < 4; ++i)
#pragma unroll
                for (int j = 0; j < 4; ++j)
                    acc[i][j] = fmaf(a_[i], b_[j], acc[i][j]);
        }
    }

    const float4 b4 = *(const float4*)(bias + gn0 + tx * 4);
#pragma unroll
    for (int i = 0; i < 4; ++i) {
        int gm = gm0 + ty * 4 + i;
        float mrow = 1.f;
        if (MASK_OUT) mrow = (wpos[gm] != -1) ? 1.f : 0.f;
        float4 o;
        o.x = (acc[i][0] + b4.x) * mrow;
        o.y = (acc[i][1] + b4.y) * mrow;
        o.z = (acc[i][2] + b4.z) * mrow;
        o.w = (acc[i][3] + b4.w) * mrow;
        *(float4*)(C + (size_t)gm * ldc + gn0 + tx * 4) = o;
    }
}

// ---------------------------------------------------------------------------
// Attention: one block per (b,h), 128 threads (one per query row).
// scores kept column-major in LDS (sc[k][i]) -> conflict-free per-thread column.
// ---------------------------------------------------------------------------
__global__ __launch_bounds__(128)
void attn_kernel(const float* __restrict__ qp, const float* __restrict__ kp,
                 const float* __restrict__ vp, float* __restrict__ ao) {
    __shared__ float sc[128][128];   // 64 KB
    const int bh = blockIdx.x;
    const int b = bh >> 3, h = bh & 7;
    const int i = threadIdx.x;
    const float scale = 0.10206207261596575f;  // 1/sqrt(96)

    float4 q[24];
    const float4* qrow = (const float4*)(qp + ((size_t)(b * NN + i) * DD) + h * HDh);
#pragma unroll
    for (int d = 0; d < 24; ++d) q[d] = qrow[d];

    for (int k = 0; k < 128; ++k) {
        const float4* krow = (const float4*)(kp + ((size_t)(b * NN + k) * DD) + h * HDh);
        float s = 0.f;
#pragma unroll
        for (int d = 0; d < 24; ++d) {
            float4 kv = krow[d];
            s = fmaf(q[d].x, kv.x, s); s = fmaf(q[d].y, kv.y, s);
            s = fmaf(q[d].z, kv.z, s); s = fmaf(q[d].w, kv.w, s);
        }
        sc[k][i] = s * scale;
    }

    float m = -1e30f;
    for (int k = 0; k < 128; ++k) m = fmaxf(m, sc[k][i]);
    float ssum = 0.f;
    for (int k = 0; k < 128; ++k) {
        float p = expf(sc[k][i] - m);
        sc[k][i] = p;
        ssum += p;
    }
    const float inv = 1.f / ssum;

    float4 acc[24];
#pragma unroll
    for (int d = 0; d < 24; ++d) acc[d] = make_float4(0.f, 0.f, 0.f, 0.f);
    for (int k = 0; k < 128; ++k) {
        float p = sc[k][i];
        const float4* vrow = (const float4*)(vp + ((size_t)(b * NN + k) * DD) + h * HDh);
#pragma unroll
        for (int d = 0; d < 24; ++d) {
            float4 vv = vrow[d];
            acc[d].x = fmaf(p, vv.x, acc[d].x);
            acc[d].y = fmaf(p, vv.y, acc[d].y);
            acc[d].z = fmaf(p, vv.z, acc[d].z);
            acc[d].w = fmaf(p, vv.w, acc[d].w);
        }
    }
    float4* arow = (float4*)(ao + ((size_t)(b * NN + i) * DD) + h * HDh);
#pragma unroll
    for (int d = 0; d < 24; ++d)
        arow[d] = make_float4(acc[d].x * inv, acc[d].y * inv, acc[d].z * inv, acc[d].w * inv);
}

// ---------------------------------------------------------------------------
// x = layernorm(word_feat*vf + attn_out; cn_g, cn_b) * vf     (row = 768)
// ---------------------------------------------------------------------------
__global__ __launch_bounds__(256)
void ln768_kernel(const float* __restrict__ wf, const float* __restrict__ at,
                  const int* __restrict__ wpos, const float* __restrict__ g,
                  const float* __restrict__ bta, float* __restrict__ xout) {
    __shared__ float red[256];
    const int r = blockIdx.x, tid = threadIdx.x;
    const float vf = (wpos[r] != -1) ? 1.f : 0.f;
    float t[3]; float s = 0.f, q = 0.f;
#pragma unroll
    for (int j = 0; j < 3; ++j) {
        int d = tid + j * 256;
        t[j] = wf[(size_t)r * DD + d] * vf + at[(size_t)r * DD + d];
        s += t[j];
        q = fmaf(t[j], t[j], q);
    }
    s = breduce_sum<256>(s, red);
    q = breduce_sum<256>(q, red);
    float mean = s * (1.f / DD);
    float var  = q * (1.f / DD) - mean * mean;
    float inv  = 1.f / sqrtf(var + 1e-5f);
#pragma unroll
    for (int j = 0; j < 3; ++j) {
        int d = tid + j * 256;
        xout[(size_t)r * DD + d] = ((t[j] - mean) * inv * g[d] + bta[d]) * vf;
    }
}

// ---------------------------------------------------------------------------
// h = layernorm(gelu_exact(g1); ln_g, ln_b)          (row = 256)
// ---------------------------------------------------------------------------
__global__ __launch_bounds__(256)
void ln256_gelu_kernel(const float* __restrict__ g1, const float* __restrict__ lg,
                       const float* __restrict__ lb, float* __restrict__ hout) {
    __shared__ float red[256];
    const int r = blockIdx.x, tid = threadIdx.x;
    float v  = g1[(size_t)r * HIDN + tid];
    float ge = 0.5f * v * (1.f + erff(v * 0.7071067811865475f));
    float s = breduce_sum<256>(ge, red);
    float q = breduce_sum<256>(ge * ge, red);
    float mean = s * (1.f / HIDN);
    float var  = q * (1.f / HIDN) - mean * mean;
    float inv  = 1.f / sqrtf(var + 1e-5f);
    hout[(size_t)r * HIDN + tid] = (ge - mean) * inv * lg[tid] + lb[tid];
}

// ---------------------------------------------------------------------------
// L2-normalize rows of 768
// ---------------------------------------------------------------------------
__global__ __launch_bounds__(256)
void norm768_kernel(const float* __restrict__ in, float* __restrict__ outp) {
    __shared__ float red[256];
    const int r = blockIdx.x, tid = threadIdx.x;
    float t[3]; float q = 0.f;
#pragma unroll
    for (int j = 0; j < 3; ++j) {
        t[j] = in[(size_t)r * DD + tid + j * 256];
        q = fmaf(t[j], t[j], q);
    }
    q = breduce_sum<256>(q, red);
    float inv = 1.f / fmaxf(sqrtf(q), 1e-12f);
#pragma unroll
    for (int j = 0; j < 3; ++j)
        outp[(size_t)r * DD + tid + j * 256] = t[j] * inv;
}

// ---------------------------------------------------------------------------
// clip_ref_n, stored TRANSPOSED: clipT[d*248 + l] = pos_emb[l]/||pos_emb[l]||
// ---------------------------------------------------------------------------
__global__ __launch_bounds__(256)
void clipT_kernel(const float* __restrict__ pe, float* __restrict__ clipT) {
    __shared__ float red[256];
    const int l = blockIdx.x, tid = threadIdx.x;
    float t[3]; float q = 0.f;
#pragma unroll
    for (int j = 0; j < 3; ++j) {
        t[j] = pe[(size_t)l * DD + tid + j * 256];
        q = fmaf(t[j], t[j], q);
    }
    q = breduce_sum<256>(q, red);
    float inv = 1.f / fmaxf(sqrtf(q), 1e-12f);
#pragma unroll
    for (int j = 0; j < 3; ++j)
        clipT[(size_t)(tid + j * 256) * LL + l] = t[j] * inv;
}

// ---------------------------------------------------------------------------
// KL head, fused per row: logits -> log_softmax -> gaussian target KL
// One block per (b,n), 256 threads; thread t owns position l=t (t<248).
// ---------------------------------------------------------------------------
__global__ __launch_bounds__(256)
void kl_kernel(const float* __restrict__ rope_n, const float* __restrict__ clipT,
               const int* __restrict__ wpos, const float* __restrict__ pos_temp,
               float* __restrict__ kl_part) {
    __shared__ float rn[768];
    __shared__ float red[256];
    const int r = blockIdx.x, tid = threadIdx.x;
    for (int d = tid; d < DD; d += 256) rn[d] = rope_n[(size_t)r * DD + d];
    __syncthreads();

    float logit = -1e30f;
    if (tid < LL) {
        float s = 0.f;
        for (int d = 0; d < DD; ++d)
            s = fmaf(rn[d], clipT[(size_t)d * LL + tid], s);
        float temp = fmaxf(pos_temp[0], 0.001f);
        logit = s / temp;
    }
    float m = breduce_max<256>(logit, red);
    float e = (tid < LL) ? expf(logit - m) : 0.f;
    float S = breduce_sum<256>(e, red);
    float logZ = m + logf(S);

    int wr = wpos[r];
    bool valid = (wr != -1);
    int wp = wr < 0 ? 0 : (wr > LL - 1 ? LL - 1 : wr);
    float dl = (float)tid - (float)wp;
    float targ = (tid < LL) ? expf(-dl * dl * 0.125f) : 0.f;  // 2*sigma^2 = 8
    float tsum = breduce_sum<256>(targ, red);
    float tn = targ / (tsum + 1e-12f);
    float c = (valid && tid < LL && tn > 0.f) ? tn * (logf(tn) - (logit - logZ)) : 0.f;
    float ksum = breduce_sum<256>(c, red);
    if (tid == 0) kl_part[r] = ksum;
}

// ---------------------------------------------------------------------------
// rel head: one block per (b,i), 128 threads (thread j = other row)
// ---------------------------------------------------------------------------
__global__ __launch_bounds__(128)
void rel_kernel(const float* __restrict__ rope_n, const int* __restrict__ wpos,
                float* __restrict__ rel_part, float* __restrict__ vm2_part) {
    __shared__ float rn[768];
    __shared__ float red[128];
    const int r = blockIdx.x, j = threadIdx.x;
    const int b = r >> 7;
    for (int d = j; d < DD; d += 128) rn[d] = rope_n[(size_t)r * DD + d];
    __syncthreads();

    int wi = wpos[r];
    bool vi = (wi != -1);
    float wif = (float)(wi < 0 ? 0 : (wi > LL - 1 ? LL - 1 : wi));
    int rj = b * NN + j;
    int wj = wpos[rj];
    bool vj = (wj != -1);
    float wjf = (float)(wj < 0 ? 0 : (wj > LL - 1 ? LL - 1 : wj));

    const float4* rv = (const float4*)(rope_n + (size_t)rj * DD);
    float s = 0.f;
    for (int d = 0; d < 192; ++d) {
        float4 v = rv[d];
        s = fmaf(rn[d * 4 + 0], v.x, s);
        s = fmaf(rn[d * 4 + 1], v.y, s);
        s = fmaf(rn[d * 4 + 2], v.z, s);
        s = fmaf(rn[d * 4 + 3], v.w, s);
    }
    float sim = (s + 1.f) * 0.5f;
    float ts  = 1.f - fabsf(wif - wjf) * (1.f / (float)LL);
    float m2  = (vi && vj) ? 1.f : 0.f;
    float df  = m2 * (sim - ts);
    float c   = df * df;
    float csum = breduce_sum<128>(c, red);
    float msum = breduce_sum<128>(m2, red);
    if (j == 0) { rel_part[r] = csum; vm2_part[r] = msum; }
}

// ---------------------------------------------------------------------------
// scatter: emb[b, wp, :] = 0.8*pos_emb[wp] + 0.2*rope[b,n]   (valid only)
// ---------------------------------------------------------------------------
__global__ __launch_bounds__(256)
void scatter_kernel(const float* __restrict__ pe, const float* __restrict__ rope,
                    const int* __restrict__ wpos, float* __restrict__ emb) {
    const int r = blockIdx.x, tid = threadIdx.x;
    int wr = wpos[r];
    if (wr == -1) return;
    int wp = wr < 0 ? 0 : (wr > LL - 1 ? LL - 1 : wr);
    int b = r >> 7;
    for (int d = tid; d < DD; d += 256)
        emb[((size_t)b * LL + wp) * DD + d] =
            0.8f * pe[(size_t)wp * DD + d] + 0.2f * rope[(size_t)r * DD + d];
}

// ---------------------------------------------------------------------------
// Final deterministic reduction of scalar losses (fp64, fixed order)
// ---------------------------------------------------------------------------
__global__ __launch_bounds__(256)
void final_kernel(const float* __restrict__ klp, const float* __restrict__ relp,
                  const float* __restrict__ vmp, const int* __restrict__ wpos,
                  float* __restrict__ outs) {
    __shared__ double rd[256];
    const int tid = threadIdx.x;
    double kl = 0.0, rel = 0.0, vm = 0.0, nv = 0.0;
    for (int r = tid; r < MROWS; r += 256) {
        kl  += (double)klp[r];
        rel += (double)relp[r];
        vm  += (double)vmp[r];
        nv  += (wpos[r] != -1) ? 1.0 : 0.0;
    }
    kl  = breduce_sum_d256(kl, rd);
    rel = breduce_sum_d256(rel, rd);
    vm  = breduce_sum_d256(vm, rd);
    nv  = breduce_sum_d256(nv, rd);
    if (tid == 0) {
        float klf  = (float)(kl / (nv + 1e-12));
        float relf = (float)(rel / (vm + 1e-12));
        outs[0] = klf + 0.5f * relf;   // peb_loss (1.0*kl + 0.5*rel)
        outs[1] = klf;
        outs[2] = relf;
    }
}

// ---------------------------------------------------------------------------
extern "C" void kernel_launch(void* const* d_in, const int* in_sizes, int n_in,
                              void* d_out, int out_size, void* d_ws, size_t ws_size,
                              hipStream_t stream) {
    (void)in_sizes; (void)n_in; (void)ws_size;

    const float* word_feat = (const float*)d_in[0];
    const float* text      = (const float*)d_in[1];
    const int*   wpos      = (const int*)d_in[2];
    const float* ctx_W     = (const float*)d_in[3];
    const float* ctx_b     = (const float*)d_in[4];
    const float* in_W      = (const float*)d_in[5];
    const float* in_b      = (const float*)d_in[6];
    const float* out_W     = (const float*)d_in[7];
    const float* out_b     = (const float*)d_in[8];
    const float* cn_g      = (const float*)d_in[9];
    const float* cn_b      = (const float*)d_in[10];
    const float* r1_W      = (const float*)d_in[11];
    const float* r1_b      = (const float*)d_in[12];
    const float* ln_g      = (const float*)d_in[13];
    const float* ln_b      = (const float*)d_in[14];
    const float* r2_W      = (const float*)d_in[15];
    const float* r2_b      = (const float*)d_in[16];
    const float* pos_emb   = (const float*)d_in[17];
    const float* pos_temp  = (const float*)d_in[18];

    float* ws = (float*)d_ws;
    const size_t BUF = (size_t)MROWS * DD;          // 12,582,912 floats
    float* X1 = ws + 0 * BUF;   // ctx_anchor -> ao -> rope
    float* X2 = ws + 1 * BUF;   // qp -> attn_out
    float* X3 = ws + 2 * BUF;   // kp -> x -> rope_n
    float* X4 = ws + 3 * BUF;   // vp ; then g1/h/clipT/partials
    float* G1    = X4;                                  // 16384*256
    float* Hbuf  = X4 + (size_t)MROWS * HIDN;           // 16384*256
    float* clipT = X4 + (size_t)2 * MROWS * HIDN;       // 768*248
    float* kl_part  = clipT + (size_t)DD * LL;
    float* rel_part = kl_part + MROWS;
    float* vm2_part = rel_part + MROWS;
    // total ws usage: 4*BUF floats = ~201 MB

    // zero the output (emb is a sparse scatter; scalars written by final_kernel)
    hipMemsetAsync(d_out, 0, (size_t)out_size * sizeof(float), stream);

    dim3 blk(256);
    dim3 gD (DD / 64,   MROWS / 64);   // N=768
    dim3 gHID(HIDN / 64, MROWS / 64);  // N=256

    // 1. ctx_anchor = (gather(text) @ ctx_W + ctx_b) * vf   -> X1
    gemm_kernel<2, true><<<gD, blk, 0, stream>>>(
        nullptr, 0, ctx_W, DD, ctx_b, X1, DD, 3 * DD, text, wpos);
    // 2. qp = (word_feat*vf) @ in_W[:, :768] + in_b[:768]   -> X2
    gemm_kernel<1, false><<<gD, blk, 0, stream>>>(
        word_feat, DD, in_W, 3 * DD, in_b, X2, DD, DD, nullptr, wpos);
    // 3. kp = ctx_anchor @ in_W[:, 768:1536] + in_b[768:]   -> X3
    gemm_kernel<0, false><<<gD, blk, 0, stream>>>(
        X1, DD, in_W + DD, 3 * DD, in_b + DD, X3, DD, DD, nullptr, nullptr);
    // 4. vp = ctx_anchor @ in_W[:, 1536:] + in_b[1536:]     -> X4
    gemm_kernel<0, false><<<gD, blk, 0, stream>>>(
        X1, DD, in_W + 2 * DD, 3 * DD, in_b + 2 * DD, X4, DD, DD, nullptr, nullptr);
    // 5. attention -> ao in X1 (ctx_anchor dead)
    attn_kernel<<<dim3(BB * HH), dim3(128), 0, stream>>>(X2, X3, X4, X1);
    // 6. clip_ref_n transposed (vp dead now)
    clipT_kernel<<<dim3(LL), blk, 0, stream>>>(pos_emb, clipT);
    // 7. attn_out = ao @ out_W + out_b -> X2 (qp dead)
    gemm_kernel<0, false><<<gD, blk, 0, stream>>>(
        X1, DD, out_W, DD, out_b, X2, DD, DD, nullptr, nullptr);
    // 8. x = LN(word_feat*vf + attn_out)*vf -> X3 (kp dead)
    ln768_kernel<<<dim3(MROWS), blk, 0, stream>>>(word_feat, X2, wpos, cn_g, cn_b, X3);
    // 9. g1 = x @ r1_W + r1_b -> G1
    gemm_kernel<0, false><<<gHID, blk, 0, stream>>>(
        X3, DD, r1_W, HIDN, r1_b, G1, HIDN, DD, nullptr, nullptr);
    // 10. h = LN(gelu(g1)) -> Hbuf
    ln256_gelu_kernel<<<dim3(MROWS), blk, 0, stream>>>(G1, ln_g, ln_b, Hbuf);
    // 11. rope = h @ r2_W + r2_b -> X1 (ao dead)
    gemm_kernel<0, false><<<gD, blk, 0, stream>>>(
        Hbuf, HIDN, r2_W, DD, r2_b, X1, DD, HIDN, nullptr, nullptr);
    // 12. rope_n -> X3 (x dead)
    norm768_kernel<<<dim3(MROWS), blk, 0, stream>>>(X1, X3);
    // 13. KL per row
    kl_kernel<<<dim3(MROWS), blk, 0, stream>>>(X3, clipT, wpos, pos_temp, kl_part);
    // 14. rel per (b,i)
    rel_kernel<<<dim3(MROWS), dim3(128), 0, stream>>>(X3, wpos, rel_part, vm2_part);
    // 15. scatter emb
    scatter_kernel<<<dim3(MROWS), blk, 0, stream>>>(pos_emb, X1, wpos, (float*)d_out);
    // 16. scalars
    final_kernel<<<dim3(1), blk, 0, stream>>>(
        kl_part, rel_part, vm2_part, wpos, (float*)d_out + (size_t)BB * LL * DD);
}

// Round 2
// 1550.642 us; speedup vs baseline: 2.3851x; 2.3851x over previous
//
#include <hip/hip_runtime.h>
#include <math.h>

// Problem constants
#define BB   128
#define NN   128
#define LL   248
#define DD   768
#define HH   8
#define HDh  96
#define HIDN 256
#define MROWS (BB*NN)   // 16384
#define MB_   (1u<<20)

typedef unsigned short u16;
typedef unsigned int   u32;
typedef __attribute__((ext_vector_type(8))) short s16x8;
typedef __attribute__((ext_vector_type(4))) float f32x4;

// ---------------------------------------------------------------------------
// helpers
// ---------------------------------------------------------------------------
__device__ __forceinline__ u16 f2bf(float x) {
    u32 u = __float_as_uint(x);
    u32 r = u + 0x7fffu + ((u >> 16) & 1u);
    return (u16)(r >> 16);
}
__device__ __forceinline__ float bf2f(u16 h) {
    return __uint_as_float(((u32)h) << 16);
}
__device__ __forceinline__ void gload16(const void* g, void* l) {
    __builtin_amdgcn_global_load_lds(
        (const __attribute__((address_space(1))) void*)g,
        (__attribute__((address_space(3))) void*)l, 16, 0, 0);
}

template<int NT>
__device__ __forceinline__ float breduce_sum(float v, float* red) {
    const int tid = threadIdx.x;
    red[tid] = v; __syncthreads();
#pragma unroll
    for (int o = NT / 2; o > 0; o >>= 1) {
        if (tid < o) red[tid] += red[tid + o];
        __syncthreads();
    }
    float r = red[0]; __syncthreads();
    return r;
}
template<int NT>
__device__ __forceinline__ float breduce_max(float v, float* red) {
    const int tid = threadIdx.x;
    red[tid] = v; __syncthreads();
#pragma unroll
    for (int o = NT / 2; o > 0; o >>= 1) {
        if (tid < o) red[tid] = fmaxf(red[tid], red[tid + o]);
        __syncthreads();
    }
    float r = red[0]; __syncthreads();
    return r;
}
__device__ __forceinline__ double breduce_sum_d256(double v, double* red) {
    const int tid = threadIdx.x;
    red[tid] = v; __syncthreads();
#pragma unroll
    for (int o = 128; o > 0; o >>= 1) {
        if (tid < o) red[tid] += red[tid + o];
        __syncthreads();
    }
    double r = red[0]; __syncthreads();
    return r;
}

// ---------------------------------------------------------------------------
// Prep kernels
// ---------------------------------------------------------------------------
// transpose+convert: src [R][C] f32 -> dst [C][R] bf16
__global__ __launch_bounds__(256)
void transposeW_kernel(const float* __restrict__ src, int R, int C,
                       u16* __restrict__ dst) {
    __shared__ float t[32][33];
    const int c0 = blockIdx.x * 32, r0 = blockIdx.y * 32;
    const int tx = threadIdx.x & 31, ty = threadIdx.x >> 5;  // 32 x 8
#pragma unroll
    for (int i = 0; i < 32; i += 8)
        t[ty + i][tx] = src[(size_t)(r0 + ty + i) * C + c0 + tx];
    __syncthreads();
#pragma unroll
    for (int i = 0; i < 32; i += 8)
        dst[(size_t)(c0 + ty + i) * R + r0 + tx] = f2bf(t[tx][ty + i]);
}

__global__ __launch_bounds__(256)
void cvt_bf16_kernel(const float* __restrict__ src, u16* __restrict__ dst, int n8) {
    int i = blockIdx.x * 256 + threadIdx.x;
    const int stride = gridDim.x * 256;
    for (; i < n8; i += stride) {
        const float4* s = (const float4*)(src + (size_t)i * 8);
        float4 a = s[0], b = s[1];
        uint4 o;
        o.x = (u32)f2bf(a.x) | ((u32)f2bf(a.y) << 16);
        o.y = (u32)f2bf(a.z) | ((u32)f2bf(a.w) << 16);
        o.z = (u32)f2bf(b.x) | ((u32)f2bf(b.y) << 16);
        o.w = (u32)f2bf(b.z) | ((u32)f2bf(b.w) << 16);
        *(uint4*)(dst + (size_t)i * 8) = o;
    }
}

// q_bf16 = bf16(word_feat * vf), 8 elems/chunk (768/8 = 96 chunks per row)
__global__ __launch_bounds__(256)
void qmask_kernel(const float* __restrict__ wf, const int* __restrict__ wpos,
                  u16* __restrict__ dst, int n8) {
    int i = blockIdx.x * 256 + threadIdx.x;
    const int stride = gridDim.x * 256;
    for (; i < n8; i += stride) {
        int row = i / 96;
        float vf = (wpos[row] != -1) ? 1.f : 0.f;
        const float4* s = (const float4*)(wf + (size_t)i * 8);
        float4 a = s[0], b = s[1];
        uint4 o;
        o.x = (u32)f2bf(a.x * vf) | ((u32)f2bf(a.y * vf) << 16);
        o.y = (u32)f2bf(a.z * vf) | ((u32)f2bf(a.w * vf) << 16);
        o.z = (u32)f2bf(b.x * vf) | ((u32)f2bf(b.y * vf) << 16);
        o.w = (u32)f2bf(b.z * vf) | ((u32)f2bf(b.w * vf) << 16);
        *(uint4*)(dst + (size_t)i * 8) = o;
    }
}

__global__ __launch_bounds__(256)
void cpos_kernel(const int* __restrict__ wpos, int* __restrict__ cpos, int n) {
    int i = blockIdx.x * 256 + threadIdx.x;
    if (i < n) {
        int w = wpos[i];
        cpos[i] = w < 0 ? 0 : (w > LL - 1 ? LL - 1 : w);
    }
}

// ---------------------------------------------------------------------------
// bf16 MFMA GEMM (m97 structure): C[M,N] = A[M,K](bf16) @ Bt[N,K]^T(bf16) + bias
// 128x128 tile, BK=32, 256 threads (4 waves, 2x2), 4x4 frags of 16x16x32.
// Bank swizzle: LDS dest linear (global_load_lds), global SOURCE column is
// inverse-swizzled, ds_read address swizzled with the same involution:
//   X(row) = ((row>>1)&3)<<4  (bytes)
// GATHER=1: A is the ctx window-gather from text_bf16 via per-lane addresses.
// MASK=1: output row *= (wpos[row] != -1).  CBF16: output dtype.
// ---------------------------------------------------------------------------
template<int GATHER, int CBF16, int MASK>
__global__ __launch_bounds__(256)
void gemm_bt(const u16* __restrict__ A,
             const u16* __restrict__ TXT,
             const int* __restrict__ cpos,
             const u16* __restrict__ Bt,
             const float* __restrict__ bias,
             void* __restrict__ Cout, int ldc, int K,
             const int* __restrict__ wpos) {
    __shared__ __align__(16) u16 Alds[128 * 32];
    __shared__ __align__(16) u16 Blds[128 * 32];
    const int tid = threadIdx.x;
    const int l = tid & 63, wv = tid >> 6;
    const int m0 = blockIdx.y * 128, n0 = blockIdx.x * 128;

    // staging geometry: flat byte f = issue*4096 + wv*1024 + l*16
    const int f0 = wv * 1024 + l * 16;
    const int f1 = f0 + 4096;
    const int rA0 = f0 >> 6, rA1 = f1 >> 6;
    const int cb0 = (f0 & 63) ^ (((rA0 >> 1) & 3) << 4);
    const int cb1 = (f1 & 63) ^ (((rA1 >> 1) & 3) << 4);
    const int c0e = cb0 >> 1, c1e = cb1 >> 1;

    u16* Ad0 = Alds + wv * 512;
    u16* Ad1 = Alds + 2048 + wv * 512;
    u16* Bd0 = Blds + wv * 512;
    u16* Bd1 = Blds + 2048 + wv * 512;

    const u16* pb0 = Bt + (size_t)(n0 + rA0) * K + c0e;
    const u16* pb1 = Bt + (size_t)(n0 + rA1) * K + c1e;

    const u16* pa0 = nullptr; const u16* pa1 = nullptr;
    int gb0 = 0, gb1 = 0, gc0 = 0, gc1 = 0;
    if constexpr (GATHER) {
        int g0 = m0 + rA0, g1 = m0 + rA1;
        gb0 = g0 >> 7; gb1 = g1 >> 7;
        gc0 = cpos[g0]; gc1 = cpos[g1];
    } else {
        pa0 = A + (size_t)(m0 + rA0) * K + c0e;
        pa1 = A + (size_t)(m0 + rA1) * K + c1e;
    }

    const int wm = (wv >> 1) * 64, wn = (wv & 1) * 64;
    const int la = l & 15, lg = l >> 4;

    int aoff[4], boff[4];
#pragma unroll
    for (int m = 0; m < 4; ++m) {
        int ra = wm + m * 16 + la;
        aoff[m] = ra * 32 + ((lg * 8) ^ (((ra >> 1) & 3) << 3));
        int rb = wn + m * 16 + la;
        boff[m] = rb * 32 + ((lg * 8) ^ (((rb >> 1) & 3) << 3));
    }

    f32x4 acc[4][4] = {};
    const int nk = K >> 5;
    for (int kt = 0; kt < nk; ++kt) {
        const int k0 = kt << 5;
        const u16 *ga0, *ga1;
        if constexpr (GATHER) {
            int w = k0 / DD;
            int kin = k0 - w * DD;
            int p0 = gc0 + w - 1; p0 = p0 < 0 ? 0 : (p0 > LL - 1 ? LL - 1 : p0);
            int p1 = gc1 + w - 1; p1 = p1 < 0 ? 0 : (p1 > LL - 1 ? LL - 1 : p1);
            ga0 = TXT + ((size_t)(gb0 * LL + p0)) * DD + kin + c0e;
            ga1 = TXT + ((size_t)(gb1 * LL + p1)) * DD + kin + c1e;
        } else {
            ga0 = pa0 + k0; ga1 = pa1 + k0;
        }
        gload16(ga0, Ad0);
        gload16(ga1, Ad1);
        gload16(pb0 + k0, Bd0);
        gload16(pb1 + k0, Bd1);
        __syncthreads();   // drains vmcnt -> LDS tile complete

        s16x8 af[4], bf[4];
#pragma unroll
        for (int m = 0; m < 4; ++m) af[m] = *(const s16x8*)(Alds + aoff[m]);
#pragma unroll
        for (int n = 0; n < 4; ++n) bf[n] = *(const s16x8*)(Blds + boff[n]);
#pragma unroll
        for (int m = 0; m < 4; ++m)
#pragma unroll
            for (int n = 0; n < 4; ++n)
                acc[m][n] = __builtin_amdgcn_mfma_f32_16x16x32_bf16(
                    af[m], bf[n], acc[m][n], 0, 0, 0);
        __syncthreads();
    }

    // epilogue: D row = (lane>>4)*4 + r, col = lane&15 (per 16x16 frag)
#pragma unroll
    for (int m = 0; m < 4; ++m) {
        const int rb = m0 + wm + m * 16 + lg * 4;
        float vf[4];
        if constexpr (MASK) {
#pragma unroll
            for (int r = 0; r < 4; ++r) vf[r] = (wpos[rb + r] != -1) ? 1.f : 0.f;
        }
#pragma unroll
        for (int n = 0; n < 4; ++n) {
            const int col = n0 + wn + n * 16 + la;
            const float bv = bias[col];
#pragma unroll
            for (int r = 0; r < 4; ++r) {
                float o = acc[m][n][r] + bv;
                if constexpr (MASK) o *= vf[r];
                if constexpr (CBF16)
                    ((u16*)Cout)[(size_t)(rb + r) * ldc + col] = f2bf(o);
                else
                    ((float*)Cout)[(size_t)(rb + r) * ldc + col] = o;
            }
        }
    }
}

// ---------------------------------------------------------------------------
// Attention: one block per (b,h), 128 threads (one per query row), bf16 I/O.
// ---------------------------------------------------------------------------
__global__ __launch_bounds__(128)
void attn_kernel(const u16* __restrict__ qp, const u16* __restrict__ kp,
                 const u16* __restrict__ vp, u16* __restrict__ ao) {
    __shared__ float sc[128][128];   // 64 KB
    const int bh = blockIdx.x;
    const int b = bh >> 3, h = bh & 7;
    const int i = threadIdx.x;
    const float scale = 0.10206207261596575f;  // 1/sqrt(96)

    float q[96];
    {
        const uint4* qr = (const uint4*)(qp + ((size_t)(b * NN + i)) * DD + h * HDh);
#pragma unroll
        for (int j = 0; j < 12; ++j) {
            uint4 w = qr[j];
            q[j*8+0] = __uint_as_float(w.x << 16); q[j*8+1] = __uint_as_float(w.x & 0xffff0000u);
            q[j*8+2] = __uint_as_float(w.y << 16); q[j*8+3] = __uint_as_float(w.y & 0xffff0000u);
            q[j*8+4] = __uint_as_float(w.z << 16); q[j*8+5] = __uint_as_float(w.z & 0xffff0000u);
            q[j*8+6] = __uint_as_float(w.w << 16); q[j*8+7] = __uint_as_float(w.w & 0xffff0000u);
        }
    }
    for (int k = 0; k < 128; ++k) {
        const uint4* kr = (const uint4*)(kp + ((size_t)(b * NN + k)) * DD + h * HDh);
        float s = 0.f;
#pragma unroll
        for (int j = 0; j < 12; ++j) {
            uint4 w = kr[j];
            s = fmaf(q[j*8+0], __uint_as_float(w.x << 16), s);
            s = fmaf(q[j*8+1], __uint_as_float(w.x & 0xffff0000u), s);
            s = fmaf(q[j*8+2], __uint_as_float(w.y << 16), s);
            s = fmaf(q[j*8+3], __uint_as_float(w.y & 0xffff0000u), s);
            s = fmaf(q[j*8+4], __uint_as_float(w.z << 16), s);
            s = fmaf(q[j*8+5], __uint_as_float(w.z & 0xffff0000u), s);
            s = fmaf(q[j*8+6], __uint_as_float(w.w << 16), s);
            s = fmaf(q[j*8+7], __uint_as_float(w.w & 0xffff0000u), s);
        }
        sc[k][i] = s * scale;
    }

    float m = -1e30f;
    for (int k = 0; k < 128; ++k) m = fmaxf(m, sc[k][i]);
    float ssum = 0.f;
    for (int k = 0; k < 128; ++k) {
        float p = expf(sc[k][i] - m);
        sc[k][i] = p;
        ssum += p;
    }
    const float inv = 1.f / ssum;

    float acc[96];
#pragma unroll
    for (int d = 0; d < 96; ++d) acc[d] = 0.f;
    for (int k = 0; k < 128; ++k) {
        float p = sc[k][i];
        const uint4* vr = (const uint4*)(vp + ((size_t)(b * NN + k)) * DD + h * HDh);
#pragma unroll
        for (int j = 0; j < 12; ++j) {
            uint4 w = vr[j];
            acc[j*8+0] = fmaf(p, __uint_as_float(w.x << 16), acc[j*8+0]);
            acc[j*8+1] = fmaf(p, __uint_as_float(w.x & 0xffff0000u), acc[j*8+1]);
            acc[j*8+2] = fmaf(p, __uint_as_float(w.y << 16), acc[j*8+2]);
            acc[j*8+3] = fmaf(p, __uint_as_float(w.y & 0xffff0000u), acc[j*8+3]);
            acc[j*8+4] = fmaf(p, __uint_as_float(w.z << 16), acc[j*8+4]);
            acc[j*8+5] = fmaf(p, __uint_as_float(w.z & 0xffff0000u), acc[j*8+5]);
            acc[j*8+6] = fmaf(p, __uint_as_float(w.w << 16), acc[j*8+6]);
            acc[j*8+7] = fmaf(p, __uint_as_float(w.w & 0xffff0000u), acc[j*8+7]);
        }
    }
    u16* ar = ao + ((size_t)(b * NN + i)) * DD + h * HDh;
#pragma unroll
    for (int j = 0; j < 12; ++j) {
        uint4 o;
        o.x = (u32)f2bf(acc[j*8+0] * inv) | ((u32)f2bf(acc[j*8+1] * inv) << 16);
        o.y = (u32)f2bf(acc[j*8+2] * inv) | ((u32)f2bf(acc[j*8+3] * inv) << 16);
        o.z = (u32)f2bf(acc[j*8+4] * inv) | ((u32)f2bf(acc[j*8+5] * inv) << 16);
        o.w = (u32)f2bf(acc[j*8+6] * inv) | ((u32)f2bf(acc[j*8+7] * inv) << 16);
        ((uint4*)ar)[j] = o;
    }
}

// ---------------------------------------------------------------------------
// x = layernorm(word_feat*vf + attn_out(bf16); cn_g, cn_b) * vf -> bf16
// ---------------------------------------------------------------------------
__global__ __launch_bounds__(256)
void ln768_kernel(const float* __restrict__ wf, const u16* __restrict__ at,
                  const int* __restrict__ wpos, const float* __restrict__ g,
                  const float* __restrict__ bta, u16* __restrict__ xout) {
    __shared__ float red[256];
    const int r = blockIdx.x, tid = threadIdx.x;
    const float vf = (wpos[r] != -1) ? 1.f : 0.f;
    float t[3]; float s = 0.f, q = 0.f;
#pragma unroll
    for (int j = 0; j < 3; ++j) {
        int d = tid + j * 256;
        t[j] = wf[(size_t)r * DD + d] * vf + bf2f(at[(size_t)r * DD + d]);
        s += t[j];
        q = fmaf(t[j], t[j], q);
    }
    s = breduce_sum<256>(s, red);
    q = breduce_sum<256>(q, red);
    float mean = s * (1.f / DD);
    float var  = q * (1.f / DD) - mean * mean;
    float inv  = 1.f / sqrtf(var + 1e-5f);
#pragma unroll
    for (int j = 0; j < 3; ++j) {
        int d = tid + j * 256;
        xout[(size_t)r * DD + d] = f2bf(((t[j] - mean) * inv * g[d] + bta[d]) * vf);
    }
}

// ---------------------------------------------------------------------------
// h = layernorm(gelu_exact(g1); ln_g, ln_b) -> bf16      (row = 256)
// ---------------------------------------------------------------------------
__global__ __launch_bounds__(256)
void ln256_gelu_kernel(const float* __restrict__ g1, const float* __restrict__ lg,
                       const float* __restrict__ lb, u16* __restrict__ hout) {
    __shared__ float red[256];
    const int r = blockIdx.x, tid = threadIdx.x;
    float v  = g1[(size_t)r * HIDN + tid];
    float ge = 0.5f * v * (1.f + erff(v * 0.7071067811865475f));
    float s = breduce_sum<256>(ge, red);
    float q = breduce_sum<256>(ge * ge, red);
    float mean = s * (1.f / HIDN);
    float var  = q * (1.f / HIDN) - mean * mean;
    float inv  = 1.f / sqrtf(var + 1e-5f);
    hout[(size_t)r * HIDN + tid] = f2bf((ge - mean) * inv * lg[tid] + lb[tid]);
}

// ---------------------------------------------------------------------------
// L2-normalize rows of 768 IN PLACE (rope -> rope_n)
// ---------------------------------------------------------------------------
__global__ __launch_bounds__(256)
void norm768_kernel(float* __restrict__ buf) {
    __shared__ float red[256];
    const int r = blockIdx.x, tid = threadIdx.x;
    float t[3]; float q = 0.f;
#pragma unroll
    for (int j = 0; j < 3; ++j) {
        t[j] = buf[(size_t)r * DD + tid + j * 256];
        q = fmaf(t[j], t[j], q);
    }
    q = breduce_sum<256>(q, red);
    float inv = 1.f / fmaxf(sqrtf(q), 1e-12f);
#pragma unroll
    for (int j = 0; j < 3; ++j)
        buf[(size_t)r * DD + tid + j * 256] = t[j] * inv;
}

// ---------------------------------------------------------------------------
// clip_ref_n stored TRANSPOSED: clipT[d*248 + l]
// ---------------------------------------------------------------------------
__global__ __launch_bounds__(256)
void clipT_kernel(const float* __restrict__ pe, float* __restrict__ clipT) {
    __shared__ float red[256];
    const int l = blockIdx.x, tid = threadIdx.x;
    float t[3]; float q = 0.f;
#pragma unroll
    for (int j = 0; j < 3; ++j) {
        t[j] = pe[(size_t)l * DD + tid + j * 256];
        q = fmaf(t[j], t[j], q);
    }
    q = breduce_sum<256>(q, red);
    float inv = 1.f / fmaxf(sqrtf(q), 1e-12f);
#pragma unroll
    for (int j = 0; j < 3; ++j)
        clipT[(size_t)(tid + j * 256) * LL + l] = t[j] * inv;
}

// ---------------------------------------------------------------------------
// KL head fused per row
// ---------------------------------------------------------------------------
__global__ __launch_bounds__(256)
void kl_kernel(const float* __restrict__ rope_n, const float* __restrict__ clipT,
               const int* __restrict__ wpos, const float* __restrict__ pos_temp,
               float* __restrict__ kl_part) {
    __shared__ float rn[768];
    __shared__ float red[256];
    const int r = blockIdx.x, tid = threadIdx.x;
    for (int d = tid; d < DD; d += 256) rn[d] = rope_n[(size_t)r * DD + d];
    __syncthreads();

    float logit = -1e30f;
    if (tid < LL) {
        float s = 0.f;
        for (int d = 0; d < DD; ++d)
            s = fmaf(rn[d], clipT[(size_t)d * LL + tid], s);
        float temp = fmaxf(pos_temp[0], 0.001f);
        logit = s / temp;
    }
    float m = breduce_max<256>(logit, red);
    float e = (tid < LL) ? expf(logit - m) : 0.f;
    float S = breduce_sum<256>(e, red);
    float logZ = m + logf(S);

    int wr = wpos[r];
    bool valid = (wr != -1);
    int wp = wr < 0 ? 0 : (wr > LL - 1 ? LL - 1 : wr);
    float dl = (float)tid - (float)wp;
    float targ = (tid < LL) ? expf(-dl * dl * 0.125f) : 0.f;
    float tsum = breduce_sum<256>(targ, red);
    float tn = targ / (tsum + 1e-12f);
    float c = (valid && tid < LL && tn > 0.f) ? tn * (logf(tn) - (logit - logZ)) : 0.f;
    float ksum = breduce_sum<256>(c, red);
    if (tid == 0) kl_part[r] = ksum;
}

// ---------------------------------------------------------------------------
// rel head: one block per (b, 16-row tile). 256 threads.
// thread t: fixed j = t&127; pairs ii = (t>>7) + 2q, q=0..7.
// ---------------------------------------------------------------------------
__global__ __launch_bounds__(256)
void rel_kernel(const float* __restrict__ rope_n, const int* __restrict__ wpos,
                float* __restrict__ rel_part, float* __restrict__ vm2_part) {
    __shared__ __align__(16) float ri[16][768];   // 48 KB
    __shared__ float red[256];
    const int blk = blockIdx.x;
    const int b = blk >> 3, i0 = (blk & 7) * 16;
    const int t = threadIdx.x;

    for (int e = t; e < 16 * 768; e += 256) {
        int ii = e / 768, d = e - ii * 768;
        ri[ii][d] = rope_n[((size_t)(b * NN + i0 + ii)) * DD + d];
    }
    __syncthreads();

    const int j = t & 127;
    const int g0 = t >> 7;
    const float4* rj = (const float4*)(rope_n + ((size_t)(b * NN + j)) * DD);

    float dot[8];
#pragma unroll
    for (int q = 0; q < 8; ++q) dot[q] = 0.f;
    for (int d4 = 0; d4 < 192; ++d4) {
        float4 v = rj[d4];
#pragma unroll
        for (int q = 0; q < 8; ++q) {
            const float4 rv = *(const float4*)&ri[g0 + q * 2][d4 * 4];
            dot[q] = fmaf(rv.x, v.x, dot[q]);
            dot[q] = fmaf(rv.y, v.y, dot[q]);
            dot[q] = fmaf(rv.z, v.z, dot[q]);
            dot[q] = fmaf(rv.w, v.w, dot[q]);
        }
    }

    int wj = wpos[b * NN + j];
    bool vj = (wj != -1);
    float wjf = (float)(wj < 0 ? 0 : (wj > LL - 1 ? LL - 1 : wj));

    float csum = 0.f, msum = 0.f;
#pragma unroll
    for (int q = 0; q < 8; ++q) {
        int ii = g0 + q * 2;
        int wi = wpos[b * NN + i0 + ii];
        bool vi = (wi != -1);
        float wif = (float)(wi < 0 ? 0 : (wi > LL - 1 ? LL - 1 : wi));
        float sim = (dot[q] + 1.f) * 0.5f;
        float ts  = 1.f - fabsf(wif - wjf) * (1.f / (float)LL);
        float m2  = (vi && vj) ? 1.f : 0.f;
        float df  = m2 * (sim - ts);
        csum += df * df;
        msum += m2;
    }
    csum = breduce_sum<256>(csum, red);
    msum = breduce_sum<256>(msum, red);
    if (t == 0) { rel_part[blk] = csum; vm2_part[blk] = msum; }
}

// ---------------------------------------------------------------------------
// scatter: emb[b, wp, :] = 0.8*pos_emb[wp] + 0.2*rope[b,n]   (valid only)
// ---------------------------------------------------------------------------
__global__ __launch_bounds__(256)
void scatter_kernel(const float* __restrict__ pe, const float* __restrict__ rope,
                    const int* __restrict__ wpos, float* __restrict__ emb) {
    const int r = blockIdx.x, tid = threadIdx.x;
    int wr = wpos[r];
    if (wr == -1) return;
    int wp = wr < 0 ? 0 : (wr > LL - 1 ? LL - 1 : wr);
    int b = r >> 7;
    for (int d = tid; d < DD; d += 256)
        emb[((size_t)b * LL + wp) * DD + d] =
            0.8f * pe[(size_t)wp * DD + d] + 0.2f * rope[(size_t)r * DD + d];
}

// ---------------------------------------------------------------------------
// Final deterministic fp64 reduction
// ---------------------------------------------------------------------------
__global__ __launch_bounds__(256)
void final_kernel(const float* __restrict__ klp, const float* __restrict__ relp,
                  const float* __restrict__ vmp, const int* __restrict__ wpos,
                  float* __restrict__ outs) {
    __shared__ double rd[256];
    const int tid = threadIdx.x;
    double kl = 0.0, rel = 0.0, vm = 0.0, nv = 0.0;
    for (int r = tid; r < MROWS; r += 256) {
        kl += (double)klp[r];
        nv += (wpos[r] != -1) ? 1.0 : 0.0;
    }
    for (int r = tid; r < 1024; r += 256) {
        rel += (double)relp[r];
        vm  += (double)vmp[r];
    }
    kl  = breduce_sum_d256(kl, rd);
    rel = breduce_sum_d256(rel, rd);
    vm  = breduce_sum_d256(vm, rd);
    nv  = breduce_sum_d256(nv, rd);
    if (tid == 0) {
        float klf  = (float)(kl / (nv + 1e-12));
        float relf = (float)(rel / (vm + 1e-12));
        outs[0] = klf + 0.5f * relf;
        outs[1] = klf;
        outs[2] = relf;
    }
}

// ---------------------------------------------------------------------------
extern "C" void kernel_launch(void* const* d_in, const int* in_sizes, int n_in,
                              void* d_out, int out_size, void* d_ws, size_t ws_size,
                              hipStream_t stream) {
    (void)in_sizes; (void)n_in; (void)ws_size;

    const float* word_feat = (const float*)d_in[0];
    const float* text      = (const float*)d_in[1];
    const int*   wpos      = (const int*)d_in[2];
    const float* ctx_W     = (const float*)d_in[3];
    const float* ctx_b     = (const float*)d_in[4];
    const float* in_W      = (const float*)d_in[5];
    const float* in_b      = (const float*)d_in[6];
    const float* out_W     = (const float*)d_in[7];
    const float* out_b     = (const float*)d_in[8];
    const float* cn_g      = (const float*)d_in[9];
    const float* cn_b      = (const float*)d_in[10];
    const float* r1_W      = (const float*)d_in[11];
    const float* r1_b      = (const float*)d_in[12];
    const float* ln_g      = (const float*)d_in[13];
    const float* ln_b      = (const float*)d_in[14];
    const float* r2_W      = (const float*)d_in[15];
    const float* r2_b      = (const float*)d_in[16];
    const float* pos_emb   = (const float*)d_in[17];
    const float* pos_temp  = (const float*)d_in[18];

    char* W = (char*)d_ws;
    // --- weight/partials area [0, 12MB) ---
    u16*   ctx_Wt = (u16*)(W);
    u16*   in_Wt  = ctx_Wt + (size_t)768 * 2304;
    u16*   out_Wt = in_Wt  + (size_t)2304 * 768;
    u16*   r1_Wt  = out_Wt + (size_t)768 * 768;
    u16*   r2_Wt  = r1_Wt  + (size_t)256 * 768;
    float* clipT  = (float*)(r2_Wt + (size_t)768 * 256);
    int*   cposb  = (int*)(clipT + (size_t)DD * LL);
    float* klp    = (float*)(cposb + MROWS);
    float* relp   = klp + MROWS;
    float* vmp    = relp + 1024;
    // --- big regions ---
    u16*   textb  = (u16*)(W + (size_t)12 * MB_);   // 48.8MB, dead after ctx GEMM
    u16*   xb     = textb;                           // reuse: x_bf16 (25.2MB)
    u16*   hb     = (u16*)(W + (size_t)38 * MB_);   // h bf16 (8.4MB)
    u16*   ctxa   = (u16*)(W + (size_t)62 * MB_);   // ctx_anchor bf16 (24MB)
    u16*   aob    = ctxa;                            // reuse: ao bf16
    u16*   qb     = (u16*)(W + (size_t)88 * MB_);   // q bf16 (24MB)
    u16*   atoutb = qb;                              // reuse: attn_out bf16
    u16*   qpb    = (u16*)(W + (size_t)114 * MB_);  // qp (24MB)
    u16*   kpb    = qpb + (size_t)MROWS * DD;        // kp @138MB
    u16*   vpb    = kpb + (size_t)MROWS * DD;        // vp @162MB, ends 186MB
    float* g1     = (float*)(W + (size_t)114 * MB_); // reuse after attn (16MB)
    float* rope   = (float*)(W + (size_t)140 * MB_); // 50.3MB, ends ~190MB

    hipMemsetAsync(d_out, 0, (size_t)out_size * sizeof(float), stream);

    dim3 blk(256);

    // --- prep: weights transpose+bf16, text/q conversions, cpos, clipT ---
    transposeW_kernel<<<dim3(768/32, 2304/32), blk, 0, stream>>>(ctx_W, 2304, 768, ctx_Wt);
    transposeW_kernel<<<dim3(2304/32, 768/32), blk, 0, stream>>>(in_W, 768, 2304, in_Wt);
    transposeW_kernel<<<dim3(768/32, 768/32),  blk, 0, stream>>>(out_W, 768, 768, out_Wt);
    transposeW_kernel<<<dim3(256/32, 768/32),  blk, 0, stream>>>(r1_W, 768, 256, r1_Wt);
    transposeW_kernel<<<dim3(768/32, 256/32),  blk, 0, stream>>>(r2_W, 256, 768, r2_Wt);
    cvt_bf16_kernel<<<dim3(2048), blk, 0, stream>>>(text, textb, BB * LL * DD / 8);
    qmask_kernel<<<dim3(2048), blk, 0, stream>>>(word_feat, wpos, qb, MROWS * DD / 8);
    cpos_kernel<<<dim3(64), blk, 0, stream>>>(wpos, cposb, MROWS);
    clipT_kernel<<<dim3(LL), blk, 0, stream>>>(pos_emb, clipT);

    dim3 g768(6, 128);
    dim3 g256(2, 128);

    // 1. ctx_anchor = (gather(text_bf16) @ ctx_W + ctx_b) * vf  -> bf16
    gemm_bt<1, 1, 1><<<g768, blk, 0, stream>>>(
        nullptr, textb, cposb, ctx_Wt, ctx_b, ctxa, DD, 3 * DD, wpos);
    // 2. qp = q_bf16 @ in_W[:, :768] + in_b[:768]
    gemm_bt<0, 1, 0><<<g768, blk, 0, stream>>>(
        qb, nullptr, nullptr, in_Wt, in_b, qpb, DD, DD, nullptr);
    // 3. kp
    gemm_bt<0, 1, 0><<<g768, blk, 0, stream>>>(
        ctxa, nullptr, nullptr, in_Wt + (size_t)768 * 768, in_b + DD, kpb, DD, DD, nullptr);
    // 4. vp
    gemm_bt<0, 1, 0><<<g768, blk, 0, stream>>>(
        ctxa, nullptr, nullptr, in_Wt + (size_t)1536 * 768, in_b + 2 * DD, vpb, DD, DD, nullptr);
    // 5. attention -> ao (bf16, overwrites ctx_anchor region)
    attn_kernel<<<dim3(BB * HH), dim3(128), 0, stream>>>(qpb, kpb, vpb, aob);
    // 6. attn_out = ao @ out_W + out_b -> bf16 (overwrites q region)
    gemm_bt<0, 1, 0><<<g768, blk, 0, stream>>>(
        aob, nullptr, nullptr, out_Wt, out_b, atoutb, DD, DD, nullptr);
    // 7. x = LN(word_feat*vf + attn_out)*vf -> bf16 (overwrites text region)
    ln768_kernel<<<dim3(MROWS), blk, 0, stream>>>(word_feat, atoutb, wpos, cn_g, cn_b, xb);
    // 8. g1 = x @ r1_W + r1_b -> fp32
    gemm_bt<0, 0, 0><<<g256, blk, 0, stream>>>(
        xb, nullptr, nullptr, r1_Wt, r1_b, g1, HIDN, DD, nullptr);
    // 9. h = LN(gelu(g1)) -> bf16
    ln256_gelu_kernel<<<dim3(MROWS), blk, 0, stream>>>(g1, ln_g, ln_b, hb);
    // 10. rope = h @ r2_W + r2_b -> fp32
    gemm_bt<0, 0, 0><<<g768, blk, 0, stream>>>(
        hb, nullptr, nullptr, r2_Wt, r2_b, rope, DD, HIDN, nullptr);
    // 11. scatter emb (uses raw rope) BEFORE in-place normalize
    scatter_kernel<<<dim3(MROWS), blk, 0, stream>>>(pos_emb, rope, wpos, (float*)d_out);
    // 12. rope -> rope_n in place
    norm768_kernel<<<dim3(MROWS), blk, 0, stream>>>(rope);
    // 13. KL per row
    kl_kernel<<<dim3(MROWS), blk, 0, stream>>>(rope, clipT, wpos, pos_temp, klp);
    // 14. rel per (b, 16-row tile)
    rel_kernel<<<dim3(BB * 8), blk, 0, stream>>>(rope, wpos, relp, vmp);
    // 15. scalars
    final_kernel<<<dim3(1), blk, 0, stream>>>(
        klp, relp, vmp, wpos, (float*)d_out + (size_t)BB * LL * DD);
}

// Round 3
// 1085.984 us; speedup vs baseline: 3.4056x; 1.4279x over previous
//
#include <hip/hip_runtime.h>
#include <math.h>

// Problem constants
#define BB   128
#define NN   128
#define LL   248
#define DD   768
#define HH   8
#define HDh  96
#define HIDN 256
#define MROWS (BB*NN)   // 16384
#define MB_   (1u<<20)

typedef unsigned short u16;
typedef unsigned int   u32;
typedef __attribute__((ext_vector_type(8))) short s16x8;
typedef __attribute__((ext_vector_type(4))) float f32x4;

// ---------------------------------------------------------------------------
// helpers
// ---------------------------------------------------------------------------
__device__ __forceinline__ u16 f2bf(float x) {
    u32 u = __float_as_uint(x);
    u32 r = u + 0x7fffu + ((u >> 16) & 1u);
    return (u16)(r >> 16);
}
__device__ __forceinline__ float bf2f(u16 h) {
    return __uint_as_float(((u32)h) << 16);
}
__device__ __forceinline__ void gload16(const void* g, void* l) {
    __builtin_amdgcn_global_load_lds(
        (const __attribute__((address_space(1))) void*)g,
        (__attribute__((address_space(3))) void*)l, 16, 0, 0);
}

template<int NT>
__device__ __forceinline__ float breduce_sum(float v, float* red) {
    const int tid = threadIdx.x;
    red[tid] = v; __syncthreads();
#pragma unroll
    for (int o = NT / 2; o > 0; o >>= 1) {
        if (tid < o) red[tid] += red[tid + o];
        __syncthreads();
    }
    float r = red[0]; __syncthreads();
    return r;
}
__device__ __forceinline__ double breduce_sum_d256(double v, double* red) {
    const int tid = threadIdx.x;
    red[tid] = v; __syncthreads();
#pragma unroll
    for (int o = 128; o > 0; o >>= 1) {
        if (tid < o) red[tid] += red[tid + o];
        __syncthreads();
    }
    double r = red[0]; __syncthreads();
    return r;
}

// ---------------------------------------------------------------------------
// Prep kernels
// ---------------------------------------------------------------------------
// transpose+convert: src [R][C] f32 -> dst [C][R] bf16
__global__ __launch_bounds__(256)
void transposeW_kernel(const float* __restrict__ src, int R, int C,
                       u16* __restrict__ dst) {
    __shared__ float t[32][33];
    const int c0 = blockIdx.x * 32, r0 = blockIdx.y * 32;
    const int tx = threadIdx.x & 31, ty = threadIdx.x >> 5;  // 32 x 8
#pragma unroll
    for (int i = 0; i < 32; i += 8)
        t[ty + i][tx] = src[(size_t)(r0 + ty + i) * C + c0 + tx];
    __syncthreads();
#pragma unroll
    for (int i = 0; i < 32; i += 8)
        dst[(size_t)(c0 + ty + i) * R + r0 + tx] = f2bf(t[tx][ty + i]);
}

__global__ __launch_bounds__(256)
void cvt_bf16_kernel(const float* __restrict__ src, u16* __restrict__ dst, int n8) {
    int i = blockIdx.x * 256 + threadIdx.x;
    const int stride = gridDim.x * 256;
    for (; i < n8; i += stride) {
        const float4* s = (const float4*)(src + (size_t)i * 8);
        float4 a = s[0], b = s[1];
        uint4 o;
        o.x = (u32)f2bf(a.x) | ((u32)f2bf(a.y) << 16);
        o.y = (u32)f2bf(a.z) | ((u32)f2bf(a.w) << 16);
        o.z = (u32)f2bf(b.x) | ((u32)f2bf(b.y) << 16);
        o.w = (u32)f2bf(b.z) | ((u32)f2bf(b.w) << 16);
        *(uint4*)(dst + (size_t)i * 8) = o;
    }
}

// q_bf16 = bf16(word_feat * vf)
__global__ __launch_bounds__(256)
void qmask_kernel(const float* __restrict__ wf, const int* __restrict__ wpos,
                  u16* __restrict__ dst, int n8) {
    int i = blockIdx.x * 256 + threadIdx.x;
    const int stride = gridDim.x * 256;
    for (; i < n8; i += stride) {
        int row = i / 96;
        float vf = (wpos[row] != -1) ? 1.f : 0.f;
        const float4* s = (const float4*)(wf + (size_t)i * 8);
        float4 a = s[0], b = s[1];
        uint4 o;
        o.x = (u32)f2bf(a.x * vf) | ((u32)f2bf(a.y * vf) << 16);
        o.y = (u32)f2bf(a.z * vf) | ((u32)f2bf(a.w * vf) << 16);
        o.z = (u32)f2bf(b.x * vf) | ((u32)f2bf(b.y * vf) << 16);
        o.w = (u32)f2bf(b.z * vf) | ((u32)f2bf(b.w * vf) << 16);
        *(uint4*)(dst + (size_t)i * 8) = o;
    }
}

__global__ __launch_bounds__(256)
void cpos_kernel(const int* __restrict__ wpos, int* __restrict__ cpos, int n) {
    int i = blockIdx.x * 256 + threadIdx.x;
    if (i < n) {
        int w = wpos[i];
        cpos[i] = w < 0 ? 0 : (w > LL - 1 ? LL - 1 : w);
    }
}

// clip_n bf16, row-major [256][768], rows 248..255 zero (B^T for logits GEMM)
__global__ __launch_bounds__(256)
void clipb_kernel(const float* __restrict__ pe, u16* __restrict__ clipb) {
    __shared__ float red[256];
    const int l = blockIdx.x, tid = threadIdx.x;
    if (l >= LL) {
        for (int j = 0; j < 3; ++j)
            clipb[(size_t)l * DD + tid + j * 256] = 0;
        return;
    }
    float t[3]; float q = 0.f;
#pragma unroll
    for (int j = 0; j < 3; ++j) {
        t[j] = pe[(size_t)l * DD + tid + j * 256];
        q = fmaf(t[j], t[j], q);
    }
    q = breduce_sum<256>(q, red);
    float inv = 1.f / fmaxf(sqrtf(q), 1e-12f);
#pragma unroll
    for (int j = 0; j < 3; ++j)
        clipb[(size_t)l * DD + tid + j * 256] = f2bf(t[j] * inv);
}

// ---------------------------------------------------------------------------
// bf16 MFMA GEMM (m97 structure): C[M,N] = A[M,K](bf16) @ Bt[N,K]^T(bf16) + bias
// 128x128 tile, BK=32, 256 threads (4 waves, 2x2), 4x4 frags of 16x16x32.
// Swizzle: linear LDS dest (global_load_lds), inverse-swizzled global SOURCE,
// swizzled ds_read (rule #21 both-sides involution).
// ---------------------------------------------------------------------------
template<int GATHER, int CBF16, int MASK>
__global__ __launch_bounds__(256)
void gemm_bt(const u16* __restrict__ A,
             const u16* __restrict__ TXT,
             const int* __restrict__ cpos,
             const u16* __restrict__ Bt,
             const float* __restrict__ bias,
             void* __restrict__ Cout, int ldc, int K,
             const int* __restrict__ wpos) {
    __shared__ __align__(16) u16 Alds[128 * 32];
    __shared__ __align__(16) u16 Blds[128 * 32];
    const int tid = threadIdx.x;
    const int l = tid & 63, wv = tid >> 6;
    const int m0 = blockIdx.y * 128, n0 = blockIdx.x * 128;

    const int f0 = wv * 1024 + l * 16;
    const int f1 = f0 + 4096;
    const int rA0 = f0 >> 6, rA1 = f1 >> 6;
    const int cb0 = (f0 & 63) ^ (((rA0 >> 1) & 3) << 4);
    const int cb1 = (f1 & 63) ^ (((rA1 >> 1) & 3) << 4);
    const int c0e = cb0 >> 1, c1e = cb1 >> 1;

    u16* Ad0 = Alds + wv * 512;
    u16* Ad1 = Alds + 2048 + wv * 512;
    u16* Bd0 = Blds + wv * 512;
    u16* Bd1 = Blds + 2048 + wv * 512;

    const u16* pb0 = Bt + (size_t)(n0 + rA0) * K + c0e;
    const u16* pb1 = Bt + (size_t)(n0 + rA1) * K + c1e;

    const u16* pa0 = nullptr; const u16* pa1 = nullptr;
    int gb0 = 0, gb1 = 0, gc0 = 0, gc1 = 0;
    if constexpr (GATHER) {
        int g0 = m0 + rA0, g1 = m0 + rA1;
        gb0 = g0 >> 7; gb1 = g1 >> 7;
        gc0 = cpos[g0]; gc1 = cpos[g1];
    } else {
        pa0 = A + (size_t)(m0 + rA0) * K + c0e;
        pa1 = A + (size_t)(m0 + rA1) * K + c1e;
    }

    const int wm = (wv >> 1) * 64, wn = (wv & 1) * 64;
    const int la = l & 15, lg = l >> 4;

    int aoff[4], boff[4];
#pragma unroll
    for (int m = 0; m < 4; ++m) {
        int ra = wm + m * 16 + la;
        aoff[m] = ra * 32 + ((lg * 8) ^ (((ra >> 1) & 3) << 3));
        int rb = wn + m * 16 + la;
        boff[m] = rb * 32 + ((lg * 8) ^ (((rb >> 1) & 3) << 3));
    }

    f32x4 acc[4][4] = {};
    const int nk = K >> 5;
    for (int kt = 0; kt < nk; ++kt) {
        const int k0 = kt << 5;
        const u16 *ga0, *ga1;
        if constexpr (GATHER) {
            int w = k0 / DD;
            int kin = k0 - w * DD;
            int p0 = gc0 + w - 1; p0 = p0 < 0 ? 0 : (p0 > LL - 1 ? LL - 1 : p0);
            int p1 = gc1 + w - 1; p1 = p1 < 0 ? 0 : (p1 > LL - 1 ? LL - 1 : p1);
            ga0 = TXT + ((size_t)(gb0 * LL + p0)) * DD + kin + c0e;
            ga1 = TXT + ((size_t)(gb1 * LL + p1)) * DD + kin + c1e;
        } else {
            ga0 = pa0 + k0; ga1 = pa1 + k0;
        }
        gload16(ga0, Ad0);
        gload16(ga1, Ad1);
        gload16(pb0 + k0, Bd0);
        gload16(pb1 + k0, Bd1);
        __syncthreads();

        s16x8 af[4], bf[4];
#pragma unroll
        for (int m = 0; m < 4; ++m) af[m] = *(const s16x8*)(Alds + aoff[m]);
#pragma unroll
        for (int n = 0; n < 4; ++n) bf[n] = *(const s16x8*)(Blds + boff[n]);
#pragma unroll
        for (int m = 0; m < 4; ++m)
#pragma unroll
            for (int n = 0; n < 4; ++n)
                acc[m][n] = __builtin_amdgcn_mfma_f32_16x16x32_bf16(
                    af[m], bf[n], acc[m][n], 0, 0, 0);
        __syncthreads();
    }

#pragma unroll
    for (int m = 0; m < 4; ++m) {
        const int rb = m0 + wm + m * 16 + lg * 4;
        float vf[4];
        if constexpr (MASK) {
#pragma unroll
            for (int r = 0; r < 4; ++r) vf[r] = (wpos[rb + r] != -1) ? 1.f : 0.f;
        }
#pragma unroll
        for (int n = 0; n < 4; ++n) {
            const int col = n0 + wn + n * 16 + la;
            const float bv = bias[col];
#pragma unroll
            for (int r = 0; r < 4; ++r) {
                float o = acc[m][n][r] + bv;
                if constexpr (MASK) o *= vf[r];
                if constexpr (CBF16)
                    ((u16*)Cout)[(size_t)(rb + r) * ldc + col] = f2bf(o);
                else
                    ((float*)Cout)[(size_t)(rb + r) * ldc + col] = o;
            }
        }
    }
}

// ---------------------------------------------------------------------------
// Attention: one block per (b,h), 128 threads (one per query row), bf16 I/O.
// ---------------------------------------------------------------------------
__global__ __launch_bounds__(128)
void attn_kernel(const u16* __restrict__ qp, const u16* __restrict__ kp,
                 const u16* __restrict__ vp, u16* __restrict__ ao) {
    __shared__ float sc[128][128];   // 64 KB
    const int bh = blockIdx.x;
    const int b = bh >> 3, h = bh & 7;
    const int i = threadIdx.x;
    const float scale = 0.10206207261596575f;  // 1/sqrt(96)

    float q[96];
    {
        const uint4* qr = (const uint4*)(qp + ((size_t)(b * NN + i)) * DD + h * HDh);
#pragma unroll
        for (int j = 0; j < 12; ++j) {
            uint4 w = qr[j];
            q[j*8+0] = __uint_as_float(w.x << 16); q[j*8+1] = __uint_as_float(w.x & 0xffff0000u);
            q[j*8+2] = __uint_as_float(w.y << 16); q[j*8+3] = __uint_as_float(w.y & 0xffff0000u);
            q[j*8+4] = __uint_as_float(w.z << 16); q[j*8+5] = __uint_as_float(w.z & 0xffff0000u);
            q[j*8+6] = __uint_as_float(w.w << 16); q[j*8+7] = __uint_as_float(w.w & 0xffff0000u);
        }
    }
    for (int k = 0; k < 128; ++k) {
        const uint4* kr = (const uint4*)(kp + ((size_t)(b * NN + k)) * DD + h * HDh);
        float s = 0.f;
#pragma unroll
        for (int j = 0; j < 12; ++j) {
            uint4 w = kr[j];
            s = fmaf(q[j*8+0], __uint_as_float(w.x << 16), s);
            s = fmaf(q[j*8+1], __uint_as_float(w.x & 0xffff0000u), s);
            s = fmaf(q[j*8+2], __uint_as_float(w.y << 16), s);
            s = fmaf(q[j*8+3], __uint_as_float(w.y & 0xffff0000u), s);
            s = fmaf(q[j*8+4], __uint_as_float(w.z << 16), s);
            s = fmaf(q[j*8+5], __uint_as_float(w.z & 0xffff0000u), s);
            s = fmaf(q[j*8+6], __uint_as_float(w.w << 16), s);
            s = fmaf(q[j*8+7], __uint_as_float(w.w & 0xffff0000u), s);
        }
        sc[k][i] = s * scale;
    }

    float m = -1e30f;
    for (int k = 0; k < 128; ++k) m = fmaxf(m, sc[k][i]);
    float ssum = 0.f;
    for (int k = 0; k < 128; ++k) {
        float p = expf(sc[k][i] - m);
        sc[k][i] = p;
        ssum += p;
    }
    const float inv = 1.f / ssum;

    float acc[96];
#pragma unroll
    for (int d = 0; d < 96; ++d) acc[d] = 0.f;
    for (int k = 0; k < 128; ++k) {
        float p = sc[k][i];
        const uint4* vr = (const uint4*)(vp + ((size_t)(b * NN + k)) * DD + h * HDh);
#pragma unroll
        for (int j = 0; j < 12; ++j) {
            uint4 w = vr[j];
            acc[j*8+0] = fmaf(p, __uint_as_float(w.x << 16), acc[j*8+0]);
            acc[j*8+1] = fmaf(p, __uint_as_float(w.x & 0xffff0000u), acc[j*8+1]);
            acc[j*8+2] = fmaf(p, __uint_as_float(w.y << 16), acc[j*8+2]);
            acc[j*8+3] = fmaf(p, __uint_as_float(w.y & 0xffff0000u), acc[j*8+3]);
            acc[j*8+4] = fmaf(p, __uint_as_float(w.z << 16), acc[j*8+4]);
            acc[j*8+5] = fmaf(p, __uint_as_float(w.z & 0xffff0000u), acc[j*8+5]);
            acc[j*8+6] = fmaf(p, __uint_as_float(w.w << 16), acc[j*8+6]);
            acc[j*8+7] = fmaf(p, __uint_as_float(w.w & 0xffff0000u), acc[j*8+7]);
        }
    }
    u16* ar = ao + ((size_t)(b * NN + i)) * DD + h * HDh;
#pragma unroll
    for (int j = 0; j < 12; ++j) {
        uint4 o;
        o.x = (u32)f2bf(acc[j*8+0] * inv) | ((u32)f2bf(acc[j*8+1] * inv) << 16);
        o.y = (u32)f2bf(acc[j*8+2] * inv) | ((u32)f2bf(acc[j*8+3] * inv) << 16);
        o.z = (u32)f2bf(acc[j*8+4] * inv) | ((u32)f2bf(acc[j*8+5] * inv) << 16);
        o.w = (u32)f2bf(acc[j*8+6] * inv) | ((u32)f2bf(acc[j*8+7] * inv) << 16);
        ((uint4*)ar)[j] = o;
    }
}

// ---------------------------------------------------------------------------
// x = layernorm(word_feat*vf + attn_out(bf16); cn_g, cn_b) * vf -> bf16
// ---------------------------------------------------------------------------
__global__ __launch_bounds__(256)
void ln768_kernel(const float* __restrict__ wf, const u16* __restrict__ at,
                  const int* __restrict__ wpos, const float* __restrict__ g,
                  const float* __restrict__ bta, u16* __restrict__ xout) {
    __shared__ float red[256];
    const int r = blockIdx.x, tid = threadIdx.x;
    const float vf = (wpos[r] != -1) ? 1.f : 0.f;
    float t[3]; float s = 0.f, q = 0.f;
#pragma unroll
    for (int j = 0; j < 3; ++j) {
        int d = tid + j * 256;
        t[j] = wf[(size_t)r * DD + d] * vf + bf2f(at[(size_t)r * DD + d]);
        s += t[j];
        q = fmaf(t[j], t[j], q);
    }
    s = breduce_sum<256>(s, red);
    q = breduce_sum<256>(q, red);
    float mean = s * (1.f / DD);
    float var  = q * (1.f / DD) - mean * mean;
    float inv  = 1.f / sqrtf(var + 1e-5f);
#pragma unroll
    for (int j = 0; j < 3; ++j) {
        int d = tid + j * 256;
        xout[(size_t)r * DD + d] = f2bf(((t[j] - mean) * inv * g[d] + bta[d]) * vf);
    }
}

// ---------------------------------------------------------------------------
// h = layernorm(gelu_exact(g1); ln_g, ln_b) -> bf16      (row = 256)
// ---------------------------------------------------------------------------
__global__ __launch_bounds__(256)
void ln256_gelu_kernel(const float* __restrict__ g1, const float* __restrict__ lg,
                       const float* __restrict__ lb, u16* __restrict__ hout) {
    __shared__ float red[256];
    const int r = blockIdx.x, tid = threadIdx.x;
    float v  = g1[(size_t)r * HIDN + tid];
    float ge = 0.5f * v * (1.f + erff(v * 0.7071067811865475f));
    float s = breduce_sum<256>(ge, red);
    float q = breduce_sum<256>(ge * ge, red);
    float mean = s * (1.f / HIDN);
    float var  = q * (1.f / HIDN) - mean * mean;
    float inv  = 1.f / sqrtf(var + 1e-5f);
    hout[(size_t)r * HIDN + tid] = f2bf((ge - mean) * inv * lg[tid] + lb[tid]);
}

// ---------------------------------------------------------------------------
// L2-normalize rows of 768 IN PLACE + emit bf16 copy
// ---------------------------------------------------------------------------
__global__ __launch_bounds__(256)
void norm768_kernel(float* __restrict__ buf, u16* __restrict__ outb) {
    __shared__ float red[256];
    const int r = blockIdx.x, tid = threadIdx.x;
    float t[3]; float q = 0.f;
#pragma unroll
    for (int j = 0; j < 3; ++j) {
        t[j] = buf[(size_t)r * DD + tid + j * 256];
        q = fmaf(t[j], t[j], q);
    }
    q = breduce_sum<256>(q, red);
    float inv = 1.f / fmaxf(sqrtf(q), 1e-12f);
#pragma unroll
    for (int j = 0; j < 3; ++j) {
        float v = t[j] * inv;
        buf[(size_t)r * DD + tid + j * 256] = v;
        outb[(size_t)r * DD + tid + j * 256] = f2bf(v);
    }
}

// ---------------------------------------------------------------------------
// KL from precomputed logits (raw dots). One WAVE per row, 4 rows/block.
// Lane l owns cols l, l+64, l+128, l+192. All reductions via shfl_xor.
// ---------------------------------------------------------------------------
__global__ __launch_bounds__(256)
void kl_lite_kernel(const float* __restrict__ logits, const int* __restrict__ wpos,
                    const float* __restrict__ pos_temp, float* __restrict__ klp) {
    const int row = blockIdx.x * 4 + (threadIdx.x >> 6);
    const int l = threadIdx.x & 63;
    const float invt = 1.f / fmaxf(pos_temp[0], 0.001f);
    const float* lrow = logits + (size_t)row * 256;

    float lg[4];
#pragma unroll
    for (int q = 0; q < 4; ++q) {
        int c = l + q * 64;
        lg[q] = (c < LL) ? lrow[c] * invt : -1e30f;
    }
    float m = fmaxf(fmaxf(lg[0], lg[1]), fmaxf(lg[2], lg[3]));
#pragma unroll
    for (int o = 32; o > 0; o >>= 1) m = fmaxf(m, __shfl_xor(m, o, 64));

    float S = 0.f;
#pragma unroll
    for (int q = 0; q < 4; ++q) S += expf(lg[q] - m);
#pragma unroll
    for (int o = 32; o > 0; o >>= 1) S += __shfl_xor(S, o, 64);
    const float logZ = m + logf(S);

    const int wr = wpos[row];
    const bool valid = (wr != -1);
    const int wp = wr < 0 ? 0 : (wr > LL - 1 ? LL - 1 : wr);

    float targ[4]; float tsum = 0.f;
#pragma unroll
    for (int q = 0; q < 4; ++q) {
        int c = l + q * 64;
        float dl = (float)c - (float)wp;
        targ[q] = (c < LL) ? expf(-dl * dl * 0.125f) : 0.f;
        tsum += targ[q];
    }
#pragma unroll
    for (int o = 32; o > 0; o >>= 1) tsum += __shfl_xor(tsum, o, 64);
    const float tden = 1.f / (tsum + 1e-12f);

    float c_ = 0.f;
#pragma unroll
    for (int q = 0; q < 4; ++q) {
        float tn = targ[q] * tden;
        if (valid && tn > 0.f) c_ += tn * (logf(tn) - (lg[q] - logZ));
    }
#pragma unroll
    for (int o = 32; o > 0; o >>= 1) c_ += __shfl_xor(c_, o, 64);
    if (l == 0) klp[row] = c_;
}

// ---------------------------------------------------------------------------
// rel head: one block per (b, 16-row tile). 256 threads.
// ---------------------------------------------------------------------------
__global__ __launch_bounds__(256)
void rel_kernel(const float* __restrict__ rope_n, const int* __restrict__ wpos,
                float* __restrict__ rel_part, float* __restrict__ vm2_part) {
    __shared__ __align__(16) float ri[16][768];   // 48 KB
    __shared__ float red[256];
    const int blk = blockIdx.x;
    const int b = blk >> 3, i0 = (blk & 7) * 16;
    const int t = threadIdx.x;

    for (int e = t; e < 16 * 768; e += 256) {
        int ii = e / 768, d = e - ii * 768;
        ri[ii][d] = rope_n[((size_t)(b * NN + i0 + ii)) * DD + d];
    }
    __syncthreads();

    const int j = t & 127;
    const int g0 = t >> 7;
    const float4* rj = (const float4*)(rope_n + ((size_t)(b * NN + j)) * DD);

    float dot[8];
#pragma unroll
    for (int q = 0; q < 8; ++q) dot[q] = 0.f;
    for (int d4 = 0; d4 < 192; ++d4) {
        float4 v = rj[d4];
#pragma unroll
        for (int q = 0; q < 8; ++q) {
            const float4 rv = *(const float4*)&ri[g0 + q * 2][d4 * 4];
            dot[q] = fmaf(rv.x, v.x, dot[q]);
            dot[q] = fmaf(rv.y, v.y, dot[q]);
            dot[q] = fmaf(rv.z, v.z, dot[q]);
            dot[q] = fmaf(rv.w, v.w, dot[q]);
        }
    }

    int wj = wpos[b * NN + j];
    bool vj = (wj != -1);
    float wjf = (float)(wj < 0 ? 0 : (wj > LL - 1 ? LL - 1 : wj));

    float csum = 0.f, msum = 0.f;
#pragma unroll
    for (int q = 0; q < 8; ++q) {
        int ii = g0 + q * 2;
        int wi = wpos[b * NN + i0 + ii];
        bool vi = (wi != -1);
        float wif = (float)(wi < 0 ? 0 : (wi > LL - 1 ? LL - 1 : wi));
        float sim = (dot[q] + 1.f) * 0.5f;
        float ts  = 1.f - fabsf(wif - wjf) * (1.f / (float)LL);
        float m2  = (vi && vj) ? 1.f : 0.f;
        float df  = m2 * (sim - ts);
        csum += df * df;
        msum += m2;
    }
    csum = breduce_sum<256>(csum, red);
    msum = breduce_sum<256>(msum, red);
    if (t == 0) { rel_part[blk] = csum; vm2_part[blk] = msum; }
}

// ---------------------------------------------------------------------------
// scatter: emb[b, wp, :] = 0.8*pos_emb[wp] + 0.2*rope[b,n]   (valid only)
// ---------------------------------------------------------------------------
__global__ __launch_bounds__(256)
void scatter_kernel(const float* __restrict__ pe, const float* __restrict__ rope,
                    const int* __restrict__ wpos, float* __restrict__ emb) {
    const int r = blockIdx.x, tid = threadIdx.x;
    int wr = wpos[r];
    if (wr == -1) return;
    int wp = wr < 0 ? 0 : (wr > LL - 1 ? LL - 1 : wr);
    int b = r >> 7;
    for (int d = tid; d < DD; d += 256)
        emb[((size_t)b * LL + wp) * DD + d] =
            0.8f * pe[(size_t)wp * DD + d] + 0.2f * rope[(size_t)r * DD + d];
}

// ---------------------------------------------------------------------------
// Final deterministic fp64 reduction
// ---------------------------------------------------------------------------
__global__ __launch_bounds__(256)
void final_kernel(const float* __restrict__ klp, const float* __restrict__ relp,
                  const float* __restrict__ vmp, const int* __restrict__ wpos,
                  float* __restrict__ outs) {
    __shared__ double rd[256];
    const int tid = threadIdx.x;
    double kl = 0.0, rel = 0.0, vm = 0.0, nv = 0.0;
    for (int r = tid; r < MROWS; r += 256) {
        kl += (double)klp[r];
        nv += (wpos[r] != -1) ? 1.0 : 0.0;
    }
    for (int r = tid; r < 1024; r += 256) {
        rel += (double)relp[r];
        vm  += (double)vmp[r];
    }
    kl  = breduce_sum_d256(kl, rd);
    rel = breduce_sum_d256(rel, rd);
    vm  = breduce_sum_d256(vm, rd);
    nv  = breduce_sum_d256(nv, rd);
    if (tid == 0) {
        float klf  = (float)(kl / (nv + 1e-12));
        float relf = (float)(rel / (vm + 1e-12));
        outs[0] = klf + 0.5f * relf;
        outs[1] = klf;
        outs[2] = relf;
    }
}

// ---------------------------------------------------------------------------
extern "C" void kernel_launch(void* const* d_in, const int* in_sizes, int n_in,
                              void* d_out, int out_size, void* d_ws, size_t ws_size,
                              hipStream_t stream) {
    (void)in_sizes; (void)n_in; (void)ws_size;

    const float* word_feat = (const float*)d_in[0];
    const float* text      = (const float*)d_in[1];
    const int*   wpos      = (const int*)d_in[2];
    const float* ctx_W     = (const float*)d_in[3];
    const float* ctx_b     = (const float*)d_in[4];
    const float* in_W      = (const float*)d_in[5];
    const float* in_b      = (const float*)d_in[6];
    const float* out_W     = (const float*)d_in[7];
    const float* out_b     = (const float*)d_in[8];
    const float* cn_g      = (const float*)d_in[9];
    const float* cn_b      = (const float*)d_in[10];
    const float* r1_W      = (const float*)d_in[11];
    const float* r1_b      = (const float*)d_in[12];
    const float* ln_g      = (const float*)d_in[13];
    const float* ln_b      = (const float*)d_in[14];
    const float* r2_W      = (const float*)d_in[15];
    const float* r2_b      = (const float*)d_in[16];
    const float* pos_emb   = (const float*)d_in[17];
    const float* pos_temp  = (const float*)d_in[18];

    char* W = (char*)d_ws;
    // --- weight/partials area [0, 12MB) ---
    u16*   ctx_Wt = (u16*)(W);
    u16*   in_Wt  = ctx_Wt + (size_t)768 * 2304;
    u16*   out_Wt = in_Wt  + (size_t)2304 * 768;
    u16*   r1_Wt  = out_Wt + (size_t)768 * 768;
    u16*   r2_Wt  = r1_Wt  + (size_t)256 * 768;
    u16*   clipb  = r2_Wt + (size_t)768 * 256;          // [256][768] bf16
    int*   cposb  = (int*)(clipb + (size_t)256 * DD);
    float* klp    = (float*)(cposb + MROWS);
    float* relp   = klp + MROWS;
    float* vmp    = relp + 1024;
    float* zbias  = vmp + 1024;                          // 256 zero floats
    // --- big regions ---
    u16*   textb  = (u16*)(W + (size_t)12 * MB_);   // 46.5MB, dead after ctx GEMM
    u16*   xb     = textb;                           // reuse: x_bf16 (24MB)
    u16*   hb     = (u16*)(W + (size_t)38 * MB_);   // h bf16 (8.4MB)
    u16*   ctxa   = (u16*)(W + (size_t)62 * MB_);   // ctx_anchor bf16 (24MB)
    u16*   aob    = ctxa;                            // reuse: ao bf16
    u16*   rnb    = ctxa;                            // reuse: rope_n bf16 (24MB)
    u16*   qb     = (u16*)(W + (size_t)88 * MB_);   // q bf16 (24MB)
    u16*   atoutb = qb;                              // reuse: attn_out bf16
    float* logits = (float*)qb;                      // reuse: logits fp32 (16MB)
    u16*   qpb    = (u16*)(W + (size_t)114 * MB_);  // qp (24MB)
    u16*   kpb    = qpb + (size_t)MROWS * DD;        // kp @138MB
    u16*   vpb    = kpb + (size_t)MROWS * DD;        // vp @162MB, ends 186MB
    float* g1     = (float*)(W + (size_t)114 * MB_); // reuse after attn (16MB)
    float* rope   = (float*)(W + (size_t)140 * MB_); // 50.3MB, ends ~190MB

    hipMemsetAsync(d_out, 0, (size_t)out_size * sizeof(float), stream);
    hipMemsetAsync(zbias, 0, 256 * sizeof(float), stream);

    dim3 blk(256);

    // --- prep ---
    transposeW_kernel<<<dim3(768/32, 2304/32), blk, 0, stream>>>(ctx_W, 2304, 768, ctx_Wt);
    transposeW_kernel<<<dim3(2304/32, 768/32), blk, 0, stream>>>(in_W, 768, 2304, in_Wt);
    transposeW_kernel<<<dim3(768/32, 768/32),  blk, 0, stream>>>(out_W, 768, 768, out_Wt);
    transposeW_kernel<<<dim3(256/32, 768/32),  blk, 0, stream>>>(r1_W, 768, 256, r1_Wt);
    transposeW_kernel<<<dim3(768/32, 256/32),  blk, 0, stream>>>(r2_W, 256, 768, r2_Wt);
    cvt_bf16_kernel<<<dim3(2048), blk, 0, stream>>>(text, textb, BB * LL * DD / 8);
    qmask_kernel<<<dim3(2048), blk, 0, stream>>>(word_feat, wpos, qb, MROWS * DD / 8);
    cpos_kernel<<<dim3(64), blk, 0, stream>>>(wpos, cposb, MROWS);
    clipb_kernel<<<dim3(256), blk, 0, stream>>>(pos_emb, clipb);

    dim3 g768(6, 128);
    dim3 g256(2, 128);

    // 1. ctx_anchor
    gemm_bt<1, 1, 1><<<g768, blk, 0, stream>>>(
        nullptr, textb, cposb, ctx_Wt, ctx_b, ctxa, DD, 3 * DD, wpos);
    // 2. qp
    gemm_bt<0, 1, 0><<<g768, blk, 0, stream>>>(
        qb, nullptr, nullptr, in_Wt, in_b, qpb, DD, DD, nullptr);
    // 3. kp
    gemm_bt<0, 1, 0><<<g768, blk, 0, stream>>>(
        ctxa, nullptr, nullptr, in_Wt + (size_t)768 * 768, in_b + DD, kpb, DD, DD, nullptr);
    // 4. vp
    gemm_bt<0, 1, 0><<<g768, blk, 0, stream>>>(
        ctxa, nullptr, nullptr, in_Wt + (size_t)1536 * 768, in_b + 2 * DD, vpb, DD, DD, nullptr);
    // 5. attention -> ao (overwrites ctx_anchor region)
    attn_kernel<<<dim3(BB * HH), dim3(128), 0, stream>>>(qpb, kpb, vpb, aob);
    // 6. attn_out = ao @ out_W + out_b (overwrites q region)
    gemm_bt<0, 1, 0><<<g768, blk, 0, stream>>>(
        aob, nullptr, nullptr, out_Wt, out_b, atoutb, DD, DD, nullptr);
    // 7. x = LN(word_feat*vf + attn_out)*vf (overwrites text region)
    ln768_kernel<<<dim3(MROWS), blk, 0, stream>>>(word_feat, atoutb, wpos, cn_g, cn_b, xb);
    // 8. g1 = x @ r1_W + r1_b
    gemm_bt<0, 0, 0><<<g256, blk, 0, stream>>>(
        xb, nullptr, nullptr, r1_Wt, r1_b, g1, HIDN, DD, nullptr);
    // 9. h = LN(gelu(g1))
    ln256_gelu_kernel<<<dim3(MROWS), blk, 0, stream>>>(g1, ln_g, ln_b, hb);
    // 10. rope = h @ r2_W + r2_b
    gemm_bt<0, 0, 0><<<g768, blk, 0, stream>>>(
        hb, nullptr, nullptr, r2_Wt, r2_b, rope, DD, HIDN, nullptr);
    // 11. scatter emb (raw rope) BEFORE normalize
    scatter_kernel<<<dim3(MROWS), blk, 0, stream>>>(pos_emb, rope, wpos, (float*)d_out);
    // 12. rope -> rope_n in place + bf16 copy (overwrites ao region)
    norm768_kernel<<<dim3(MROWS), blk, 0, stream>>>(rope, rnb);
    // 13. logits = rope_n_bf16 @ clip_n^T  (fp32 out, overwrites attn_out region)
    gemm_bt<0, 0, 0><<<g256, blk, 0, stream>>>(
        rnb, nullptr, nullptr, clipb, zbias, logits, 256, DD, nullptr);
    // 14. KL from logits (wave per row)
    kl_lite_kernel<<<dim3(MROWS / 4), blk, 0, stream>>>(logits, wpos, pos_temp, klp);
    // 15. rel per (b, 16-row tile)
    rel_kernel<<<dim3(BB * 8), blk, 0, stream>>>(rope, wpos, relp, vmp);
    // 16. scalars
    final_kernel<<<dim3(1), blk, 0, stream>>>(
        klp, relp, vmp, wpos, (float*)d_out + (size_t)BB * LL * DD);
}

// Round 4
// 690.159 us; speedup vs baseline: 5.3588x; 1.5735x over previous
//
#include <hip/hip_runtime.h>
#include <math.h>

// Problem constants
#define BB   128
#define NN   128
#define LL   248
#define DD   768
#define HH   8
#define HDh  96
#define HIDN 256
#define MROWS (BB*NN)   // 16384
#define MB_   (1u<<20)

typedef unsigned short u16;
typedef unsigned int   u32;
typedef __attribute__((ext_vector_type(8))) short s16x8;
typedef __attribute__((ext_vector_type(4))) float f32x4;

// ---------------------------------------------------------------------------
// helpers
// ---------------------------------------------------------------------------
__device__ __forceinline__ u16 f2bf(float x) {
    u32 u = __float_as_uint(x);
    u32 r = u + 0x7fffu + ((u >> 16) & 1u);
    return (u16)(r >> 16);
}
__device__ __forceinline__ float bf2f(u16 h) {
    return __uint_as_float(((u32)h) << 16);
}
__device__ __forceinline__ void gload16(const void* g, void* l) {
    __builtin_amdgcn_global_load_lds(
        (const __attribute__((address_space(1))) void*)g,
        (__attribute__((address_space(3))) void*)l, 16, 0, 0);
}

template<int NT>
__device__ __forceinline__ float breduce_sum(float v, float* red) {
    const int tid = threadIdx.x;
    red[tid] = v; __syncthreads();
#pragma unroll
    for (int o = NT / 2; o > 0; o >>= 1) {
        if (tid < o) red[tid] += red[tid + o];
        __syncthreads();
    }
    float r = red[0]; __syncthreads();
    return r;
}
__device__ __forceinline__ double breduce_sum_d256(double v, double* red) {
    const int tid = threadIdx.x;
    red[tid] = v; __syncthreads();
#pragma unroll
    for (int o = 128; o > 0; o >>= 1) {
        if (tid < o) red[tid] += red[tid + o];
        __syncthreads();
    }
    double r = red[0]; __syncthreads();
    return r;
}

// ---------------------------------------------------------------------------
// Prep kernels
// ---------------------------------------------------------------------------
// transpose+convert: src [R][C] f32 -> dst [C][R] bf16
__global__ __launch_bounds__(256)
void transposeW_kernel(const float* __restrict__ src, int R, int C,
                       u16* __restrict__ dst) {
    __shared__ float t[32][33];
    const int c0 = blockIdx.x * 32, r0 = blockIdx.y * 32;
    const int tx = threadIdx.x & 31, ty = threadIdx.x >> 5;  // 32 x 8
#pragma unroll
    for (int i = 0; i < 32; i += 8)
        t[ty + i][tx] = src[(size_t)(r0 + ty + i) * C + c0 + tx];
    __syncthreads();
#pragma unroll
    for (int i = 0; i < 32; i += 8)
        dst[(size_t)(c0 + ty + i) * R + r0 + tx] = f2bf(t[tx][ty + i]);
}

__global__ __launch_bounds__(256)
void cvt_bf16_kernel(const float* __restrict__ src, u16* __restrict__ dst, int n8) {
    int i = blockIdx.x * 256 + threadIdx.x;
    const int stride = gridDim.x * 256;
    for (; i < n8; i += stride) {
        const float4* s = (const float4*)(src + (size_t)i * 8);
        float4 a = s[0], b = s[1];
        uint4 o;
        o.x = (u32)f2bf(a.x) | ((u32)f2bf(a.y) << 16);
        o.y = (u32)f2bf(a.z) | ((u32)f2bf(a.w) << 16);
        o.z = (u32)f2bf(b.x) | ((u32)f2bf(b.y) << 16);
        o.w = (u32)f2bf(b.z) | ((u32)f2bf(b.w) << 16);
        *(uint4*)(dst + (size_t)i * 8) = o;
    }
}

// q_bf16 = bf16(word_feat * vf)
__global__ __launch_bounds__(256)
void qmask_kernel(const float* __restrict__ wf, const int* __restrict__ wpos,
                  u16* __restrict__ dst, int n8) {
    int i = blockIdx.x * 256 + threadIdx.x;
    const int stride = gridDim.x * 256;
    for (; i < n8; i += stride) {
        int row = i / 96;
        float vf = (wpos[row] != -1) ? 1.f : 0.f;
        const float4* s = (const float4*)(wf + (size_t)i * 8);
        float4 a = s[0], b = s[1];
        uint4 o;
        o.x = (u32)f2bf(a.x * vf) | ((u32)f2bf(a.y * vf) << 16);
        o.y = (u32)f2bf(a.z * vf) | ((u32)f2bf(a.w * vf) << 16);
        o.z = (u32)f2bf(b.x * vf) | ((u32)f2bf(b.y * vf) << 16);
        o.w = (u32)f2bf(b.z * vf) | ((u32)f2bf(b.w * vf) << 16);
        *(uint4*)(dst + (size_t)i * 8) = o;
    }
}

__global__ __launch_bounds__(256)
void cpos_kernel(const int* __restrict__ wpos, int* __restrict__ cpos, int n) {
    int i = blockIdx.x * 256 + threadIdx.x;
    if (i < n) {
        int w = wpos[i];
        cpos[i] = w < 0 ? 0 : (w > LL - 1 ? LL - 1 : w);
    }
}

// clip_n bf16, row-major [256][768], rows 248..255 zero (B^T for logits GEMM)
__global__ __launch_bounds__(256)
void clipb_kernel(const float* __restrict__ pe, u16* __restrict__ clipb) {
    __shared__ float red[256];
    const int l = blockIdx.x, tid = threadIdx.x;
    if (l >= LL) {
        for (int j = 0; j < 3; ++j)
            clipb[(size_t)l * DD + tid + j * 256] = 0;
        return;
    }
    float t[3]; float q = 0.f;
#pragma unroll
    for (int j = 0; j < 3; ++j) {
        t[j] = pe[(size_t)l * DD + tid + j * 256];
        q = fmaf(t[j], t[j], q);
    }
    q = breduce_sum<256>(q, red);
    float inv = 1.f / fmaxf(sqrtf(q), 1e-12f);
#pragma unroll
    for (int j = 0; j < 3; ++j)
        clipb[(size_t)l * DD + tid + j * 256] = f2bf(t[j] * inv);
}

// ---------------------------------------------------------------------------
// bf16 MFMA GEMM (m97 structure): C[M,N] = A[M,K](bf16) @ Bt[N,K]^T(bf16) + bias
// ---------------------------------------------------------------------------
template<int GATHER, int CBF16, int MASK>
__global__ __launch_bounds__(256)
void gemm_bt(const u16* __restrict__ A,
             const u16* __restrict__ TXT,
             const int* __restrict__ cpos,
             const u16* __restrict__ Bt,
             const float* __restrict__ bias,
             void* __restrict__ Cout, int ldc, int K,
             const int* __restrict__ wpos) {
    __shared__ __align__(16) u16 Alds[128 * 32];
    __shared__ __align__(16) u16 Blds[128 * 32];
    const int tid = threadIdx.x;
    const int l = tid & 63, wv = tid >> 6;
    const int m0 = blockIdx.y * 128, n0 = blockIdx.x * 128;

    const int f0 = wv * 1024 + l * 16;
    const int f1 = f0 + 4096;
    const int rA0 = f0 >> 6, rA1 = f1 >> 6;
    const int cb0 = (f0 & 63) ^ (((rA0 >> 1) & 3) << 4);
    const int cb1 = (f1 & 63) ^ (((rA1 >> 1) & 3) << 4);
    const int c0e = cb0 >> 1, c1e = cb1 >> 1;

    u16* Ad0 = Alds + wv * 512;
    u16* Ad1 = Alds + 2048 + wv * 512;
    u16* Bd0 = Blds + wv * 512;
    u16* Bd1 = Blds + 2048 + wv * 512;

    const u16* pb0 = Bt + (size_t)(n0 + rA0) * K + c0e;
    const u16* pb1 = Bt + (size_t)(n0 + rA1) * K + c1e;

    const u16* pa0 = nullptr; const u16* pa1 = nullptr;
    int gb0 = 0, gb1 = 0, gc0 = 0, gc1 = 0;
    if constexpr (GATHER) {
        int g0 = m0 + rA0, g1 = m0 + rA1;
        gb0 = g0 >> 7; gb1 = g1 >> 7;
        gc0 = cpos[g0]; gc1 = cpos[g1];
    } else {
        pa0 = A + (size_t)(m0 + rA0) * K + c0e;
        pa1 = A + (size_t)(m0 + rA1) * K + c1e;
    }

    const int wm = (wv >> 1) * 64, wn = (wv & 1) * 64;
    const int la = l & 15, lg = l >> 4;

    int aoff[4], boff[4];
#pragma unroll
    for (int m = 0; m < 4; ++m) {
        int ra = wm + m * 16 + la;
        aoff[m] = ra * 32 + ((lg * 8) ^ (((ra >> 1) & 3) << 3));
        int rb = wn + m * 16 + la;
        boff[m] = rb * 32 + ((lg * 8) ^ (((rb >> 1) & 3) << 3));
    }

    f32x4 acc[4][4] = {};
    const int nk = K >> 5;
    for (int kt = 0; kt < nk; ++kt) {
        const int k0 = kt << 5;
        const u16 *ga0, *ga1;
        if constexpr (GATHER) {
            int w = k0 / DD;
            int kin = k0 - w * DD;
            int p0 = gc0 + w - 1; p0 = p0 < 0 ? 0 : (p0 > LL - 1 ? LL - 1 : p0);
            int p1 = gc1 + w - 1; p1 = p1 < 0 ? 0 : (p1 > LL - 1 ? LL - 1 : p1);
            ga0 = TXT + ((size_t)(gb0 * LL + p0)) * DD + kin + c0e;
            ga1 = TXT + ((size_t)(gb1 * LL + p1)) * DD + kin + c1e;
        } else {
            ga0 = pa0 + k0; ga1 = pa1 + k0;
        }
        gload16(ga0, Ad0);
        gload16(ga1, Ad1);
        gload16(pb0 + k0, Bd0);
        gload16(pb1 + k0, Bd1);
        __syncthreads();

        s16x8 af[4], bf[4];
#pragma unroll
        for (int m = 0; m < 4; ++m) af[m] = *(const s16x8*)(Alds + aoff[m]);
#pragma unroll
        for (int n = 0; n < 4; ++n) bf[n] = *(const s16x8*)(Blds + boff[n]);
#pragma unroll
        for (int m = 0; m < 4; ++m)
#pragma unroll
            for (int n = 0; n < 4; ++n)
                acc[m][n] = __builtin_amdgcn_mfma_f32_16x16x32_bf16(
                    af[m], bf[n], acc[m][n], 0, 0, 0);
        __syncthreads();
    }

#pragma unroll
    for (int m = 0; m < 4; ++m) {
        const int rb = m0 + wm + m * 16 + lg * 4;
        float vf[4];
        if constexpr (MASK) {
#pragma unroll
            for (int r = 0; r < 4; ++r) vf[r] = (wpos[rb + r] != -1) ? 1.f : 0.f;
        }
#pragma unroll
        for (int n = 0; n < 4; ++n) {
            const int col = n0 + wn + n * 16 + la;
            const float bv = bias[col];
#pragma unroll
            for (int r = 0; r < 4; ++r) {
                float o = acc[m][n][r] + bv;
                if constexpr (MASK) o *= vf[r];
                if constexpr (CBF16)
                    ((u16*)Cout)[(size_t)(rb + r) * ldc + col] = f2bf(o);
                else
                    ((float*)Cout)[(size_t)(rb + r) * ldc + col] = o;
            }
        }
    }
}

// ---------------------------------------------------------------------------
// MFMA attention: one block per (b,h), 512 threads = 8 waves, 16 q-rows/wave.
// K_lds [128][96] linear (192B rows: bank-even, global_load_lds staged).
// Vt_lds [96][128] transposed, XOR-swizzled byte^=((d&7)<<4).
// P_lds [128][128] bf16, XOR-swizzled byte^=((q&7)<<4), per-wave strips.
// ---------------------------------------------------------------------------
__global__ __launch_bounds__(512)
void attn_mfma_kernel(const u16* __restrict__ qp, const u16* __restrict__ kp,
                      const u16* __restrict__ vp, u16* __restrict__ ao) {
    __shared__ __align__(16) u16 K_lds[128 * 96];    // 24 KB
    __shared__ __align__(16) u16 Vt_lds[96 * 128];   // 24 KB
    __shared__ __align__(16) u16 P_lds[128 * 128];   // 32 KB
    const int bh = blockIdx.x;
    const int b = bh >> 3, h = bh & 7;
    const int tid = threadIdx.x;
    const int l = tid & 63, wv = tid >> 6;
    const int la = l & 15, lg = l >> 4;
    const float scale = 0.10206207261596575f;  // 1/sqrt(96)

    const size_t base = ((size_t)b * NN) * DD + h * HDh;

    // stage K: 3 issues/wave, linear dest (wave-uniform base + lane*16)
#pragma unroll
    for (int i = 0; i < 3; ++i) {
        int f = i * 8192 + wv * 1024 + l * 16;   // byte offset, 0..24575
        int row = f / 192;
        int inner = f - row * 192;
        gload16((const char*)(kp + base + (size_t)row * DD) + inner,
                (char*)K_lds + f);
    }

    // load V chunks (3 per thread) to regs
    uint4 vchunk[3]; int vkey[3], vd0[3];
#pragma unroll
    for (int i = 0; i < 3; ++i) {
        int c = tid + i * 512;          // 0..1535
        int key = c / 12, dc = c - key * 12;
        vkey[i] = key; vd0[i] = dc * 8;
        vchunk[i] = *(const uint4*)(vp + base + (size_t)key * DD + dc * 8);
    }

    // load Q A-frags (wave rows q0..q0+15, 3 k-steps)
    const int q0 = wv * 16;
    s16x8 qf[3];
#pragma unroll
    for (int kt = 0; kt < 3; ++kt)
        qf[kt] = *(const s16x8*)(qp + base + (size_t)(q0 + la) * DD + kt * 32 + lg * 8);

    // write Vt transposed + swizzled
#pragma unroll
    for (int i = 0; i < 3; ++i) {
        const u16* e = (const u16*)&vchunk[i];
#pragma unroll
        for (int j = 0; j < 8; ++j) {
            int d = vd0[i] + j;
            int byte = ((d * 128 + vkey[i]) * 2) ^ ((d & 7) << 4);
            *(u16*)((char*)Vt_lds + byte) = e[j];
        }
    }
    __syncthreads();   // K staged (vmcnt drained) + Vt complete

    // QK^T: S strip 16 x 128 per wave
    f32x4 sacc[8] = {};
#pragma unroll
    for (int kt = 0; kt < 3; ++kt) {
#pragma unroll
        for (int nf = 0; nf < 8; ++nf) {
            s16x8 bfr = *(const s16x8*)(K_lds + (nf * 16 + la) * 96 + kt * 32 + lg * 8);
            sacc[nf] = __builtin_amdgcn_mfma_f32_16x16x32_bf16(qf[kt], bfr, sacc[nf], 0, 0, 0);
        }
    }

    // softmax per row (rows lg*4+r within wave strip), then write P bf16
#pragma unroll
    for (int r = 0; r < 4; ++r) {
        float m = -1e30f;
#pragma unroll
        for (int nf = 0; nf < 8; ++nf) m = fmaxf(m, sacc[nf][r]);
#pragma unroll
        for (int o = 8; o > 0; o >>= 1) m = fmaxf(m, __shfl_xor(m, o, 64));
        m *= scale;
        float p[8]; float s = 0.f;
#pragma unroll
        for (int nf = 0; nf < 8; ++nf) { p[nf] = expf(sacc[nf][r] * scale - m); s += p[nf]; }
#pragma unroll
        for (int o = 8; o > 0; o >>= 1) s += __shfl_xor(s, o, 64);
        const float inv = 1.f / s;
        const int q = q0 + lg * 4 + r;
#pragma unroll
        for (int nf = 0; nf < 8; ++nf) {
            int byte = ((q * 128 + nf * 16 + la) * 2) ^ ((q & 7) << 4);
            *(u16*)((char*)P_lds + byte) = f2bf(p[nf] * inv);
        }
    }
    __syncthreads();   // P strips complete

    // PV: O strip 16 x 96
    f32x4 oacc[6] = {};
#pragma unroll
    for (int kk = 0; kk < 4; ++kk) {
        const int qrow = q0 + la;
        int abyte = ((qrow * 128 + kk * 32 + lg * 8) * 2) ^ ((qrow & 7) << 4);
        s16x8 af = *(const s16x8*)((char*)P_lds + abyte);
#pragma unroll
        for (int nf = 0; nf < 6; ++nf) {
            const int d = nf * 16 + la;
            int bbyte = ((d * 128 + kk * 32 + lg * 8) * 2) ^ ((d & 7) << 4);
            s16x8 bfr = *(const s16x8*)((char*)Vt_lds + bbyte);
            oacc[nf] = __builtin_amdgcn_mfma_f32_16x16x32_bf16(af, bfr, oacc[nf], 0, 0, 0);
        }
    }

    // epilogue
#pragma unroll
    for (int nf = 0; nf < 6; ++nf) {
#pragma unroll
        for (int r = 0; r < 4; ++r) {
            const int q = q0 + lg * 4 + r;
            ao[base + (size_t)q * DD + nf * 16 + la] = f2bf(oacc[nf][r]);
        }
    }
}

// ---------------------------------------------------------------------------
// x = layernorm(word_feat*vf + attn_out(bf16); cn_g, cn_b) * vf -> bf16
// ---------------------------------------------------------------------------
__global__ __launch_bounds__(256)
void ln768_kernel(const float* __restrict__ wf, const u16* __restrict__ at,
                  const int* __restrict__ wpos, const float* __restrict__ g,
                  const float* __restrict__ bta, u16* __restrict__ xout) {
    __shared__ float red[256];
    const int r = blockIdx.x, tid = threadIdx.x;
    const float vf = (wpos[r] != -1) ? 1.f : 0.f;
    float t[3]; float s = 0.f, q = 0.f;
#pragma unroll
    for (int j = 0; j < 3; ++j) {
        int d = tid + j * 256;
        t[j] = wf[(size_t)r * DD + d] * vf + bf2f(at[(size_t)r * DD + d]);
        s += t[j];
        q = fmaf(t[j], t[j], q);
    }
    s = breduce_sum<256>(s, red);
    q = breduce_sum<256>(q, red);
    float mean = s * (1.f / DD);
    float var  = q * (1.f / DD) - mean * mean;
    float inv  = 1.f / sqrtf(var + 1e-5f);
#pragma unroll
    for (int j = 0; j < 3; ++j) {
        int d = tid + j * 256;
        xout[(size_t)r * DD + d] = f2bf(((t[j] - mean) * inv * g[d] + bta[d]) * vf);
    }
}

// ---------------------------------------------------------------------------
// h = layernorm(gelu_exact(g1); ln_g, ln_b) -> bf16      (row = 256)
// ---------------------------------------------------------------------------
__global__ __launch_bounds__(256)
void ln256_gelu_kernel(const float* __restrict__ g1, const float* __restrict__ lg,
                       const float* __restrict__ lb, u16* __restrict__ hout) {
    __shared__ float red[256];
    const int r = blockIdx.x, tid = threadIdx.x;
    float v  = g1[(size_t)r * HIDN + tid];
    float ge = 0.5f * v * (1.f + erff(v * 0.7071067811865475f));
    float s = breduce_sum<256>(ge, red);
    float q = breduce_sum<256>(ge * ge, red);
    float mean = s * (1.f / HIDN);
    float var  = q * (1.f / HIDN) - mean * mean;
    float inv  = 1.f / sqrtf(var + 1e-5f);
    hout[(size_t)r * HIDN + tid] = f2bf((ge - mean) * inv * lg[tid] + lb[tid]);
}

// ---------------------------------------------------------------------------
// L2-normalize rows of 768 IN PLACE + emit bf16 copy
// ---------------------------------------------------------------------------
__global__ __launch_bounds__(256)
void norm768_kernel(float* __restrict__ buf, u16* __restrict__ outb) {
    __shared__ float red[256];
    const int r = blockIdx.x, tid = threadIdx.x;
    float t[3]; float q = 0.f;
#pragma unroll
    for (int j = 0; j < 3; ++j) {
        t[j] = buf[(size_t)r * DD + tid + j * 256];
        q = fmaf(t[j], t[j], q);
    }
    q = breduce_sum<256>(q, red);
    float inv = 1.f / fmaxf(sqrtf(q), 1e-12f);
#pragma unroll
    for (int j = 0; j < 3; ++j) {
        float v = t[j] * inv;
        buf[(size_t)r * DD + tid + j * 256] = v;
        outb[(size_t)r * DD + tid + j * 256] = f2bf(v);
    }
}

// ---------------------------------------------------------------------------
// KL from precomputed logits. One WAVE per row, 4 rows/block.
// ---------------------------------------------------------------------------
__global__ __launch_bounds__(256)
void kl_lite_kernel(const float* __restrict__ logits, const int* __restrict__ wpos,
                    const float* __restrict__ pos_temp, float* __restrict__ klp) {
    const int row = blockIdx.x * 4 + (threadIdx.x >> 6);
    const int l = threadIdx.x & 63;
    const float invt = 1.f / fmaxf(pos_temp[0], 0.001f);
    const float* lrow = logits + (size_t)row * 256;

    float lg[4];
#pragma unroll
    for (int q = 0; q < 4; ++q) {
        int c = l + q * 64;
        lg[q] = (c < LL) ? lrow[c] * invt : -1e30f;
    }
    float m = fmaxf(fmaxf(lg[0], lg[1]), fmaxf(lg[2], lg[3]));
#pragma unroll
    for (int o = 32; o > 0; o >>= 1) m = fmaxf(m, __shfl_xor(m, o, 64));

    float S = 0.f;
#pragma unroll
    for (int q = 0; q < 4; ++q) S += expf(lg[q] - m);
#pragma unroll
    for (int o = 32; o > 0; o >>= 1) S += __shfl_xor(S, o, 64);
    const float logZ = m + logf(S);

    const int wr = wpos[row];
    const bool valid = (wr != -1);
    const int wp = wr < 0 ? 0 : (wr > LL - 1 ? LL - 1 : wr);

    float targ[4]; float tsum = 0.f;
#pragma unroll
    for (int q = 0; q < 4; ++q) {
        int c = l + q * 64;
        float dl = (float)c - (float)wp;
        targ[q] = (c < LL) ? expf(-dl * dl * 0.125f) : 0.f;
        tsum += targ[q];
    }
#pragma unroll
    for (int o = 32; o > 0; o >>= 1) tsum += __shfl_xor(tsum, o, 64);
    const float tden = 1.f / (tsum + 1e-12f);

    float c_ = 0.f;
#pragma unroll
    for (int q = 0; q < 4; ++q) {
        float tn = targ[q] * tden;
        if (valid && tn > 0.f) c_ += tn * (logf(tn) - (lg[q] - logZ));
    }
#pragma unroll
    for (int o = 32; o > 0; o >>= 1) c_ += __shfl_xor(c_, o, 64);
    if (l == 0) klp[row] = c_;
}

// ---------------------------------------------------------------------------
// rel head: one block per (b, 16-row tile). 256 threads.
// ---------------------------------------------------------------------------
__global__ __launch_bounds__(256)
void rel_kernel(const float* __restrict__ rope_n, const int* __restrict__ wpos,
                float* __restrict__ rel_part, float* __restrict__ vm2_part) {
    __shared__ __align__(16) float ri[16][768];   // 48 KB
    __shared__ float red[256];
    const int blk = blockIdx.x;
    const int b = blk >> 3, i0 = (blk & 7) * 16;
    const int t = threadIdx.x;

    for (int e = t; e < 16 * 768; e += 256) {
        int ii = e / 768, d = e - ii * 768;
        ri[ii][d] = rope_n[((size_t)(b * NN + i0 + ii)) * DD + d];
    }
    __syncthreads();

    const int j = t & 127;
    const int g0 = t >> 7;
    const float4* rj = (const float4*)(rope_n + ((size_t)(b * NN + j)) * DD);

    float dot[8];
#pragma unroll
    for (int q = 0; q < 8; ++q) dot[q] = 0.f;
    for (int d4 = 0; d4 < 192; ++d4) {
        float4 v = rj[d4];
#pragma unroll
        for (int q = 0; q < 8; ++q) {
            const float4 rv = *(const float4*)&ri[g0 + q * 2][d4 * 4];
            dot[q] = fmaf(rv.x, v.x, dot[q]);
            dot[q] = fmaf(rv.y, v.y, dot[q]);
            dot[q] = fmaf(rv.z, v.z, dot[q]);
            dot[q] = fmaf(rv.w, v.w, dot[q]);
        }
    }

    int wj = wpos[b * NN + j];
    bool vj = (wj != -1);
    float wjf = (float)(wj < 0 ? 0 : (wj > LL - 1 ? LL - 1 : wj));

    float csum = 0.f, msum = 0.f;
#pragma unroll
    for (int q = 0; q < 8; ++q) {
        int ii = g0 + q * 2;
        int wi = wpos[b * NN + i0 + ii];
        bool vi = (wi != -1);
        float wif = (float)(wi < 0 ? 0 : (wi > LL - 1 ? LL - 1 : wi));
        float sim = (dot[q] + 1.f) * 0.5f;
        float ts  = 1.f - fabsf(wif - wjf) * (1.f / (float)LL);
        float m2  = (vi && vj) ? 1.f : 0.f;
        float df  = m2 * (sim - ts);
        csum += df * df;
        msum += m2;
    }
    csum = breduce_sum<256>(csum, red);
    msum = breduce_sum<256>(msum, red);
    if (t == 0) { rel_part[blk] = csum; vm2_part[blk] = msum; }
}

// ---------------------------------------------------------------------------
// scatter: emb[b, wp, :] = 0.8*pos_emb[wp] + 0.2*rope[b,n]   (valid only)
// ---------------------------------------------------------------------------
__global__ __launch_bounds__(256)
void scatter_kernel(const float* __restrict__ pe, const float* __restrict__ rope,
                    const int* __restrict__ wpos, float* __restrict__ emb) {
    const int r = blockIdx.x, tid = threadIdx.x;
    int wr = wpos[r];
    if (wr == -1) return;
    int wp = wr < 0 ? 0 : (wr > LL - 1 ? LL - 1 : wr);
    int b = r >> 7;
    for (int d = tid; d < DD; d += 256)
        emb[((size_t)b * LL + wp) * DD + d] =
            0.8f * pe[(size_t)wp * DD + d] + 0.2f * rope[(size_t)r * DD + d];
}

// ---------------------------------------------------------------------------
// Final deterministic fp64 reduction
// ---------------------------------------------------------------------------
__global__ __launch_bounds__(256)
void final_kernel(const float* __restrict__ klp, const float* __restrict__ relp,
                  const float* __restrict__ vmp, const int* __restrict__ wpos,
                  float* __restrict__ outs) {
    __shared__ double rd[256];
    const int tid = threadIdx.x;
    double kl = 0.0, rel = 0.0, vm = 0.0, nv = 0.0;
    for (int r = tid; r < MROWS; r += 256) {
        kl += (double)klp[r];
        nv += (wpos[r] != -1) ? 1.0 : 0.0;
    }
    for (int r = tid; r < 1024; r += 256) {
        rel += (double)relp[r];
        vm  += (double)vmp[r];
    }
    kl  = breduce_sum_d256(kl, rd);
    rel = breduce_sum_d256(rel, rd);
    vm  = breduce_sum_d256(vm, rd);
    nv  = breduce_sum_d256(nv, rd);
    if (tid == 0) {
        float klf  = (float)(kl / (nv + 1e-12));
        float relf = (float)(rel / (vm + 1e-12));
        outs[0] = klf + 0.5f * relf;
        outs[1] = klf;
        outs[2] = relf;
    }
}

// ---------------------------------------------------------------------------
extern "C" void kernel_launch(void* const* d_in, const int* in_sizes, int n_in,
                              void* d_out, int out_size, void* d_ws, size_t ws_size,
                              hipStream_t stream) {
    (void)in_sizes; (void)n_in; (void)ws_size;

    const float* word_feat = (const float*)d_in[0];
    const float* text      = (const float*)d_in[1];
    const int*   wpos      = (const int*)d_in[2];
    const float* ctx_W     = (const float*)d_in[3];
    const float* ctx_b     = (const float*)d_in[4];
    const float* in_W      = (const float*)d_in[5];
    const float* in_b      = (const float*)d_in[6];
    const float* out_W     = (const float*)d_in[7];
    const float* out_b     = (const float*)d_in[8];
    const float* cn_g      = (const float*)d_in[9];
    const float* cn_b      = (const float*)d_in[10];
    const float* r1_W      = (const float*)d_in[11];
    const float* r1_b      = (const float*)d_in[12];
    const float* ln_g      = (const float*)d_in[13];
    const float* ln_b      = (const float*)d_in[14];
    const float* r2_W      = (const float*)d_in[15];
    const float* r2_b      = (const float*)d_in[16];
    const float* pos_emb   = (const float*)d_in[17];
    const float* pos_temp  = (const float*)d_in[18];

    char* W = (char*)d_ws;
    u16*   ctx_Wt = (u16*)(W);
    u16*   in_Wt  = ctx_Wt + (size_t)768 * 2304;
    u16*   out_Wt = in_Wt  + (size_t)2304 * 768;
    u16*   r1_Wt  = out_Wt + (size_t)768 * 768;
    u16*   r2_Wt  = r1_Wt  + (size_t)256 * 768;
    u16*   clipb  = r2_Wt + (size_t)768 * 256;          // [256][768] bf16
    int*   cposb  = (int*)(clipb + (size_t)256 * DD);
    float* klp    = (float*)(cposb + MROWS);
    float* relp   = klp + MROWS;
    float* vmp    = relp + 1024;
    float* zbias  = vmp + 1024;                          // 256 zero floats
    // --- big regions ---
    u16*   textb  = (u16*)(W + (size_t)12 * MB_);
    u16*   xb     = textb;
    u16*   hb     = (u16*)(W + (size_t)38 * MB_);
    u16*   ctxa   = (u16*)(W + (size_t)62 * MB_);
    u16*   aob    = ctxa;
    u16*   rnb    = ctxa;
    u16*   qb     = (u16*)(W + (size_t)88 * MB_);
    u16*   atoutb = qb;
    float* logits = (float*)qb;
    u16*   qpb    = (u16*)(W + (size_t)114 * MB_);
    u16*   kpb    = qpb + (size_t)MROWS * DD;
    u16*   vpb    = kpb + (size_t)MROWS * DD;
    float* g1     = (float*)(W + (size_t)114 * MB_);
    float* rope   = (float*)(W + (size_t)140 * MB_);

    hipMemsetAsync(d_out, 0, (size_t)out_size * sizeof(float), stream);
    hipMemsetAsync(zbias, 0, 256 * sizeof(float), stream);

    dim3 blk(256);

    transposeW_kernel<<<dim3(768/32, 2304/32), blk, 0, stream>>>(ctx_W, 2304, 768, ctx_Wt);
    transposeW_kernel<<<dim3(2304/32, 768/32), blk, 0, stream>>>(in_W, 768, 2304, in_Wt);
    transposeW_kernel<<<dim3(768/32, 768/32),  blk, 0, stream>>>(out_W, 768, 768, out_Wt);
    transposeW_kernel<<<dim3(256/32, 768/32),  blk, 0, stream>>>(r1_W, 768, 256, r1_Wt);
    transposeW_kernel<<<dim3(768/32, 256/32),  blk, 0, stream>>>(r2_W, 256, 768, r2_Wt);
    cvt_bf16_kernel<<<dim3(2048), blk, 0, stream>>>(text, textb, BB * LL * DD / 8);
    qmask_kernel<<<dim3(2048), blk, 0, stream>>>(word_feat, wpos, qb, MROWS * DD / 8);
    cpos_kernel<<<dim3(64), blk, 0, stream>>>(wpos, cposb, MROWS);
    clipb_kernel<<<dim3(256), blk, 0, stream>>>(pos_emb, clipb);

    dim3 g768(6, 128);
    dim3 g256(2, 128);

    // 1. ctx_anchor
    gemm_bt<1, 1, 1><<<g768, blk, 0, stream>>>(
        nullptr, textb, cposb, ctx_Wt, ctx_b, ctxa, DD, 3 * DD, wpos);
    // 2. qp
    gemm_bt<0, 1, 0><<<g768, blk, 0, stream>>>(
        qb, nullptr, nullptr, in_Wt, in_b, qpb, DD, DD, nullptr);
    // 3. kp
    gemm_bt<0, 1, 0><<<g768, blk, 0, stream>>>(
        ctxa, nullptr, nullptr, in_Wt + (size_t)768 * 768, in_b + DD, kpb, DD, DD, nullptr);
    // 4. vp
    gemm_bt<0, 1, 0><<<g768, blk, 0, stream>>>(
        ctxa, nullptr, nullptr, in_Wt + (size_t)1536 * 768, in_b + 2 * DD, vpb, DD, DD, nullptr);
    // 5. MFMA attention -> ao (overwrites ctx_anchor region)
    attn_mfma_kernel<<<dim3(BB * HH), dim3(512), 0, stream>>>(qpb, kpb, vpb, aob);
    // 6. attn_out = ao @ out_W + out_b (overwrites q region)
    gemm_bt<0, 1, 0><<<g768, blk, 0, stream>>>(
        aob, nullptr, nullptr, out_Wt, out_b, atoutb, DD, DD, nullptr);
    // 7. x = LN(word_feat*vf + attn_out)*vf (overwrites text region)
    ln768_kernel<<<dim3(MROWS), blk, 0, stream>>>(word_feat, atoutb, wpos, cn_g, cn_b, xb);
    // 8. g1 = x @ r1_W + r1_b
    gemm_bt<0, 0, 0><<<g256, blk, 0, stream>>>(
        xb, nullptr, nullptr, r1_Wt, r1_b, g1, HIDN, DD, nullptr);
    // 9. h = LN(gelu(g1))
    ln256_gelu_kernel<<<dim3(MROWS), blk, 0, stream>>>(g1, ln_g, ln_b, hb);
    // 10. rope = h @ r2_W + r2_b
    gemm_bt<0, 0, 0><<<g768, blk, 0, stream>>>(
        hb, nullptr, nullptr, r2_Wt, r2_b, rope, DD, HIDN, nullptr);
    // 11. scatter emb (raw rope) BEFORE normalize
    scatter_kernel<<<dim3(MROWS), blk, 0, stream>>>(pos_emb, rope, wpos, (float*)d_out);
    // 12. rope -> rope_n in place + bf16 copy
    norm768_kernel<<<dim3(MROWS), blk, 0, stream>>>(rope, rnb);
    // 13. logits = rope_n_bf16 @ clip_n^T
    gemm_bt<0, 0, 0><<<g256, blk, 0, stream>>>(
        rnb, nullptr, nullptr, clipb, zbias, logits, 256, DD, nullptr);
    // 14. KL from logits
    kl_lite_kernel<<<dim3(MROWS / 4), blk, 0, stream>>>(logits, wpos, pos_temp, klp);
    // 15. rel per (b, 16-row tile)
    rel_kernel<<<dim3(BB * 8), blk, 0, stream>>>(rope, wpos, relp, vmp);
    // 16. scalars
    final_kernel<<<dim3(1), blk, 0, stream>>>(
        klp, relp, vmp, wpos, (float*)d_out + (size_t)BB * LL * DD);
}

// Round 5
// 543.401 us; speedup vs baseline: 6.8061x; 1.2701x over previous
//
#include <hip/hip_runtime.h>
#include <math.h>

// Problem constants
#define BB   128
#define NN   128
#define LL   248
#define DD   768
#define HH   8
#define HDh  96
#define HIDN 256
#define MROWS (BB*NN)   // 16384
#define MB_   (1u<<20)

typedef unsigned short u16;
typedef unsigned int   u32;
typedef __attribute__((ext_vector_type(8))) short s16x8;
typedef __attribute__((ext_vector_type(4))) float f32x4;

// ---------------------------------------------------------------------------
// helpers
// ---------------------------------------------------------------------------
__device__ __forceinline__ u16 f2bf(float x) {
    u32 u = __float_as_uint(x);
    u32 r = u + 0x7fffu + ((u >> 16) & 1u);
    return (u16)(r >> 16);
}
__device__ __forceinline__ float bf2f(u16 h) {
    return __uint_as_float(((u32)h) << 16);
}
__device__ __forceinline__ void gload16(const void* g, void* l) {
    __builtin_amdgcn_global_load_lds(
        (const __attribute__((address_space(1))) void*)g,
        (__attribute__((address_space(3))) void*)l, 16, 0, 0);
}

template<int NT>
__device__ __forceinline__ float breduce_sum(float v, float* red) {
    const int tid = threadIdx.x;
    red[tid] = v; __syncthreads();
#pragma unroll
    for (int o = NT / 2; o > 0; o >>= 1) {
        if (tid < o) red[tid] += red[tid + o];
        __syncthreads();
    }
    float r = red[0]; __syncthreads();
    return r;
}
__device__ __forceinline__ double breduce_sum_d256(double v, double* red) {
    const int tid = threadIdx.x;
    red[tid] = v; __syncthreads();
#pragma unroll
    for (int o = 128; o > 0; o >>= 1) {
        if (tid < o) red[tid] += red[tid + o];
        __syncthreads();
    }
    double r = red[0]; __syncthreads();
    return r;
}

// ---------------------------------------------------------------------------
// Prep kernels
// ---------------------------------------------------------------------------
// transpose+convert: src [R][C] f32 -> dst [C][R] bf16
__global__ __launch_bounds__(256)
void transposeW_kernel(const float* __restrict__ src, int R, int C,
                       u16* __restrict__ dst) {
    __shared__ float t[32][33];
    const int c0 = blockIdx.x * 32, r0 = blockIdx.y * 32;
    const int tx = threadIdx.x & 31, ty = threadIdx.x >> 5;  // 32 x 8
#pragma unroll
    for (int i = 0; i < 32; i += 8)
        t[ty + i][tx] = src[(size_t)(r0 + ty + i) * C + c0 + tx];
    __syncthreads();
#pragma unroll
    for (int i = 0; i < 32; i += 8)
        dst[(size_t)(c0 + ty + i) * R + r0 + tx] = f2bf(t[tx][ty + i]);
}

__global__ __launch_bounds__(256)
void cvt_bf16_kernel(const float* __restrict__ src, u16* __restrict__ dst, int n8) {
    int i = blockIdx.x * 256 + threadIdx.x;
    const int stride = gridDim.x * 256;
    for (; i < n8; i += stride) {
        const float4* s = (const float4*)(src + (size_t)i * 8);
        float4 a = s[0], b = s[1];
        uint4 o;
        o.x = (u32)f2bf(a.x) | ((u32)f2bf(a.y) << 16);
        o.y = (u32)f2bf(a.z) | ((u32)f2bf(a.w) << 16);
        o.z = (u32)f2bf(b.x) | ((u32)f2bf(b.y) << 16);
        o.w = (u32)f2bf(b.z) | ((u32)f2bf(b.w) << 16);
        *(uint4*)(dst + (size_t)i * 8) = o;
    }
}

// q_bf16 = bf16(word_feat * vf)
__global__ __launch_bounds__(256)
void qmask_kernel(const float* __restrict__ wf, const int* __restrict__ wpos,
                  u16* __restrict__ dst, int n8) {
    int i = blockIdx.x * 256 + threadIdx.x;
    const int stride = gridDim.x * 256;
    for (; i < n8; i += stride) {
        int row = i / 96;
        float vf = (wpos[row] != -1) ? 1.f : 0.f;
        const float4* s = (const float4*)(wf + (size_t)i * 8);
        float4 a = s[0], b = s[1];
        uint4 o;
        o.x = (u32)f2bf(a.x * vf) | ((u32)f2bf(a.y * vf) << 16);
        o.y = (u32)f2bf(a.z * vf) | ((u32)f2bf(a.w * vf) << 16);
        o.z = (u32)f2bf(b.x * vf) | ((u32)f2bf(b.y * vf) << 16);
        o.w = (u32)f2bf(b.z * vf) | ((u32)f2bf(b.w * vf) << 16);
        *(uint4*)(dst + (size_t)i * 8) = o;
    }
}

__global__ __launch_bounds__(256)
void cpos_kernel(const int* __restrict__ wpos, int* __restrict__ cpos, int n) {
    int i = blockIdx.x * 256 + threadIdx.x;
    if (i < n) {
        int w = wpos[i];
        cpos[i] = w < 0 ? 0 : (w > LL - 1 ? LL - 1 : w);
    }
}

// clip_n bf16, row-major [256][768], rows 248..255 zero (B^T for logits GEMM)
__global__ __launch_bounds__(256)
void clipb_kernel(const float* __restrict__ pe, u16* __restrict__ clipb) {
    __shared__ float red[256];
    const int l = blockIdx.x, tid = threadIdx.x;
    if (l >= LL) {
        for (int j = 0; j < 3; ++j)
            clipb[(size_t)l * DD + tid + j * 256] = 0;
        return;
    }
    float t[3]; float q = 0.f;
#pragma unroll
    for (int j = 0; j < 3; ++j) {
        t[j] = pe[(size_t)l * DD + tid + j * 256];
        q = fmaf(t[j], t[j], q);
    }
    q = breduce_sum<256>(q, red);
    float inv = 1.f / fmaxf(sqrtf(q), 1e-12f);
#pragma unroll
    for (int j = 0; j < 3; ++j)
        clipb[(size_t)l * DD + tid + j * 256] = f2bf(t[j] * inv);
}

// ---------------------------------------------------------------------------
// bf16 MFMA GEMM (m97 structure): C[M,N] = A[M,K](bf16) @ Bt[N,K]^T(bf16) + bias
// ---------------------------------------------------------------------------
template<int GATHER, int CBF16, int MASK>
__global__ __launch_bounds__(256)
void gemm_bt(const u16* __restrict__ A,
             const u16* __restrict__ TXT,
             const int* __restrict__ cpos,
             const u16* __restrict__ Bt,
             const float* __restrict__ bias,
             void* __restrict__ Cout, int ldc, int K,
             const int* __restrict__ wpos) {
    __shared__ __align__(16) u16 Alds[128 * 32];
    __shared__ __align__(16) u16 Blds[128 * 32];
    const int tid = threadIdx.x;
    const int l = tid & 63, wv = tid >> 6;
    const int m0 = blockIdx.y * 128, n0 = blockIdx.x * 128;

    const int f0 = wv * 1024 + l * 16;
    const int f1 = f0 + 4096;
    const int rA0 = f0 >> 6, rA1 = f1 >> 6;
    const int cb0 = (f0 & 63) ^ (((rA0 >> 1) & 3) << 4);
    const int cb1 = (f1 & 63) ^ (((rA1 >> 1) & 3) << 4);
    const int c0e = cb0 >> 1, c1e = cb1 >> 1;

    u16* Ad0 = Alds + wv * 512;
    u16* Ad1 = Alds + 2048 + wv * 512;
    u16* Bd0 = Blds + wv * 512;
    u16* Bd1 = Blds + 2048 + wv * 512;

    const u16* pb0 = Bt + (size_t)(n0 + rA0) * K + c0e;
    const u16* pb1 = Bt + (size_t)(n0 + rA1) * K + c1e;

    const u16* pa0 = nullptr; const u16* pa1 = nullptr;
    int gb0 = 0, gb1 = 0, gc0 = 0, gc1 = 0;
    if constexpr (GATHER) {
        int g0 = m0 + rA0, g1 = m0 + rA1;
        gb0 = g0 >> 7; gb1 = g1 >> 7;
        gc0 = cpos[g0]; gc1 = cpos[g1];
    } else {
        pa0 = A + (size_t)(m0 + rA0) * K + c0e;
        pa1 = A + (size_t)(m0 + rA1) * K + c1e;
    }

    const int wm = (wv >> 1) * 64, wn = (wv & 1) * 64;
    const int la = l & 15, lg = l >> 4;

    int aoff[4], boff[4];
#pragma unroll
    for (int m = 0; m < 4; ++m) {
        int ra = wm + m * 16 + la;
        aoff[m] = ra * 32 + ((lg * 8) ^ (((ra >> 1) & 3) << 3));
        int rb = wn + m * 16 + la;
        boff[m] = rb * 32 + ((lg * 8) ^ (((rb >> 1) & 3) << 3));
    }

    f32x4 acc[4][4] = {};
    const int nk = K >> 5;
    for (int kt = 0; kt < nk; ++kt) {
        const int k0 = kt << 5;
        const u16 *ga0, *ga1;
        if constexpr (GATHER) {
            int w = k0 / DD;
            int kin = k0 - w * DD;
            int p0 = gc0 + w - 1; p0 = p0 < 0 ? 0 : (p0 > LL - 1 ? LL - 1 : p0);
            int p1 = gc1 + w - 1; p1 = p1 < 0 ? 0 : (p1 > LL - 1 ? LL - 1 : p1);
            ga0 = TXT + ((size_t)(gb0 * LL + p0)) * DD + kin + c0e;
            ga1 = TXT + ((size_t)(gb1 * LL + p1)) * DD + kin + c1e;
        } else {
            ga0 = pa0 + k0; ga1 = pa1 + k0;
        }
        gload16(ga0, Ad0);
        gload16(ga1, Ad1);
        gload16(pb0 + k0, Bd0);
        gload16(pb1 + k0, Bd1);
        __syncthreads();

        s16x8 af[4], bf[4];
#pragma unroll
        for (int m = 0; m < 4; ++m) af[m] = *(const s16x8*)(Alds + aoff[m]);
#pragma unroll
        for (int n = 0; n < 4; ++n) bf[n] = *(const s16x8*)(Blds + boff[n]);
#pragma unroll
        for (int m = 0; m < 4; ++m)
#pragma unroll
            for (int n = 0; n < 4; ++n)
                acc[m][n] = __builtin_amdgcn_mfma_f32_16x16x32_bf16(
                    af[m], bf[n], acc[m][n], 0, 0, 0);
        __syncthreads();
    }

#pragma unroll
    for (int m = 0; m < 4; ++m) {
        const int rb = m0 + wm + m * 16 + lg * 4;
        float vf[4];
        if constexpr (MASK) {
#pragma unroll
            for (int r = 0; r < 4; ++r) vf[r] = (wpos[rb + r] != -1) ? 1.f : 0.f;
        }
#pragma unroll
        for (int n = 0; n < 4; ++n) {
            const int col = n0 + wn + n * 16 + la;
            const float bv = bias[col];
#pragma unroll
            for (int r = 0; r < 4; ++r) {
                float o = acc[m][n][r] + bv;
                if constexpr (MASK) o *= vf[r];
                if constexpr (CBF16)
                    ((u16*)Cout)[(size_t)(rb + r) * ldc + col] = f2bf(o);
                else
                    ((float*)Cout)[(size_t)(rb + r) * ldc + col] = o;
            }
        }
    }
}

// ---------------------------------------------------------------------------
// MFMA attention: one block per (b,h), 512 threads = 8 waves, 16 q-rows/wave.
// ---------------------------------------------------------------------------
__global__ __launch_bounds__(512)
void attn_mfma_kernel(const u16* __restrict__ qp, const u16* __restrict__ kp,
                      const u16* __restrict__ vp, u16* __restrict__ ao) {
    __shared__ __align__(16) u16 K_lds[128 * 96];    // 24 KB
    __shared__ __align__(16) u16 Vt_lds[96 * 128];   // 24 KB
    __shared__ __align__(16) u16 P_lds[128 * 128];   // 32 KB
    const int bh = blockIdx.x;
    const int b = bh >> 3, h = bh & 7;
    const int tid = threadIdx.x;
    const int l = tid & 63, wv = tid >> 6;
    const int la = l & 15, lg = l >> 4;
    const float scale = 0.10206207261596575f;  // 1/sqrt(96)

    const size_t base = ((size_t)b * NN) * DD + h * HDh;

#pragma unroll
    for (int i = 0; i < 3; ++i) {
        int f = i * 8192 + wv * 1024 + l * 16;
        int row = f / 192;
        int inner = f - row * 192;
        gload16((const char*)(kp + base + (size_t)row * DD) + inner,
                (char*)K_lds + f);
    }

    uint4 vchunk[3]; int vkey[3], vd0[3];
#pragma unroll
    for (int i = 0; i < 3; ++i) {
        int c = tid + i * 512;
        int key = c / 12, dc = c - key * 12;
        vkey[i] = key; vd0[i] = dc * 8;
        vchunk[i] = *(const uint4*)(vp + base + (size_t)key * DD + dc * 8);
    }

    const int q0 = wv * 16;
    s16x8 qf[3];
#pragma unroll
    for (int kt = 0; kt < 3; ++kt)
        qf[kt] = *(const s16x8*)(qp + base + (size_t)(q0 + la) * DD + kt * 32 + lg * 8);

#pragma unroll
    for (int i = 0; i < 3; ++i) {
        const u16* e = (const u16*)&vchunk[i];
#pragma unroll
        for (int j = 0; j < 8; ++j) {
            int d = vd0[i] + j;
            int byte = ((d * 128 + vkey[i]) * 2) ^ ((d & 7) << 4);
            *(u16*)((char*)Vt_lds + byte) = e[j];
        }
    }
    __syncthreads();

    f32x4 sacc[8] = {};
#pragma unroll
    for (int kt = 0; kt < 3; ++kt) {
#pragma unroll
        for (int nf = 0; nf < 8; ++nf) {
            s16x8 bfr = *(const s16x8*)(K_lds + (nf * 16 + la) * 96 + kt * 32 + lg * 8);
            sacc[nf] = __builtin_amdgcn_mfma_f32_16x16x32_bf16(qf[kt], bfr, sacc[nf], 0, 0, 0);
        }
    }

#pragma unroll
    for (int r = 0; r < 4; ++r) {
        float m = -1e30f;
#pragma unroll
        for (int nf = 0; nf < 8; ++nf) m = fmaxf(m, sacc[nf][r]);
#pragma unroll
        for (int o = 8; o > 0; o >>= 1) m = fmaxf(m, __shfl_xor(m, o, 64));
        m *= scale;
        float p[8]; float s = 0.f;
#pragma unroll
        for (int nf = 0; nf < 8; ++nf) { p[nf] = expf(sacc[nf][r] * scale - m); s += p[nf]; }
#pragma unroll
        for (int o = 8; o > 0; o >>= 1) s += __shfl_xor(s, o, 64);
        const float inv = 1.f / s;
        const int q = q0 + lg * 4 + r;
#pragma unroll
        for (int nf = 0; nf < 8; ++nf) {
            int byte = ((q * 128 + nf * 16 + la) * 2) ^ ((q & 7) << 4);
            *(u16*)((char*)P_lds + byte) = f2bf(p[nf] * inv);
        }
    }
    __syncthreads();

    f32x4 oacc[6] = {};
#pragma unroll
    for (int kk = 0; kk < 4; ++kk) {
        const int qrow = q0 + la;
        int abyte = ((qrow * 128 + kk * 32 + lg * 8) * 2) ^ ((qrow & 7) << 4);
        s16x8 af = *(const s16x8*)((char*)P_lds + abyte);
#pragma unroll
        for (int nf = 0; nf < 6; ++nf) {
            const int d = nf * 16 + la;
            int bbyte = ((d * 128 + kk * 32 + lg * 8) * 2) ^ ((d & 7) << 4);
            s16x8 bfr = *(const s16x8*)((char*)Vt_lds + bbyte);
            oacc[nf] = __builtin_amdgcn_mfma_f32_16x16x32_bf16(af, bfr, oacc[nf], 0, 0, 0);
        }
    }

#pragma unroll
    for (int nf = 0; nf < 6; ++nf) {
#pragma unroll
        for (int r = 0; r < 4; ++r) {
            const int q = q0 + lg * 4 + r;
            ao[base + (size_t)q * DD + nf * 16 + la] = f2bf(oacc[nf][r]);
        }
    }
}

// ---------------------------------------------------------------------------
// x = layernorm(word_feat*vf + attn_out(bf16); cn_g, cn_b) * vf -> bf16
// ---------------------------------------------------------------------------
__global__ __launch_bounds__(256)
void ln768_kernel(const float* __restrict__ wf, const u16* __restrict__ at,
                  const int* __restrict__ wpos, const float* __restrict__ g,
                  const float* __restrict__ bta, u16* __restrict__ xout) {
    __shared__ float red[256];
    const int r = blockIdx.x, tid = threadIdx.x;
    const float vf = (wpos[r] != -1) ? 1.f : 0.f;
    float t[3]; float s = 0.f, q = 0.f;
#pragma unroll
    for (int j = 0; j < 3; ++j) {
        int d = tid + j * 256;
        t[j] = wf[(size_t)r * DD + d] * vf + bf2f(at[(size_t)r * DD + d]);
        s += t[j];
        q = fmaf(t[j], t[j], q);
    }
    s = breduce_sum<256>(s, red);
    q = breduce_sum<256>(q, red);
    float mean = s * (1.f / DD);
    float var  = q * (1.f / DD) - mean * mean;
    float inv  = 1.f / sqrtf(var + 1e-5f);
#pragma unroll
    for (int j = 0; j < 3; ++j) {
        int d = tid + j * 256;
        xout[(size_t)r * DD + d] = f2bf(((t[j] - mean) * inv * g[d] + bta[d]) * vf);
    }
}

// ---------------------------------------------------------------------------
// h = layernorm(gelu_exact(g1); ln_g, ln_b) -> bf16      (row = 256)
// ---------------------------------------------------------------------------
__global__ __launch_bounds__(256)
void ln256_gelu_kernel(const float* __restrict__ g1, const float* __restrict__ lg,
                       const float* __restrict__ lb, u16* __restrict__ hout) {
    __shared__ float red[256];
    const int r = blockIdx.x, tid = threadIdx.x;
    float v  = g1[(size_t)r * HIDN + tid];
    float ge = 0.5f * v * (1.f + erff(v * 0.7071067811865475f));
    float s = breduce_sum<256>(ge, red);
    float q = breduce_sum<256>(ge * ge, red);
    float mean = s * (1.f / HIDN);
    float var  = q * (1.f / HIDN) - mean * mean;
    float inv  = 1.f / sqrtf(var + 1e-5f);
    hout[(size_t)r * HIDN + tid] = f2bf((ge - mean) * inv * lg[tid] + lb[tid]);
}

// ---------------------------------------------------------------------------
// L2-normalize rows of 768 IN PLACE + emit bf16 copy
// ---------------------------------------------------------------------------
__global__ __launch_bounds__(256)
void norm768_kernel(float* __restrict__ buf, u16* __restrict__ outb) {
    __shared__ float red[256];
    const int r = blockIdx.x, tid = threadIdx.x;
    float t[3]; float q = 0.f;
#pragma unroll
    for (int j = 0; j < 3; ++j) {
        t[j] = buf[(size_t)r * DD + tid + j * 256];
        q = fmaf(t[j], t[j], q);
    }
    q = breduce_sum<256>(q, red);
    float inv = 1.f / fmaxf(sqrtf(q), 1e-12f);
#pragma unroll
    for (int j = 0; j < 3; ++j) {
        float v = t[j] * inv;
        buf[(size_t)r * DD + tid + j * 256] = v;
        outb[(size_t)r * DD + tid + j * 256] = f2bf(v);
    }
}

// ---------------------------------------------------------------------------
// KL from precomputed logits. One WAVE per row, 4 rows/block.
// ---------------------------------------------------------------------------
__global__ __launch_bounds__(256)
void kl_lite_kernel(const float* __restrict__ logits, const int* __restrict__ wpos,
                    const float* __restrict__ pos_temp, float* __restrict__ klp) {
    const int row = blockIdx.x * 4 + (threadIdx.x >> 6);
    const int l = threadIdx.x & 63;
    const float invt = 1.f / fmaxf(pos_temp[0], 0.001f);
    const float* lrow = logits + (size_t)row * 256;

    float lg[4];
#pragma unroll
    for (int q = 0; q < 4; ++q) {
        int c = l + q * 64;
        lg[q] = (c < LL) ? lrow[c] * invt : -1e30f;
    }
    float m = fmaxf(fmaxf(lg[0], lg[1]), fmaxf(lg[2], lg[3]));
#pragma unroll
    for (int o = 32; o > 0; o >>= 1) m = fmaxf(m, __shfl_xor(m, o, 64));

    float S = 0.f;
#pragma unroll
    for (int q = 0; q < 4; ++q) S += expf(lg[q] - m);
#pragma unroll
    for (int o = 32; o > 0; o >>= 1) S += __shfl_xor(S, o, 64);
    const float logZ = m + logf(S);

    const int wr = wpos[row];
    const bool valid = (wr != -1);
    const int wp = wr < 0 ? 0 : (wr > LL - 1 ? LL - 1 : wr);

    float targ[4]; float tsum = 0.f;
#pragma unroll
    for (int q = 0; q < 4; ++q) {
        int c = l + q * 64;
        float dl = (float)c - (float)wp;
        targ[q] = (c < LL) ? expf(-dl * dl * 0.125f) : 0.f;
        tsum += targ[q];
    }
#pragma unroll
    for (int o = 32; o > 0; o >>= 1) tsum += __shfl_xor(tsum, o, 64);
    const float tden = 1.f / (tsum + 1e-12f);

    float c_ = 0.f;
#pragma unroll
    for (int q = 0; q < 4; ++q) {
        float tn = targ[q] * tden;
        if (valid && tn > 0.f) c_ += tn * (logf(tn) - (lg[q] - logZ));
    }
#pragma unroll
    for (int o = 32; o > 0; o >>= 1) c_ += __shfl_xor(c_, o, 64);
    if (l == 0) klp[row] = c_;
}

// ---------------------------------------------------------------------------
// rel head via MFMA: one block per (b, j-half). 512 threads = 8 waves.
// Gram strip: A rows = all 128 batch rows (wave wv owns rows wv*16..+15),
// B cols = 64 rows of the j-half. K staged [128][32] bf16, gemm_bt swizzle.
// ---------------------------------------------------------------------------
__global__ __launch_bounds__(512)
void rel_mfma_kernel(const u16* __restrict__ rnb, const int* __restrict__ wpos,
                     float* __restrict__ rel_part, float* __restrict__ vm2_part) {
    __shared__ __align__(16) u16 T[128 * 32];   // 8 KB
    __shared__ float red[512];
    const int blk = blockIdx.x;
    const int b = blk >> 1, jh = blk & 1;
    const int tid = threadIdx.x;
    const int l = tid & 63, wv = tid >> 6;
    const int la = l & 15, lg = l >> 4;

    // staging geometry (inverse-swizzled source, linear LDS dest)
    const int f = wv * 1024 + l * 16;      // bytes, covers 8 KB with 512 thr
    const int rA = f >> 6;
    const int cb = (f & 63) ^ (((rA >> 1) & 3) << 4);
    const int ce = cb >> 1;
    const u16* src = rnb + ((size_t)(b * NN + rA)) * DD + ce;
    u16* dst = T + wv * 512;               // wave-uniform base (+ lane*16 by HW)

    // fragment offsets (swizzled ds_read)
    const int ra = wv * 16 + la;
    const int aoff = ra * 32 + ((lg * 8) ^ (((ra >> 1) & 3) << 3));
    int boff[4];
#pragma unroll
    for (int nf = 0; nf < 4; ++nf) {
        int rb = jh * 64 + nf * 16 + la;
        boff[nf] = rb * 32 + ((lg * 8) ^ (((rb >> 1) & 3) << 3));
    }

    f32x4 acc[4] = {};
    for (int kt = 0; kt < 24; ++kt) {
        gload16(src + kt * 32, dst);
        __syncthreads();
        s16x8 a = *(const s16x8*)(T + aoff);
        s16x8 bf_[4];
#pragma unroll
        for (int nf = 0; nf < 4; ++nf) bf_[nf] = *(const s16x8*)(T + boff[nf]);
#pragma unroll
        for (int nf = 0; nf < 4; ++nf)
            acc[nf] = __builtin_amdgcn_mfma_f32_16x16x32_bf16(a, bf_[nf], acc[nf], 0, 0, 0);
        __syncthreads();
    }

    // C frag: row i = wv*16 + lg*4 + r, col j = jh*64 + nf*16 + la
    float wif[4], vi[4];
#pragma unroll
    for (int r = 0; r < 4; ++r) {
        int wi = wpos[b * NN + wv * 16 + lg * 4 + r];
        vi[r] = (wi != -1) ? 1.f : 0.f;
        wif[r] = (float)(wi < 0 ? 0 : (wi > LL - 1 ? LL - 1 : wi));
    }
    float csum = 0.f, msum = 0.f;
#pragma unroll
    for (int nf = 0; nf < 4; ++nf) {
        int wj = wpos[b * NN + jh * 64 + nf * 16 + la];
        float vj = (wj != -1) ? 1.f : 0.f;
        float wjf = (float)(wj < 0 ? 0 : (wj > LL - 1 ? LL - 1 : wj));
#pragma unroll
        for (int r = 0; r < 4; ++r) {
            float sim = (acc[nf][r] + 1.f) * 0.5f;
            float ts  = 1.f - fabsf(wif[r] - wjf) * (1.f / (float)LL);
            float m2  = vi[r] * vj;
            float df  = m2 * (sim - ts);
            csum += df * df;
            msum += m2;
        }
    }
    csum = breduce_sum<512>(csum, red);
    msum = breduce_sum<512>(msum, red);
    if (tid == 0) { rel_part[blk] = csum; vm2_part[blk] = msum; }
}

// ---------------------------------------------------------------------------
// scatter: emb[b, wp, :] = 0.8*pos_emb[wp] + 0.2*rope[b,n]   (valid only)
// ---------------------------------------------------------------------------
__global__ __launch_bounds__(256)
void scatter_kernel(const float* __restrict__ pe, const float* __restrict__ rope,
                    const int* __restrict__ wpos, float* __restrict__ emb) {
    const int r = blockIdx.x, tid = threadIdx.x;
    int wr = wpos[r];
    if (wr == -1) return;
    int wp = wr < 0 ? 0 : (wr > LL - 1 ? LL - 1 : wr);
    int b = r >> 7;
    for (int d = tid; d < DD; d += 256)
        emb[((size_t)b * LL + wp) * DD + d] =
            0.8f * pe[(size_t)wp * DD + d] + 0.2f * rope[(size_t)r * DD + d];
}

// ---------------------------------------------------------------------------
// Final deterministic fp64 reduction
// ---------------------------------------------------------------------------
__global__ __launch_bounds__(256)
void final_kernel(const float* __restrict__ klp, const float* __restrict__ relp,
                  const float* __restrict__ vmp, const int* __restrict__ wpos,
                  float* __restrict__ outs) {
    __shared__ double rd[256];
    const int tid = threadIdx.x;
    double kl = 0.0, rel = 0.0, vm = 0.0, nv = 0.0;
    for (int r = tid; r < MROWS; r += 256) {
        kl += (double)klp[r];
        nv += (wpos[r] != -1) ? 1.0 : 0.0;
    }
    if (tid < 256) {
        rel += (double)relp[tid];
        vm  += (double)vmp[tid];
    }
    kl  = breduce_sum_d256(kl, rd);
    rel = breduce_sum_d256(rel, rd);
    vm  = breduce_sum_d256(vm, rd);
    nv  = breduce_sum_d256(nv, rd);
    if (tid == 0) {
        float klf  = (float)(kl / (nv + 1e-12));
        float relf = (float)(rel / (vm + 1e-12));
        outs[0] = klf + 0.5f * relf;
        outs[1] = klf;
        outs[2] = relf;
    }
}

// ---------------------------------------------------------------------------
extern "C" void kernel_launch(void* const* d_in, const int* in_sizes, int n_in,
                              void* d_out, int out_size, void* d_ws, size_t ws_size,
                              hipStream_t stream) {
    (void)in_sizes; (void)n_in; (void)ws_size;

    const float* word_feat = (const float*)d_in[0];
    const float* text      = (const float*)d_in[1];
    const int*   wpos      = (const int*)d_in[2];
    const float* ctx_W     = (const float*)d_in[3];
    const float* ctx_b     = (const float*)d_in[4];
    const float* in_W      = (const float*)d_in[5];
    const float* in_b      = (const float*)d_in[6];
    const float* out_W     = (const float*)d_in[7];
    const float* out_b     = (const float*)d_in[8];
    const float* cn_g      = (const float*)d_in[9];
    const float* cn_b      = (const float*)d_in[10];
    const float* r1_W      = (const float*)d_in[11];
    const float* r1_b      = (const float*)d_in[12];
    const float* ln_g      = (const float*)d_in[13];
    const float* ln_b      = (const float*)d_in[14];
    const float* r2_W      = (const float*)d_in[15];
    const float* r2_b      = (const float*)d_in[16];
    const float* pos_emb   = (const float*)d_in[17];
    const float* pos_temp  = (const float*)d_in[18];

    char* W = (char*)d_ws;
    u16*   ctx_Wt = (u16*)(W);
    u16*   in_Wt  = ctx_Wt + (size_t)768 * 2304;
    u16*   out_Wt = in_Wt  + (size_t)2304 * 768;
    u16*   r1_Wt  = out_Wt + (size_t)768 * 768;
    u16*   r2_Wt  = r1_Wt  + (size_t)256 * 768;
    u16*   clipb  = r2_Wt + (size_t)768 * 256;          // [256][768] bf16
    int*   cposb  = (int*)(clipb + (size_t)256 * DD);
    float* klp    = (float*)(cposb + MROWS);
    float* relp   = klp + MROWS;
    float* vmp    = relp + 256;
    float* zbias  = vmp + 256;                           // 256 zero floats
    // --- big regions ---
    u16*   textb  = (u16*)(W + (size_t)12 * MB_);
    u16*   xb     = textb;
    u16*   hb     = (u16*)(W + (size_t)38 * MB_);
    u16*   ctxa   = (u16*)(W + (size_t)62 * MB_);
    u16*   aob    = ctxa;
    u16*   rnb    = ctxa;
    u16*   qb     = (u16*)(W + (size_t)88 * MB_);
    u16*   atoutb = qb;
    float* logits = (float*)qb;
    u16*   qpb    = (u16*)(W + (size_t)114 * MB_);
    u16*   kpb    = qpb + (size_t)MROWS * DD;
    u16*   vpb    = kpb + (size_t)MROWS * DD;
    float* g1     = (float*)(W + (size_t)114 * MB_);
    float* rope   = (float*)(W + (size_t)140 * MB_);

    hipMemsetAsync(d_out, 0, (size_t)out_size * sizeof(float), stream);
    hipMemsetAsync(zbias, 0, 256 * sizeof(float), stream);

    dim3 blk(256);

    transposeW_kernel<<<dim3(768/32, 2304/32), blk, 0, stream>>>(ctx_W, 2304, 768, ctx_Wt);
    transposeW_kernel<<<dim3(2304/32, 768/32), blk, 0, stream>>>(in_W, 768, 2304, in_Wt);
    transposeW_kernel<<<dim3(768/32, 768/32),  blk, 0, stream>>>(out_W, 768, 768, out_Wt);
    transposeW_kernel<<<dim3(256/32, 768/32),  blk, 0, stream>>>(r1_W, 768, 256, r1_Wt);
    transposeW_kernel<<<dim3(768/32, 256/32),  blk, 0, stream>>>(r2_W, 256, 768, r2_Wt);
    cvt_bf16_kernel<<<dim3(2048), blk, 0, stream>>>(text, textb, BB * LL * DD / 8);
    qmask_kernel<<<dim3(2048), blk, 0, stream>>>(word_feat, wpos, qb, MROWS * DD / 8);
    cpos_kernel<<<dim3(64), blk, 0, stream>>>(wpos, cposb, MROWS);
    clipb_kernel<<<dim3(256), blk, 0, stream>>>(pos_emb, clipb);

    dim3 g768(6, 128);
    dim3 g256(2, 128);

    // 1. ctx_anchor
    gemm_bt<1, 1, 1><<<g768, blk, 0, stream>>>(
        nullptr, textb, cposb, ctx_Wt, ctx_b, ctxa, DD, 3 * DD, wpos);
    // 2. qp
    gemm_bt<0, 1, 0><<<g768, blk, 0, stream>>>(
        qb, nullptr, nullptr, in_Wt, in_b, qpb, DD, DD, nullptr);
    // 3. kp
    gemm_bt<0, 1, 0><<<g768, blk, 0, stream>>>(
        ctxa, nullptr, nullptr, in_Wt + (size_t)768 * 768, in_b + DD, kpb, DD, DD, nullptr);
    // 4. vp
    gemm_bt<0, 1, 0><<<g768, blk, 0, stream>>>(
        ctxa, nullptr, nullptr, in_Wt + (size_t)1536 * 768, in_b + 2 * DD, vpb, DD, DD, nullptr);
    // 5. MFMA attention -> ao (overwrites ctx_anchor region)
    attn_mfma_kernel<<<dim3(BB * HH), dim3(512), 0, stream>>>(qpb, kpb, vpb, aob);
    // 6. attn_out = ao @ out_W + out_b (overwrites q region)
    gemm_bt<0, 1, 0><<<g768, blk, 0, stream>>>(
        aob, nullptr, nullptr, out_Wt, out_b, atoutb, DD, DD, nullptr);
    // 7. x = LN(word_feat*vf + attn_out)*vf (overwrites text region)
    ln768_kernel<<<dim3(MROWS), blk, 0, stream>>>(word_feat, atoutb, wpos, cn_g, cn_b, xb);
    // 8. g1 = x @ r1_W + r1_b
    gemm_bt<0, 0, 0><<<g256, blk, 0, stream>>>(
        xb, nullptr, nullptr, r1_Wt, r1_b, g1, HIDN, DD, nullptr);
    // 9. h = LN(gelu(g1))
    ln256_gelu_kernel<<<dim3(MROWS), blk, 0, stream>>>(g1, ln_g, ln_b, hb);
    // 10. rope = h @ r2_W + r2_b
    gemm_bt<0, 0, 0><<<g768, blk, 0, stream>>>(
        hb, nullptr, nullptr, r2_Wt, r2_b, rope, DD, HIDN, nullptr);
    // 11. scatter emb (raw rope) BEFORE normalize
    scatter_kernel<<<dim3(MROWS), blk, 0, stream>>>(pos_emb, rope, wpos, (float*)d_out);
    // 12. rope -> rope_n in place + bf16 copy (overwrites ao region)
    norm768_kernel<<<dim3(MROWS), blk, 0, stream>>>(rope, rnb);
    // 13. logits = rope_n_bf16 @ clip_n^T
    gemm_bt<0, 0, 0><<<g256, blk, 0, stream>>>(
        rnb, nullptr, nullptr, clipb, zbias, logits, 256, DD, nullptr);
    // 14. KL from logits
    kl_lite_kernel<<<dim3(MROWS / 4), blk, 0, stream>>>(logits, wpos, pos_temp, klp);
    // 15. rel via MFMA Gram (uses rnb bf16)
    rel_mfma_kernel<<<dim3(BB * 2), dim3(512), 0, stream>>>(rnb, wpos, relp, vmp);
    // 16. scalars
    final_kernel<<<dim3(1), blk, 0, stream>>>(
        klp, relp, vmp, wpos, (float*)d_out + (size_t)BB * LL * DD);
}

// Round 6
// 504.156 us; speedup vs baseline: 7.3358x; 1.0778x over previous
//
#include <hip/hip_runtime.h>
#include <math.h>

// Problem constants
#define BB   128
#define NN   128
#define LL   248
#define DD   768
#define HH   8
#define HDh  96
#define HIDN 256
#define MROWS (BB*NN)   // 16384
#define MB_   (1u<<20)
#define KVLD 1536       // fused K|V row stride (elements)

typedef unsigned short u16;
typedef unsigned int   u32;
typedef __attribute__((ext_vector_type(8))) short s16x8;
typedef __attribute__((ext_vector_type(4))) float f32x4;

// ---------------------------------------------------------------------------
// helpers
// ---------------------------------------------------------------------------
__device__ __forceinline__ u16 f2bf(float x) {
    u32 u = __float_as_uint(x);
    u32 r = u + 0x7fffu + ((u >> 16) & 1u);
    return (u16)(r >> 16);
}
__device__ __forceinline__ float bf2f(u16 h) {
    return __uint_as_float(((u32)h) << 16);
}
__device__ __forceinline__ void gload16(const void* g, void* l) {
    __builtin_amdgcn_global_load_lds(
        (const __attribute__((address_space(1))) void*)g,
        (__attribute__((address_space(3))) void*)l, 16, 0, 0);
}

template<int NT>
__device__ __forceinline__ float breduce_sum(float v, float* red) {
    const int tid = threadIdx.x;
    red[tid] = v; __syncthreads();
#pragma unroll
    for (int o = NT / 2; o > 0; o >>= 1) {
        if (tid < o) red[tid] += red[tid + o];
        __syncthreads();
    }
    float r = red[0]; __syncthreads();
    return r;
}
__device__ __forceinline__ double breduce_sum_d256(double v, double* red) {
    const int tid = threadIdx.x;
    red[tid] = v; __syncthreads();
#pragma unroll
    for (int o = 128; o > 0; o >>= 1) {
        if (tid < o) red[tid] += red[tid + o];
        __syncthreads();
    }
    double r = red[0]; __syncthreads();
    return r;
}

// ---------------------------------------------------------------------------
// Prep kernels
// ---------------------------------------------------------------------------
__global__ __launch_bounds__(256)
void transposeW_kernel(const float* __restrict__ src, int R, int C,
                       u16* __restrict__ dst) {
    __shared__ float t[32][33];
    const int c0 = blockIdx.x * 32, r0 = blockIdx.y * 32;
    const int tx = threadIdx.x & 31, ty = threadIdx.x >> 5;  // 32 x 8
#pragma unroll
    for (int i = 0; i < 32; i += 8)
        t[ty + i][tx] = src[(size_t)(r0 + ty + i) * C + c0 + tx];
    __syncthreads();
#pragma unroll
    for (int i = 0; i < 32; i += 8)
        dst[(size_t)(c0 + ty + i) * R + r0 + tx] = f2bf(t[tx][ty + i]);
}

__global__ __launch_bounds__(256)
void cvt_bf16_kernel(const float* __restrict__ src, u16* __restrict__ dst, int n8) {
    int i = blockIdx.x * 256 + threadIdx.x;
    const int stride = gridDim.x * 256;
    for (; i < n8; i += stride) {
        const float4* s = (const float4*)(src + (size_t)i * 8);
        float4 a = s[0], b = s[1];
        uint4 o;
        o.x = (u32)f2bf(a.x) | ((u32)f2bf(a.y) << 16);
        o.y = (u32)f2bf(a.z) | ((u32)f2bf(a.w) << 16);
        o.z = (u32)f2bf(b.x) | ((u32)f2bf(b.y) << 16);
        o.w = (u32)f2bf(b.z) | ((u32)f2bf(b.w) << 16);
        *(uint4*)(dst + (size_t)i * 8) = o;
    }
}

__global__ __launch_bounds__(256)
void qmask_kernel(const float* __restrict__ wf, const int* __restrict__ wpos,
                  u16* __restrict__ dst, int n8) {
    int i = blockIdx.x * 256 + threadIdx.x;
    const int stride = gridDim.x * 256;
    for (; i < n8; i += stride) {
        int row = i / 96;
        float vf = (wpos[row] != -1) ? 1.f : 0.f;
        const float4* s = (const float4*)(wf + (size_t)i * 8);
        float4 a = s[0], b = s[1];
        uint4 o;
        o.x = (u32)f2bf(a.x * vf) | ((u32)f2bf(a.y * vf) << 16);
        o.y = (u32)f2bf(a.z * vf) | ((u32)f2bf(a.w * vf) << 16);
        o.z = (u32)f2bf(b.x * vf) | ((u32)f2bf(b.y * vf) << 16);
        o.w = (u32)f2bf(b.z * vf) | ((u32)f2bf(b.w * vf) << 16);
        *(uint4*)(dst + (size_t)i * 8) = o;
    }
}

__global__ __launch_bounds__(256)
void cpos_kernel(const int* __restrict__ wpos, int* __restrict__ cpos, int n) {
    int i = blockIdx.x * 256 + threadIdx.x;
    if (i < n) {
        int w = wpos[i];
        cpos[i] = w < 0 ? 0 : (w > LL - 1 ? LL - 1 : w);
    }
}

__global__ __launch_bounds__(256)
void clipb_kernel(const float* __restrict__ pe, u16* __restrict__ clipb) {
    __shared__ float red[256];
    const int l = blockIdx.x, tid = threadIdx.x;
    if (l >= LL) {
        for (int j = 0; j < 3; ++j)
            clipb[(size_t)l * DD + tid + j * 256] = 0;
        return;
    }
    float t[3]; float q = 0.f;
#pragma unroll
    for (int j = 0; j < 3; ++j) {
        t[j] = pe[(size_t)l * DD + tid + j * 256];
        q = fmaf(t[j], t[j], q);
    }
    q = breduce_sum<256>(q, red);
    float inv = 1.f / fmaxf(sqrtf(q), 1e-12f);
#pragma unroll
    for (int j = 0; j < 3; ++j)
        clipb[(size_t)l * DD + tid + j * 256] = f2bf(t[j] * inv);
}

// ---------------------------------------------------------------------------
// bf16 MFMA GEMM (m97 structure) + XCD-aware block swizzle (T1):
// blocks sharing an A-panel (same m0) land contiguously on ONE XCD.
// ---------------------------------------------------------------------------
template<int GATHER, int CBF16, int MASK>
__global__ __launch_bounds__(256)
void gemm_bt(const u16* __restrict__ A,
             const u16* __restrict__ TXT,
             const int* __restrict__ cpos,
             const u16* __restrict__ Bt,
             const float* __restrict__ bias,
             void* __restrict__ Cout, int ldc, int K,
             const int* __restrict__ wpos) {
    __shared__ __align__(16) u16 Alds[128 * 32];
    __shared__ __align__(16) u16 Blds[128 * 32];
    const int tid = threadIdx.x;
    const int l = tid & 63, wv = tid >> 6;

    // XCD swizzle: hw -> (xcd chunk, slot); same-m0 blocks contiguous per XCD.
    const int gx  = gridDim.x;
    const int hw  = blockIdx.y * gx + blockIdx.x;
    const int nwg = gx * gridDim.y;
    const int cpx = nwg >> 3;
    const int lin = (hw & 7) * cpx + (hw >> 3);
    const int m0 = (lin / gx) * 128, n0 = (lin % gx) * 128;

    const int f0 = wv * 1024 + l * 16;
    const int f1 = f0 + 4096;
    const int rA0 = f0 >> 6, rA1 = f1 >> 6;
    const int cb0 = (f0 & 63) ^ (((rA0 >> 1) & 3) << 4);
    const int cb1 = (f1 & 63) ^ (((rA1 >> 1) & 3) << 4);
    const int c0e = cb0 >> 1, c1e = cb1 >> 1;

    u16* Ad0 = Alds + wv * 512;
    u16* Ad1 = Alds + 2048 + wv * 512;
    u16* Bd0 = Blds + wv * 512;
    u16* Bd1 = Blds + 2048 + wv * 512;

    const u16* pb0 = Bt + (size_t)(n0 + rA0) * K + c0e;
    const u16* pb1 = Bt + (size_t)(n0 + rA1) * K + c1e;

    const u16* pa0 = nullptr; const u16* pa1 = nullptr;
    int gb0 = 0, gb1 = 0, gc0 = 0, gc1 = 0;
    if constexpr (GATHER) {
        int g0 = m0 + rA0, g1 = m0 + rA1;
        gb0 = g0 >> 7; gb1 = g1 >> 7;
        gc0 = cpos[g0]; gc1 = cpos[g1];
    } else {
        pa0 = A + (size_t)(m0 + rA0) * K + c0e;
        pa1 = A + (size_t)(m0 + rA1) * K + c1e;
    }

    const int wm = (wv >> 1) * 64, wn = (wv & 1) * 64;
    const int la = l & 15, lg = l >> 4;

    int aoff[4], boff[4];
#pragma unroll
    for (int m = 0; m < 4; ++m) {
        int ra = wm + m * 16 + la;
        aoff[m] = ra * 32 + ((lg * 8) ^ (((ra >> 1) & 3) << 3));
        int rb = wn + m * 16 + la;
        boff[m] = rb * 32 + ((lg * 8) ^ (((rb >> 1) & 3) << 3));
    }

    f32x4 acc[4][4] = {};
    const int nk = K >> 5;
    for (int kt = 0; kt < nk; ++kt) {
        const int k0 = kt << 5;
        const u16 *ga0, *ga1;
        if constexpr (GATHER) {
            int w = k0 / DD;
            int kin = k0 - w * DD;
            int p0 = gc0 + w - 1; p0 = p0 < 0 ? 0 : (p0 > LL - 1 ? LL - 1 : p0);
            int p1 = gc1 + w - 1; p1 = p1 < 0 ? 0 : (p1 > LL - 1 ? LL - 1 : p1);
            ga0 = TXT + ((size_t)(gb0 * LL + p0)) * DD + kin + c0e;
            ga1 = TXT + ((size_t)(gb1 * LL + p1)) * DD + kin + c1e;
        } else {
            ga0 = pa0 + k0; ga1 = pa1 + k0;
        }
        gload16(ga0, Ad0);
        gload16(ga1, Ad1);
        gload16(pb0 + k0, Bd0);
        gload16(pb1 + k0, Bd1);
        __syncthreads();

        s16x8 af[4], bf[4];
#pragma unroll
        for (int m = 0; m < 4; ++m) af[m] = *(const s16x8*)(Alds + aoff[m]);
#pragma unroll
        for (int n = 0; n < 4; ++n) bf[n] = *(const s16x8*)(Blds + boff[n]);
#pragma unroll
        for (int m = 0; m < 4; ++m)
#pragma unroll
            for (int n = 0; n < 4; ++n)
                acc[m][n] = __builtin_amdgcn_mfma_f32_16x16x32_bf16(
                    af[m], bf[n], acc[m][n], 0, 0, 0);
        __syncthreads();
    }

#pragma unroll
    for (int m = 0; m < 4; ++m) {
        const int rb = m0 + wm + m * 16 + lg * 4;
        float vf[4];
        if constexpr (MASK) {
#pragma unroll
            for (int r = 0; r < 4; ++r) vf[r] = (wpos[rb + r] != -1) ? 1.f : 0.f;
        }
#pragma unroll
        for (int n = 0; n < 4; ++n) {
            const int col = n0 + wn + n * 16 + la;
            const float bv = bias[col];
#pragma unroll
            for (int r = 0; r < 4; ++r) {
                float o = acc[m][n][r] + bv;
                if constexpr (MASK) o *= vf[r];
                if constexpr (CBF16)
                    ((u16*)Cout)[(size_t)(rb + r) * ldc + col] = f2bf(o);
                else
                    ((float*)Cout)[(size_t)(rb + r) * ldc + col] = o;
            }
        }
    }
}

// ---------------------------------------------------------------------------
// MFMA attention: one block per (b,h), 512 threads = 8 waves, 16 q-rows/wave.
// K and V come from the FUSED kv buffer: row stride KVLD, K at cols [0,768),
// V at cols [768,1536); per-head offset h*96.
// ---------------------------------------------------------------------------
__global__ __launch_bounds__(512)
void attn_mfma_kernel(const u16* __restrict__ qp, const u16* __restrict__ kvb,
                      u16* __restrict__ ao) {
    __shared__ __align__(16) u16 K_lds[128 * 96];    // 24 KB
    __shared__ __align__(16) u16 Vt_lds[96 * 128];   // 24 KB
    __shared__ __align__(16) u16 P_lds[128 * 128];   // 32 KB
    const int bh = blockIdx.x;
    const int b = bh >> 3, h = bh & 7;
    const int tid = threadIdx.x;
    const int l = tid & 63, wv = tid >> 6;
    const int la = l & 15, lg = l >> 4;
    const float scale = 0.10206207261596575f;  // 1/sqrt(96)

    const size_t qbase  = ((size_t)b * NN) * DD + h * HDh;
    const size_t kvbase = ((size_t)b * NN) * KVLD + h * HDh;

    // stage K: 3 issues/wave, linear dest
#pragma unroll
    for (int i = 0; i < 3; ++i) {
        int f = i * 8192 + wv * 1024 + l * 16;
        int row = f / 192;
        int inner = f - row * 192;
        gload16((const char*)(kvb + kvbase + (size_t)row * KVLD) + inner,
                (char*)K_lds + f);
    }

    // load V chunks (3 per thread) to regs
    uint4 vchunk[3]; int vkey[3], vd0[3];
#pragma unroll
    for (int i = 0; i < 3; ++i) {
        int c = tid + i * 512;
        int key = c / 12, dc = c - key * 12;
        vkey[i] = key; vd0[i] = dc * 8;
        vchunk[i] = *(const uint4*)(kvb + kvbase + (size_t)key * KVLD + DD + dc * 8);
    }

    const int q0 = wv * 16;
    s16x8 qf[3];
#pragma unroll
    for (int kt = 0; kt < 3; ++kt)
        qf[kt] = *(const s16x8*)(qp + qbase + (size_t)(q0 + la) * DD + kt * 32 + lg * 8);

#pragma unroll
    for (int i = 0; i < 3; ++i) {
        const u16* e = (const u16*)&vchunk[i];
#pragma unroll
        for (int j = 0; j < 8; ++j) {
            int d = vd0[i] + j;
            int byte = ((d * 128 + vkey[i]) * 2) ^ ((d & 7) << 4);
            *(u16*)((char*)Vt_lds + byte) = e[j];
        }
    }
    __syncthreads();

    f32x4 sacc[8] = {};
#pragma unroll
    for (int kt = 0; kt < 3; ++kt) {
#pragma unroll
        for (int nf = 0; nf < 8; ++nf) {
            s16x8 bfr = *(const s16x8*)(K_lds + (nf * 16 + la) * 96 + kt * 32 + lg * 8);
            sacc[nf] = __builtin_amdgcn_mfma_f32_16x16x32_bf16(qf[kt], bfr, sacc[nf], 0, 0, 0);
        }
    }

#pragma unroll
    for (int r = 0; r < 4; ++r) {
        float m = -1e30f;
#pragma unroll
        for (int nf = 0; nf < 8; ++nf) m = fmaxf(m, sacc[nf][r]);
#pragma unroll
        for (int o = 8; o > 0; o >>= 1) m = fmaxf(m, __shfl_xor(m, o, 64));
        m *= scale;
        float p[8]; float s = 0.f;
#pragma unroll
        for (int nf = 0; nf < 8; ++nf) { p[nf] = expf(sacc[nf][r] * scale - m); s += p[nf]; }
#pragma unroll
        for (int o = 8; o > 0; o >>= 1) s += __shfl_xor(s, o, 64);
        const float inv = 1.f / s;
        const int q = q0 + lg * 4 + r;
#pragma unroll
        for (int nf = 0; nf < 8; ++nf) {
            int byte = ((q * 128 + nf * 16 + la) * 2) ^ ((q & 7) << 4);
            *(u16*)((char*)P_lds + byte) = f2bf(p[nf] * inv);
        }
    }
    __syncthreads();

    f32x4 oacc[6] = {};
#pragma unroll
    for (int kk = 0; kk < 4; ++kk) {
        const int qrow = q0 + la;
        int abyte = ((qrow * 128 + kk * 32 + lg * 8) * 2) ^ ((qrow & 7) << 4);
        s16x8 af = *(const s16x8*)((char*)P_lds + abyte);
#pragma unroll
        for (int nf = 0; nf < 6; ++nf) {
            const int d = nf * 16 + la;
            int bbyte = ((d * 128 + kk * 32 + lg * 8) * 2) ^ ((d & 7) << 4);
            s16x8 bfr = *(const s16x8*)((char*)Vt_lds + bbyte);
            oacc[nf] = __builtin_amdgcn_mfma_f32_16x16x32_bf16(af, bfr, oacc[nf], 0, 0, 0);
        }
    }

#pragma unroll
    for (int nf = 0; nf < 6; ++nf) {
#pragma unroll
        for (int r = 0; r < 4; ++r) {
            const int q = q0 + lg * 4 + r;
            ao[qbase + (size_t)q * DD + nf * 16 + la] = f2bf(oacc[nf][r]);
        }
    }
}

// ---------------------------------------------------------------------------
// x = layernorm(word_feat*vf + attn_out(bf16); cn_g, cn_b) * vf -> bf16
// ---------------------------------------------------------------------------
__global__ __launch_bounds__(256)
void ln768_kernel(const float* __restrict__ wf, const u16* __restrict__ at,
                  const int* __restrict__ wpos, const float* __restrict__ g,
                  const float* __restrict__ bta, u16* __restrict__ xout) {
    __shared__ float red[256];
    const int r = blockIdx.x, tid = threadIdx.x;
    const float vf = (wpos[r] != -1) ? 1.f : 0.f;
    float t[3]; float s = 0.f, q = 0.f;
#pragma unroll
    for (int j = 0; j < 3; ++j) {
        int d = tid + j * 256;
        t[j] = wf[(size_t)r * DD + d] * vf + bf2f(at[(size_t)r * DD + d]);
        s += t[j];
        q = fmaf(t[j], t[j], q);
    }
    s = breduce_sum<256>(s, red);
    q = breduce_sum<256>(q, red);
    float mean = s * (1.f / DD);
    float var  = q * (1.f / DD) - mean * mean;
    float inv  = 1.f / sqrtf(var + 1e-5f);
#pragma unroll
    for (int j = 0; j < 3; ++j) {
        int d = tid + j * 256;
        xout[(size_t)r * DD + d] = f2bf(((t[j] - mean) * inv * g[d] + bta[d]) * vf);
    }
}

// ---------------------------------------------------------------------------
// h = layernorm(gelu_exact(g1); ln_g, ln_b) -> bf16      (row = 256)
// ---------------------------------------------------------------------------
__global__ __launch_bounds__(256)
void ln256_gelu_kernel(const float* __restrict__ g1, const float* __restrict__ lg,
                       const float* __restrict__ lb, u16* __restrict__ hout) {
    __shared__ float red[256];
    const int r = blockIdx.x, tid = threadIdx.x;
    float v  = g1[(size_t)r * HIDN + tid];
    float ge = 0.5f * v * (1.f + erff(v * 0.7071067811865475f));
    float s = breduce_sum<256>(ge, red);
    float q = breduce_sum<256>(ge * ge, red);
    float mean = s * (1.f / HIDN);
    float var  = q * (1.f / HIDN) - mean * mean;
    float inv  = 1.f / sqrtf(var + 1e-5f);
    hout[(size_t)r * HIDN + tid] = f2bf((ge - mean) * inv * lg[tid] + lb[tid]);
}

// ---------------------------------------------------------------------------
// L2-normalize rows of 768 IN PLACE + emit bf16 copy
// ---------------------------------------------------------------------------
__global__ __launch_bounds__(256)
void norm768_kernel(float* __restrict__ buf, u16* __restrict__ outb) {
    __shared__ float red[256];
    const int r = blockIdx.x, tid = threadIdx.x;
    float t[3]; float q = 0.f;
#pragma unroll
    for (int j = 0; j < 3; ++j) {
        t[j] = buf[(size_t)r * DD + tid + j * 256];
        q = fmaf(t[j], t[j], q);
    }
    q = breduce_sum<256>(q, red);
    float inv = 1.f / fmaxf(sqrtf(q), 1e-12f);
#pragma unroll
    for (int j = 0; j < 3; ++j) {
        float v = t[j] * inv;
        buf[(size_t)r * DD + tid + j * 256] = v;
        outb[(size_t)r * DD + tid + j * 256] = f2bf(v);
    }
}

// ---------------------------------------------------------------------------
// KL from precomputed logits. One WAVE per row, 4 rows/block.
// ---------------------------------------------------------------------------
__global__ __launch_bounds__(256)
void kl_lite_kernel(const float* __restrict__ logits, const int* __restrict__ wpos,
                    const float* __restrict__ pos_temp, float* __restrict__ klp) {
    const int row = blockIdx.x * 4 + (threadIdx.x >> 6);
    const int l = threadIdx.x & 63;
    const float invt = 1.f / fmaxf(pos_temp[0], 0.001f);
    const float* lrow = logits + (size_t)row * 256;

    float lg[4];
#pragma unroll
    for (int q = 0; q < 4; ++q) {
        int c = l + q * 64;
        lg[q] = (c < LL) ? lrow[c] * invt : -1e30f;
    }
    float m = fmaxf(fmaxf(lg[0], lg[1]), fmaxf(lg[2], lg[3]));
#pragma unroll
    for (int o = 32; o > 0; o >>= 1) m = fmaxf(m, __shfl_xor(m, o, 64));

    float S = 0.f;
#pragma unroll
    for (int q = 0; q < 4; ++q) S += expf(lg[q] - m);
#pragma unroll
    for (int o = 32; o > 0; o >>= 1) S += __shfl_xor(S, o, 64);
    const float logZ = m + logf(S);

    const int wr = wpos[row];
    const bool valid = (wr != -1);
    const int wp = wr < 0 ? 0 : (wr > LL - 1 ? LL - 1 : wr);

    float targ[4]; float tsum = 0.f;
#pragma unroll
    for (int q = 0; q < 4; ++q) {
        int c = l + q * 64;
        float dl = (float)c - (float)wp;
        targ[q] = (c < LL) ? expf(-dl * dl * 0.125f) : 0.f;
        tsum += targ[q];
    }
#pragma unroll
    for (int o = 32; o > 0; o >>= 1) tsum += __shfl_xor(tsum, o, 64);
    const float tden = 1.f / (tsum + 1e-12f);

    float c_ = 0.f;
#pragma unroll
    for (int q = 0; q < 4; ++q) {
        float tn = targ[q] * tden;
        if (valid && tn > 0.f) c_ += tn * (logf(tn) - (lg[q] - logZ));
    }
#pragma unroll
    for (int o = 32; o > 0; o >>= 1) c_ += __shfl_xor(c_, o, 64);
    if (l == 0) klp[row] = c_;
}

// ---------------------------------------------------------------------------
// rel head via MFMA Gram: one block per (b, j-half). 512 threads = 8 waves.
// ---------------------------------------------------------------------------
__global__ __launch_bounds__(512)
void rel_mfma_kernel(const u16* __restrict__ rnb, const int* __restrict__ wpos,
                     float* __restrict__ rel_part, float* __restrict__ vm2_part) {
    __shared__ __align__(16) u16 T[128 * 32];   // 8 KB
    __shared__ float red[512];
    const int blk = blockIdx.x;
    const int b = blk >> 1, jh = blk & 1;
    const int tid = threadIdx.x;
    const int l = tid & 63, wv = tid >> 6;
    const int la = l & 15, lg = l >> 4;

    const int f = wv * 1024 + l * 16;
    const int rA = f >> 6;
    const int cb = (f & 63) ^ (((rA >> 1) & 3) << 4);
    const int ce = cb >> 1;
    const u16* src = rnb + ((size_t)(b * NN + rA)) * DD + ce;
    u16* dst = T + wv * 512;

    const int ra = wv * 16 + la;
    const int aoff = ra * 32 + ((lg * 8) ^ (((ra >> 1) & 3) << 3));
    int boff[4];
#pragma unroll
    for (int nf = 0; nf < 4; ++nf) {
        int rb = jh * 64 + nf * 16 + la;
        boff[nf] = rb * 32 + ((lg * 8) ^ (((rb >> 1) & 3) << 3));
    }

    f32x4 acc[4] = {};
    for (int kt = 0; kt < 24; ++kt) {
        gload16(src + kt * 32, dst);
        __syncthreads();
        s16x8 a = *(const s16x8*)(T + aoff);
        s16x8 bf_[4];
#pragma unroll
        for (int nf = 0; nf < 4; ++nf) bf_[nf] = *(const s16x8*)(T + boff[nf]);
#pragma unroll
        for (int nf = 0; nf < 4; ++nf)
            acc[nf] = __builtin_amdgcn_mfma_f32_16x16x32_bf16(a, bf_[nf], acc[nf], 0, 0, 0);
        __syncthreads();
    }

    float wif[4], vi[4];
#pragma unroll
    for (int r = 0; r < 4; ++r) {
        int wi = wpos[b * NN + wv * 16 + lg * 4 + r];
        vi[r] = (wi != -1) ? 1.f : 0.f;
        wif[r] = (float)(wi < 0 ? 0 : (wi > LL - 1 ? LL - 1 : wi));
    }
    float csum = 0.f, msum = 0.f;
#pragma unroll
    for (int nf = 0; nf < 4; ++nf) {
        int wj = wpos[b * NN + jh * 64 + nf * 16 + la];
        float vj = (wj != -1) ? 1.f : 0.f;
        float wjf = (float)(wj < 0 ? 0 : (wj > LL - 1 ? LL - 1 : wj));
#pragma unroll
        for (int r = 0; r < 4; ++r) {
            float sim = (acc[nf][r] + 1.f) * 0.5f;
            float ts  = 1.f - fabsf(wif[r] - wjf) * (1.f / (float)LL);
            float m2  = vi[r] * vj;
            float df  = m2 * (sim - ts);
            csum += df * df;
            msum += m2;
        }
    }
    csum = breduce_sum<512>(csum, red);
    msum = breduce_sum<512>(msum, red);
    if (tid == 0) { rel_part[blk] = csum; vm2_part[blk] = msum; }
}

// ---------------------------------------------------------------------------
// scatter: emb[b, wp, :] = 0.8*pos_emb[wp] + 0.2*rope[b,n]   (valid only)
// ---------------------------------------------------------------------------
__global__ __launch_bounds__(256)
void scatter_kernel(const float* __restrict__ pe, const float* __restrict__ rope,
                    const int* __restrict__ wpos, float* __restrict__ emb) {
    const int r = blockIdx.x, tid = threadIdx.x;
    int wr = wpos[r];
    if (wr == -1) return;
    int wp = wr < 0 ? 0 : (wr > LL - 1 ? LL - 1 : wr);
    int b = r >> 7;
    for (int d = tid; d < DD; d += 256)
        emb[((size_t)b * LL + wp) * DD + d] =
            0.8f * pe[(size_t)wp * DD + d] + 0.2f * rope[(size_t)r * DD + d];
}

// ---------------------------------------------------------------------------
// Final deterministic fp64 reduction
// ---------------------------------------------------------------------------
__global__ __launch_bounds__(256)
void final_kernel(const float* __restrict__ klp, const float* __restrict__ relp,
                  const float* __restrict__ vmp, const int* __restrict__ wpos,
                  float* __restrict__ outs) {
    __shared__ double rd[256];
    const int tid = threadIdx.x;
    double kl = 0.0, rel = 0.0, vm = 0.0, nv = 0.0;
    for (int r = tid; r < MROWS; r += 256) {
        kl += (double)klp[r];
        nv += (wpos[r] != -1) ? 1.0 : 0.0;
    }
    if (tid < 256) {
        rel += (double)relp[tid];
        vm  += (double)vmp[tid];
    }
    kl  = breduce_sum_d256(kl, rd);
    rel = breduce_sum_d256(rel, rd);
    vm  = breduce_sum_d256(vm, rd);
    nv  = breduce_sum_d256(nv, rd);
    if (tid == 0) {
        float klf  = (float)(kl / (nv + 1e-12));
        float relf = (float)(rel / (vm + 1e-12));
        outs[0] = klf + 0.5f * relf;
        outs[1] = klf;
        outs[2] = relf;
    }
}

// ---------------------------------------------------------------------------
extern "C" void kernel_launch(void* const* d_in, const int* in_sizes, int n_in,
                              void* d_out, int out_size, void* d_ws, size_t ws_size,
                              hipStream_t stream) {
    (void)in_sizes; (void)n_in; (void)ws_size;

    const float* word_feat = (const float*)d_in[0];
    const float* text      = (const float*)d_in[1];
    const int*   wpos      = (const int*)d_in[2];
    const float* ctx_W     = (const float*)d_in[3];
    const float* ctx_b     = (const float*)d_in[4];
    const float* in_W      = (const float*)d_in[5];
    const float* in_b      = (const float*)d_in[6];
    const float* out_W     = (const float*)d_in[7];
    const float* out_b     = (const float*)d_in[8];
    const float* cn_g      = (const float*)d_in[9];
    const float* cn_b      = (const float*)d_in[10];
    const float* r1_W      = (const float*)d_in[11];
    const float* r1_b      = (const float*)d_in[12];
    const float* ln_g      = (const float*)d_in[13];
    const float* ln_b      = (const float*)d_in[14];
    const float* r2_W      = (const float*)d_in[15];
    const float* r2_b      = (const float*)d_in[16];
    const float* pos_emb   = (const float*)d_in[17];
    const float* pos_temp  = (const float*)d_in[18];

    char* W = (char*)d_ws;
    u16*   ctx_Wt = (u16*)(W);
    u16*   in_Wt  = ctx_Wt + (size_t)768 * 2304;
    u16*   out_Wt = in_Wt  + (size_t)2304 * 768;
    u16*   r1_Wt  = out_Wt + (size_t)768 * 768;
    u16*   r2_Wt  = r1_Wt  + (size_t)256 * 768;
    u16*   clipb  = r2_Wt + (size_t)768 * 256;          // [256][768] bf16
    int*   cposb  = (int*)(clipb + (size_t)256 * DD);
    float* klp    = (float*)(cposb + MROWS);
    float* relp   = klp + MROWS;
    float* vmp    = relp + 256;
    float* zbias  = vmp + 256;                           // 256 zero floats
    // --- big regions ---
    u16*   textb  = (u16*)(W + (size_t)12 * MB_);   // 46.5MB, dead after ctx GEMM
    u16*   xb     = textb;                           // reuse: x bf16
    u16*   hb     = (u16*)(W + (size_t)38 * MB_);   // h bf16
    u16*   ctxa   = (u16*)(W + (size_t)62 * MB_);   // ctx_anchor bf16
    u16*   aob    = ctxa;                            // reuse: ao bf16
    u16*   rnb    = ctxa;                            // reuse: rope_n bf16
    u16*   qb     = (u16*)(W + (size_t)88 * MB_);   // q bf16
    u16*   atoutb = qb;                              // reuse: attn_out bf16
    float* logits = (float*)qb;                      // reuse: logits fp32
    u16*   qpb    = (u16*)(W + (size_t)114 * MB_);  // qp (24MB) [114,138)
    u16*   kvb    = (u16*)(W + (size_t)138 * MB_);  // fused K|V (48MB) [138,186)
    float* g1     = (float*)(W + (size_t)114 * MB_); // reuse after attn (16MB)
    float* rope   = (float*)(W + (size_t)140 * MB_); // 50.3MB (after kv dead)

    hipMemsetAsync(d_out, 0, (size_t)out_size * sizeof(float), stream);
    hipMemsetAsync(zbias, 0, 256 * sizeof(float), stream);

    dim3 blk(256);

    transposeW_kernel<<<dim3(768/32, 2304/32), blk, 0, stream>>>(ctx_W, 2304, 768, ctx_Wt);
    transposeW_kernel<<<dim3(2304/32, 768/32), blk, 0, stream>>>(in_W, 768, 2304, in_Wt);
    transposeW_kernel<<<dim3(768/32, 768/32),  blk, 0, stream>>>(out_W, 768, 768, out_Wt);
    transposeW_kernel<<<dim3(256/32, 768/32),  blk, 0, stream>>>(r1_W, 768, 256, r1_Wt);
    transposeW_kernel<<<dim3(768/32, 256/32),  blk, 0, stream>>>(r2_W, 256, 768, r2_Wt);
    cvt_bf16_kernel<<<dim3(2048), blk, 0, stream>>>(text, textb, BB * LL * DD / 8);
    qmask_kernel<<<dim3(2048), blk, 0, stream>>>(word_feat, wpos, qb, MROWS * DD / 8);
    cpos_kernel<<<dim3(64), blk, 0, stream>>>(wpos, cposb, MROWS);
    clipb_kernel<<<dim3(256), blk, 0, stream>>>(pos_emb, clipb);

    dim3 g768(6, 128);
    dim3 g1536(12, 128);
    dim3 g256(2, 128);

    // 1. ctx_anchor
    gemm_bt<1, 1, 1><<<g768, blk, 0, stream>>>(
        nullptr, textb, cposb, ctx_Wt, ctx_b, ctxa, DD, 3 * DD, wpos);
    // 2. qp
    gemm_bt<0, 1, 0><<<g768, blk, 0, stream>>>(
        qb, nullptr, nullptr, in_Wt, in_b, qpb, DD, DD, nullptr);
    // 3. fused kp|vp: N=1536, one pass over ctx_anchor
    gemm_bt<0, 1, 0><<<g1536, blk, 0, stream>>>(
        ctxa, nullptr, nullptr, in_Wt + (size_t)768 * 768, in_b + DD, kvb, KVLD, DD, nullptr);
    // 4. MFMA attention -> ao (overwrites ctx_anchor region)
    attn_mfma_kernel<<<dim3(BB * HH), dim3(512), 0, stream>>>(qpb, kvb, aob);
    // 5. attn_out = ao @ out_W + out_b (overwrites q region)
    gemm_bt<0, 1, 0><<<g768, blk, 0, stream>>>(
        aob, nullptr, nullptr, out_Wt, out_b, atoutb, DD, DD, nullptr);
    // 6. x = LN(word_feat*vf + attn_out)*vf (overwrites text region)
    ln768_kernel<<<dim3(MROWS), blk, 0, stream>>>(word_feat, atoutb, wpos, cn_g, cn_b, xb);
    // 7. g1 = x @ r1_W + r1_b
    gemm_bt<0, 0, 0><<<g256, blk, 0, stream>>>(
        xb, nullptr, nullptr, r1_Wt, r1_b, g1, HIDN, DD, nullptr);
    // 8. h = LN(gelu(g1))
    ln256_gelu_kernel<<<dim3(MROWS), blk, 0, stream>>>(g1, ln_g, ln_b, hb);
    // 9. rope = h @ r2_W + r2_b
    gemm_bt<0, 0, 0><<<g768, blk, 0, stream>>>(
        hb, nullptr, nullptr, r2_Wt, r2_b, rope, DD, HIDN, nullptr);
    // 10. scatter emb (raw rope) BEFORE normalize
    scatter_kernel<<<dim3(MROWS), blk, 0, stream>>>(pos_emb, rope, wpos, (float*)d_out);
    // 11. rope -> rope_n in place + bf16 copy (overwrites ao region)
    norm768_kernel<<<dim3(MROWS), blk, 0, stream>>>(rope, rnb);
    // 12. logits = rope_n_bf16 @ clip_n^T
    gemm_bt<0, 0, 0><<<g256, blk, 0, stream>>>(
        rnb, nullptr, nullptr, clipb, zbias, logits, 256, DD, nullptr);
    // 13. KL from logits
    kl_lite_kernel<<<dim3(MROWS / 4), blk, 0, stream>>>(logits, wpos, pos_temp, klp);
    // 14. rel via MFMA Gram (uses rnb bf16)
    rel_mfma_kernel<<<dim3(BB * 2), dim3(512), 0, stream>>>(rnb, wpos, relp, vmp);
    // 15. scalars
    final_kernel<<<dim3(1), blk, 0, stream>>>(
        klp, relp, vmp, wpos, (float*)d_out + (size_t)BB * LL * DD);
}

// Round 7
// 454.798 us; speedup vs baseline: 8.1320x; 1.1085x over previous
//
#include <hip/hip_runtime.h>
#include <math.h>

// Problem constants
#define BB   128
#define NN   128
#define LL   248
#define DD   768
#define HH   8
#define HDh  96
#define HIDN 256
#define MROWS (BB*NN)   // 16384
#define MB_   (1u<<20)
#define KVLD 1536       // fused K|V row stride (elements)

typedef unsigned short u16;
typedef unsigned int   u32;
typedef __attribute__((ext_vector_type(8))) short s16x8;
typedef __attribute__((ext_vector_type(4))) float f32x4;

// ---------------------------------------------------------------------------
// helpers
// ---------------------------------------------------------------------------
__device__ __forceinline__ u16 f2bf(float x) {
    u32 u = __float_as_uint(x);
    u32 r = u + 0x7fffu + ((u >> 16) & 1u);
    return (u16)(r >> 16);
}
__device__ __forceinline__ float bf2f(u16 h) {
    return __uint_as_float(((u32)h) << 16);
}
__device__ __forceinline__ void gload16(const void* g, void* l) {
    __builtin_amdgcn_global_load_lds(
        (const __attribute__((address_space(1))) void*)g,
        (__attribute__((address_space(3))) void*)l, 16, 0, 0);
}

template<int NT>
__device__ __forceinline__ float breduce_sum(float v, float* red) {
    const int tid = threadIdx.x;
    red[tid] = v; __syncthreads();
#pragma unroll
    for (int o = NT / 2; o > 0; o >>= 1) {
        if (tid < o) red[tid] += red[tid + o];
        __syncthreads();
    }
    float r = red[0]; __syncthreads();
    return r;
}
__device__ __forceinline__ double breduce_sum_d256(double v, double* red) {
    const int tid = threadIdx.x;
    red[tid] = v; __syncthreads();
#pragma unroll
    for (int o = 128; o > 0; o >>= 1) {
        if (tid < o) red[tid] += red[tid + o];
        __syncthreads();
    }
    double r = red[0]; __syncthreads();
    return r;
}

// ---------------------------------------------------------------------------
// Prep: all 5 weight transposes in ONE dispatch
// tiles: ctx 1728 | in 1728 | out 576 | r1 192 | r2 192 = 4416 blocks
// ---------------------------------------------------------------------------
__global__ __launch_bounds__(256)
void transposeAll_kernel(const float* __restrict__ ctx_W, u16* __restrict__ ctx_Wt,
                         const float* __restrict__ in_W,  u16* __restrict__ in_Wt,
                         const float* __restrict__ out_W, u16* __restrict__ out_Wt,
                         const float* __restrict__ r1_W,  u16* __restrict__ r1_Wt,
                         const float* __restrict__ r2_W,  u16* __restrict__ r2_Wt) {
    __shared__ float t[32][33];
    int bid = blockIdx.x;
    const float* src; u16* dst; int R, C;
    if (bid < 1728)      { src = ctx_W; dst = ctx_Wt; R = 2304; C = 768;  }
    else if (bid < 3456) { src = in_W;  dst = in_Wt;  R = 768;  C = 2304; bid -= 1728; }
    else if (bid < 4032) { src = out_W; dst = out_Wt; R = 768;  C = 768;  bid -= 3456; }
    else if (bid < 4224) { src = r1_W;  dst = r1_Wt;  R = 768;  C = 256;  bid -= 4032; }
    else                 { src = r2_W;  dst = r2_Wt;  R = 256;  C = 768;  bid -= 4224; }
    const int ct = C >> 5;
    const int r0 = (bid / ct) * 32, c0 = (bid % ct) * 32;
    const int tx = threadIdx.x & 31, ty = threadIdx.x >> 5;
#pragma unroll
    for (int i = 0; i < 32; i += 8)
        t[ty + i][tx] = src[(size_t)(r0 + ty + i) * C + c0 + tx];
    __syncthreads();
#pragma unroll
    for (int i = 0; i < 32; i += 8)
        dst[(size_t)(c0 + ty + i) * R + r0 + tx] = f2bf(t[tx][ty + i]);
}

// ---------------------------------------------------------------------------
// Prep: text->bf16, q=bf16(wf*vf), cpos — one grid-stride dispatch
// ---------------------------------------------------------------------------
#define TEXT_N8 (BB*LL*DD/8)     // 3047424
#define Q_N8    (MROWS*(DD/8))   // 1572864
__global__ __launch_bounds__(256)
void prep_elem_kernel(const float* __restrict__ text, u16* __restrict__ textb,
                      const float* __restrict__ wf, u16* __restrict__ qb,
                      const int* __restrict__ wpos, int* __restrict__ cpos) {
    const int TOT = TEXT_N8 + Q_N8 + MROWS;
    int i = blockIdx.x * 256 + threadIdx.x;
    const int stride = gridDim.x * 256;
    for (; i < TOT; i += stride) {
        if (i < TEXT_N8) {
            const float4* s = (const float4*)(text + (size_t)i * 8);
            float4 a = s[0], b = s[1];
            uint4 o;
            o.x = (u32)f2bf(a.x) | ((u32)f2bf(a.y) << 16);
            o.y = (u32)f2bf(a.z) | ((u32)f2bf(a.w) << 16);
            o.z = (u32)f2bf(b.x) | ((u32)f2bf(b.y) << 16);
            o.w = (u32)f2bf(b.z) | ((u32)f2bf(b.w) << 16);
            *(uint4*)(textb + (size_t)i * 8) = o;
        } else if (i < TEXT_N8 + Q_N8) {
            int c = i - TEXT_N8;
            int row = c / 96;
            float vf = (wpos[row] != -1) ? 1.f : 0.f;
            const float4* s = (const float4*)(wf + (size_t)c * 8);
            float4 a = s[0], b = s[1];
            uint4 o;
            o.x = (u32)f2bf(a.x * vf) | ((u32)f2bf(a.y * vf) << 16);
            o.y = (u32)f2bf(a.z * vf) | ((u32)f2bf(a.w * vf) << 16);
            o.z = (u32)f2bf(b.x * vf) | ((u32)f2bf(b.y * vf) << 16);
            o.w = (u32)f2bf(b.z * vf) | ((u32)f2bf(b.w * vf) << 16);
            *(uint4*)(qb + (size_t)c * 8) = o;
        } else {
            int r = i - TEXT_N8 - Q_N8;
            int w = wpos[r];
            cpos[r] = w < 0 ? 0 : (w > LL - 1 ? LL - 1 : w);
        }
    }
}

// clip_n bf16, row-major [256][768], rows 248..255 zero
__global__ __launch_bounds__(256)
void clipb_kernel(const float* __restrict__ pe, u16* __restrict__ clipb) {
    __shared__ float red[256];
    const int l = blockIdx.x, tid = threadIdx.x;
    if (l >= LL) {
        for (int j = 0; j < 3; ++j)
            clipb[(size_t)l * DD + tid + j * 256] = 0;
        return;
    }
    float t[3]; float q = 0.f;
#pragma unroll
    for (int j = 0; j < 3; ++j) {
        t[j] = pe[(size_t)l * DD + tid + j * 256];
        q = fmaf(t[j], t[j], q);
    }
    q = breduce_sum<256>(q, red);
    float inv = 1.f / fmaxf(sqrtf(q), 1e-12f);
#pragma unroll
    for (int j = 0; j < 3; ++j)
        clipb[(size_t)l * DD + tid + j * 256] = f2bf(t[j] * inv);
}

// ---------------------------------------------------------------------------
// GEMM K-step body (stage -> barrier -> MFMA -> barrier)
// ---------------------------------------------------------------------------
__device__ __forceinline__ void gemm_step(
    const u16* ga0, const u16* ga1, const u16* gb0, const u16* gb1,
    u16* Ad0, u16* Ad1, u16* Bd0, u16* Bd1,
    const u16* Alds, const u16* Blds,
    const int* aoff, const int* boff, f32x4 acc[4][4]) {
    gload16(ga0, Ad0); gload16(ga1, Ad1);
    gload16(gb0, Bd0); gload16(gb1, Bd1);
    __syncthreads();
    s16x8 af[4], bf[4];
#pragma unroll
    for (int m = 0; m < 4; ++m) af[m] = *(const s16x8*)(Alds + aoff[m]);
#pragma unroll
    for (int n = 0; n < 4; ++n) bf[n] = *(const s16x8*)(Blds + boff[n]);
#pragma unroll
    for (int m = 0; m < 4; ++m)
#pragma unroll
        for (int n = 0; n < 4; ++n)
            acc[m][n] = __builtin_amdgcn_mfma_f32_16x16x32_bf16(
                af[m], bf[n], acc[m][n], 0, 0, 0);
    __syncthreads();
}

// ---------------------------------------------------------------------------
// bf16 MFMA GEMM (m97 structure) + XCD swizzle; GATHER path hoists the
// window-slot loop (clamps+bases once per 768-K segment).
// ---------------------------------------------------------------------------
template<int GATHER, int CBF16, int MASK>
__global__ __launch_bounds__(256)
void gemm_bt(const u16* __restrict__ A,
             const u16* __restrict__ TXT,
             const int* __restrict__ cpos,
             const u16* __restrict__ Bt,
             const float* __restrict__ bias,
             void* __restrict__ Cout, int ldc, int K,
             const int* __restrict__ wpos) {
    __shared__ __align__(16) u16 Alds[128 * 32];
    __shared__ __align__(16) u16 Blds[128 * 32];
    const int tid = threadIdx.x;
    const int l = tid & 63, wv = tid >> 6;

    // XCD swizzle
    const int gx  = gridDim.x;
    const int hw  = blockIdx.y * gx + blockIdx.x;
    const int nwg = gx * gridDim.y;
    const int cpx = nwg >> 3;
    const int lin = (hw & 7) * cpx + (hw >> 3);
    const int m0 = (lin / gx) * 128, n0 = (lin % gx) * 128;

    const int f0 = wv * 1024 + l * 16;
    const int f1 = f0 + 4096;
    const int rA0 = f0 >> 6, rA1 = f1 >> 6;
    const int cb0 = (f0 & 63) ^ (((rA0 >> 1) & 3) << 4);
    const int cb1 = (f1 & 63) ^ (((rA1 >> 1) & 3) << 4);
    const int c0e = cb0 >> 1, c1e = cb1 >> 1;

    u16* Ad0 = Alds + wv * 512;
    u16* Ad1 = Alds + 2048 + wv * 512;
    u16* Bd0 = Blds + wv * 512;
    u16* Bd1 = Blds + 2048 + wv * 512;

    const u16* pb0 = Bt + (size_t)(n0 + rA0) * K + c0e;
    const u16* pb1 = Bt + (size_t)(n0 + rA1) * K + c1e;

    const int wm = (wv >> 1) * 64, wn = (wv & 1) * 64;
    const int la = l & 15, lg = l >> 4;

    int aoff[4], boff[4];
#pragma unroll
    for (int m = 0; m < 4; ++m) {
        int ra = wm + m * 16 + la;
        aoff[m] = ra * 32 + ((lg * 8) ^ (((ra >> 1) & 3) << 3));
        int rb = wn + m * 16 + la;
        boff[m] = rb * 32 + ((lg * 8) ^ (((rb >> 1) & 3) << 3));
    }

    f32x4 acc[4][4] = {};

    if constexpr (GATHER) {
        const int g0 = m0 + rA0, g1 = m0 + rA1;
        const int gb0 = g0 >> 7, gb1 = g1 >> 7;
        const int gc0 = cpos[g0], gc1 = cpos[g1];
#pragma unroll 1
        for (int w = 0; w < 3; ++w) {
            int p0 = gc0 + w - 1; p0 = p0 < 0 ? 0 : (p0 > LL - 1 ? LL - 1 : p0);
            int p1 = gc1 + w - 1; p1 = p1 < 0 ? 0 : (p1 > LL - 1 ? LL - 1 : p1);
            const u16* a0 = TXT + ((size_t)(gb0 * LL + p0)) * DD + c0e;
            const u16* a1 = TXT + ((size_t)(gb1 * LL + p1)) * DD + c1e;
            const u16* b0 = pb0 + w * DD;
            const u16* b1 = pb1 + w * DD;
#pragma unroll 1
            for (int kt = 0; kt < 24; ++kt)
                gemm_step(a0 + kt * 32, a1 + kt * 32, b0 + kt * 32, b1 + kt * 32,
                          Ad0, Ad1, Bd0, Bd1, Alds, Blds, aoff, boff, acc);
        }
    } else {
        const u16* pa0 = A + (size_t)(m0 + rA0) * K + c0e;
        const u16* pa1 = A + (size_t)(m0 + rA1) * K + c1e;
        const int nk = K >> 5;
#pragma unroll 1
        for (int kt = 0; kt < nk; ++kt)
            gemm_step(pa0 + (kt << 5), pa1 + (kt << 5), pb0 + (kt << 5), pb1 + (kt << 5),
                      Ad0, Ad1, Bd0, Bd1, Alds, Blds, aoff, boff, acc);
    }

#pragma unroll
    for (int m = 0; m < 4; ++m) {
        const int rb = m0 + wm + m * 16 + lg * 4;
        float vf[4];
        if constexpr (MASK) {
#pragma unroll
            for (int r = 0; r < 4; ++r) vf[r] = (wpos[rb + r] != -1) ? 1.f : 0.f;
        }
#pragma unroll
        for (int n = 0; n < 4; ++n) {
            const int col = n0 + wn + n * 16 + la;
            const float bv = bias[col];
#pragma unroll
            for (int r = 0; r < 4; ++r) {
                float o = acc[m][n][r] + bv;
                if constexpr (MASK) o *= vf[r];
                if constexpr (CBF16)
                    ((u16*)Cout)[(size_t)(rb + r) * ldc + col] = f2bf(o);
                else
                    ((float*)Cout)[(size_t)(rb + r) * ldc + col] = o;
            }
        }
    }
}

// ---------------------------------------------------------------------------
// MFMA attention: one block per (b,h), 512 threads = 8 waves, 16 q-rows/wave.
// K/V from fused kv buffer (row stride KVLD; K cols [0,768), V cols [768,1536)).
// ---------------------------------------------------------------------------
__global__ __launch_bounds__(512)
void attn_mfma_kernel(const u16* __restrict__ qp, const u16* __restrict__ kvb,
                      u16* __restrict__ ao) {
    __shared__ __align__(16) u16 K_lds[128 * 96];    // 24 KB
    __shared__ __align__(16) u16 Vt_lds[96 * 128];   // 24 KB
    __shared__ __align__(16) u16 P_lds[128 * 128];   // 32 KB
    const int bh = blockIdx.x;
    const int b = bh >> 3, h = bh & 7;
    const int tid = threadIdx.x;
    const int l = tid & 63, wv = tid >> 6;
    const int la = l & 15, lg = l >> 4;
    const float scale = 0.10206207261596575f;  // 1/sqrt(96)

    const size_t qbase  = ((size_t)b * NN) * DD + h * HDh;
    const size_t kvbase = ((size_t)b * NN) * KVLD + h * HDh;

#pragma unroll
    for (int i = 0; i < 3; ++i) {
        int f = i * 8192 + wv * 1024 + l * 16;
        int row = f / 192;
        int inner = f - row * 192;
        gload16((const char*)(kvb + kvbase + (size_t)row * KVLD) + inner,
                (char*)K_lds + f);
    }

    uint4 vchunk[3]; int vkey[3], vd0[3];
#pragma unroll
    for (int i = 0; i < 3; ++i) {
        int c = tid + i * 512;
        int key = c / 12, dc = c - key * 12;
        vkey[i] = key; vd0[i] = dc * 8;
        vchunk[i] = *(const uint4*)(kvb + kvbase + (size_t)key * KVLD + DD + dc * 8);
    }

    const int q0 = wv * 16;
    s16x8 qf[3];
#pragma unroll
    for (int kt = 0; kt < 3; ++kt)
        qf[kt] = *(const s16x8*)(qp + qbase + (size_t)(q0 + la) * DD + kt * 32 + lg * 8);

#pragma unroll
    for (int i = 0; i < 3; ++i) {
        const u16* e = (const u16*)&vchunk[i];
#pragma unroll
        for (int j = 0; j < 8; ++j) {
            int d = vd0[i] + j;
            int byte = ((d * 128 + vkey[i]) * 2) ^ ((d & 7) << 4);
            *(u16*)((char*)Vt_lds + byte) = e[j];
        }
    }
    __syncthreads();

    f32x4 sacc[8] = {};
#pragma unroll
    for (int kt = 0; kt < 3; ++kt) {
#pragma unroll
        for (int nf = 0; nf < 8; ++nf) {
            s16x8 bfr = *(const s16x8*)(K_lds + (nf * 16 + la) * 96 + kt * 32 + lg * 8);
            sacc[nf] = __builtin_amdgcn_mfma_f32_16x16x32_bf16(qf[kt], bfr, sacc[nf], 0, 0, 0);
        }
    }

#pragma unroll
    for (int r = 0; r < 4; ++r) {
        float m = -1e30f;
#pragma unroll
        for (int nf = 0; nf < 8; ++nf) m = fmaxf(m, sacc[nf][r]);
#pragma unroll
        for (int o = 8; o > 0; o >>= 1) m = fmaxf(m, __shfl_xor(m, o, 64));
        m *= scale;
        float p[8]; float s = 0.f;
#pragma unroll
        for (int nf = 0; nf < 8; ++nf) { p[nf] = expf(sacc[nf][r] * scale - m); s += p[nf]; }
#pragma unroll
        for (int o = 8; o > 0; o >>= 1) s += __shfl_xor(s, o, 64);
        const float inv = 1.f / s;
        const int q = q0 + lg * 4 + r;
#pragma unroll
        for (int nf = 0; nf < 8; ++nf) {
            int byte = ((q * 128 + nf * 16 + la) * 2) ^ ((q & 7) << 4);
            *(u16*)((char*)P_lds + byte) = f2bf(p[nf] * inv);
        }
    }
    __syncthreads();

    f32x4 oacc[6] = {};
#pragma unroll
    for (int kk = 0; kk < 4; ++kk) {
        const int qrow = q0 + la;
        int abyte = ((qrow * 128 + kk * 32 + lg * 8) * 2) ^ ((qrow & 7) << 4);
        s16x8 af = *(const s16x8*)((char*)P_lds + abyte);
#pragma unroll
        for (int nf = 0; nf < 6; ++nf) {
            const int d = nf * 16 + la;
            int bbyte = ((d * 128 + kk * 32 + lg * 8) * 2) ^ ((d & 7) << 4);
            s16x8 bfr = *(const s16x8*)((char*)Vt_lds + bbyte);
            oacc[nf] = __builtin_amdgcn_mfma_f32_16x16x32_bf16(af, bfr, oacc[nf], 0, 0, 0);
        }
    }

#pragma unroll
    for (int nf = 0; nf < 6; ++nf) {
#pragma unroll
        for (int r = 0; r < 4; ++r) {
            const int q = q0 + lg * 4 + r;
            ao[qbase + (size_t)q * DD + nf * 16 + la] = f2bf(oacc[nf][r]);
        }
    }
}

// ---------------------------------------------------------------------------
// x = layernorm(q(bf16) + attn_out(bf16); cn_g, cn_b) * vf -> bf16
// q already has vf applied (qb).
// ---------------------------------------------------------------------------
__global__ __launch_bounds__(256)
void ln768_kernel(const u16* __restrict__ qb, const u16* __restrict__ at,
                  const int* __restrict__ wpos, const float* __restrict__ g,
                  const float* __restrict__ bta, u16* __restrict__ xout) {
    __shared__ float red[256];
    const int r = blockIdx.x, tid = threadIdx.x;
    const float vf = (wpos[r] != -1) ? 1.f : 0.f;
    float t[3]; float s = 0.f, q = 0.f;
#pragma unroll
    for (int j = 0; j < 3; ++j) {
        int d = tid + j * 256;
        t[j] = bf2f(qb[(size_t)r * DD + d]) + bf2f(at[(size_t)r * DD + d]);
        s += t[j];
        q = fmaf(t[j], t[j], q);
    }
    s = breduce_sum<256>(s, red);
    q = breduce_sum<256>(q, red);
    float mean = s * (1.f / DD);
    float var  = q * (1.f / DD) - mean * mean;
    float inv  = 1.f / sqrtf(var + 1e-5f);
#pragma unroll
    for (int j = 0; j < 3; ++j) {
        int d = tid + j * 256;
        xout[(size_t)r * DD + d] = f2bf(((t[j] - mean) * inv * g[d] + bta[d]) * vf);
    }
}

// ---------------------------------------------------------------------------
// h = layernorm(gelu_exact(g1); ln_g, ln_b) -> bf16      (row = 256)
// ---------------------------------------------------------------------------
__global__ __launch_bounds__(256)
void ln256_gelu_kernel(const float* __restrict__ g1, const float* __restrict__ lg,
                       const float* __restrict__ lb, u16* __restrict__ hout) {
    __shared__ float red[256];
    const int r = blockIdx.x, tid = threadIdx.x;
    float v  = g1[(size_t)r * HIDN + tid];
    float ge = 0.5f * v * (1.f + erff(v * 0.7071067811865475f));
    float s = breduce_sum<256>(ge, red);
    float q = breduce_sum<256>(ge * ge, red);
    float mean = s * (1.f / HIDN);
    float var  = q * (1.f / HIDN) - mean * mean;
    float inv  = 1.f / sqrtf(var + 1e-5f);
    hout[(size_t)r * HIDN + tid] = f2bf((ge - mean) * inv * lg[tid] + lb[tid]);
}

// ---------------------------------------------------------------------------
// Fused: L2-normalize rope (bf16 in) -> rnb bf16, and scatter emb for valid
// rows (emb = 0.8*pos_emb[wp] + 0.2*rope). fp32 rope_n never materialized.
// ---------------------------------------------------------------------------
__global__ __launch_bounds__(256)
void norm_scatter_kernel(const u16* __restrict__ ropeb, const float* __restrict__ pe,
                         const int* __restrict__ wpos, u16* __restrict__ rnb,
                         float* __restrict__ emb) {
    __shared__ float red[256];
    const int r = blockIdx.x, tid = threadIdx.x;
    float t[3]; float q = 0.f;
#pragma unroll
    for (int j = 0; j < 3; ++j) {
        t[j] = bf2f(ropeb[(size_t)r * DD + tid + j * 256]);
        q = fmaf(t[j], t[j], q);
    }
    q = breduce_sum<256>(q, red);
    float inv = 1.f / fmaxf(sqrtf(q), 1e-12f);
    const int wr = wpos[r];
    const bool valid = (wr != -1);
    const int wp = wr < 0 ? 0 : (wr > LL - 1 ? LL - 1 : wr);
    const int b = r >> 7;
#pragma unroll
    for (int j = 0; j < 3; ++j) {
        int d = tid + j * 256;
        rnb[(size_t)r * DD + d] = f2bf(t[j] * inv);
        if (valid)
            emb[((size_t)b * LL + wp) * DD + d] =
                0.8f * pe[(size_t)wp * DD + d] + 0.2f * t[j];
    }
}

// ---------------------------------------------------------------------------
// KL from precomputed logits. One WAVE per row, 4 rows/block.
// ---------------------------------------------------------------------------
__global__ __launch_bounds__(256)
void kl_lite_kernel(const float* __restrict__ logits, const int* __restrict__ wpos,
                    const float* __restrict__ pos_temp, float* __restrict__ klp) {
    const int row = blockIdx.x * 4 + (threadIdx.x >> 6);
    const int l = threadIdx.x & 63;
    const float invt = 1.f / fmaxf(pos_temp[0], 0.001f);
    const float* lrow = logits + (size_t)row * 256;

    float lg[4];
#pragma unroll
    for (int q = 0; q < 4; ++q) {
        int c = l + q * 64;
        lg[q] = (c < LL) ? lrow[c] * invt : -1e30f;
    }
    float m = fmaxf(fmaxf(lg[0], lg[1]), fmaxf(lg[2], lg[3]));
#pragma unroll
    for (int o = 32; o > 0; o >>= 1) m = fmaxf(m, __shfl_xor(m, o, 64));

    float S = 0.f;
#pragma unroll
    for (int q = 0; q < 4; ++q) S += expf(lg[q] - m);
#pragma unroll
    for (int o = 32; o > 0; o >>= 1) S += __shfl_xor(S, o, 64);
    const float logZ = m + logf(S);

    const int wr = wpos[row];
    const bool valid = (wr != -1);
    const int wp = wr < 0 ? 0 : (wr > LL - 1 ? LL - 1 : wr);

    float targ[4]; float tsum = 0.f;
#pragma unroll
    for (int q = 0; q < 4; ++q) {
        int c = l + q * 64;
        float dl = (float)c - (float)wp;
        targ[q] = (c < LL) ? expf(-dl * dl * 0.125f) : 0.f;
        tsum += targ[q];
    }
#pragma unroll
    for (int o = 32; o > 0; o >>= 1) tsum += __shfl_xor(tsum, o, 64);
    const float tden = 1.f / (tsum + 1e-12f);

    float c_ = 0.f;
#pragma unroll
    for (int q = 0; q < 4; ++q) {
        float tn = targ[q] * tden;
        if (valid && tn > 0.f) c_ += tn * (logf(tn) - (lg[q] - logZ));
    }
#pragma unroll
    for (int o = 32; o > 0; o >>= 1) c_ += __shfl_xor(c_, o, 64);
    if (l == 0) klp[row] = c_;
}

// ---------------------------------------------------------------------------
// rel head via MFMA Gram: one block per (b, j-half). 512 threads = 8 waves.
// ---------------------------------------------------------------------------
__global__ __launch_bounds__(512)
void rel_mfma_kernel(const u16* __restrict__ rnb, const int* __restrict__ wpos,
                     float* __restrict__ rel_part, float* __restrict__ vm2_part) {
    __shared__ __align__(16) u16 T[128 * 32];   // 8 KB
    __shared__ float red[512];
    const int blk = blockIdx.x;
    const int b = blk >> 1, jh = blk & 1;
    const int tid = threadIdx.x;
    const int l = tid & 63, wv = tid >> 6;
    const int la = l & 15, lg = l >> 4;

    const int f = wv * 1024 + l * 16;
    const int rA = f >> 6;
    const int cb = (f & 63) ^ (((rA >> 1) & 3) << 4);
    const int ce = cb >> 1;
    const u16* src = rnb + ((size_t)(b * NN + rA)) * DD + ce;
    u16* dst = T + wv * 512;

    const int ra = wv * 16 + la;
    const int aoff = ra * 32 + ((lg * 8) ^ (((ra >> 1) & 3) << 3));
    int boff[4];
#pragma unroll
    for (int nf = 0; nf < 4; ++nf) {
        int rb = jh * 64 + nf * 16 + la;
        boff[nf] = rb * 32 + ((lg * 8) ^ (((rb >> 1) & 3) << 3));
    }

    f32x4 acc[4] = {};
    for (int kt = 0; kt < 24; ++kt) {
        gload16(src + kt * 32, dst);
        __syncthreads();
        s16x8 a = *(const s16x8*)(T + aoff);
        s16x8 bf_[4];
#pragma unroll
        for (int nf = 0; nf < 4; ++nf) bf_[nf] = *(const s16x8*)(T + boff[nf]);
#pragma unroll
        for (int nf = 0; nf < 4; ++nf)
            acc[nf] = __builtin_amdgcn_mfma_f32_16x16x32_bf16(a, bf_[nf], acc[nf], 0, 0, 0);
        __syncthreads();
    }

    float wif[4], vi[4];
#pragma unroll
    for (int r = 0; r < 4; ++r) {
        int wi = wpos[b * NN + wv * 16 + lg * 4 + r];
        vi[r] = (wi != -1) ? 1.f : 0.f;
        wif[r] = (float)(wi < 0 ? 0 : (wi > LL - 1 ? LL - 1 : wi));
    }
    float csum = 0.f, msum = 0.f;
#pragma unroll
    for (int nf = 0; nf < 4; ++nf) {
        int wj = wpos[b * NN + jh * 64 + nf * 16 + la];
        float vj = (wj != -1) ? 1.f : 0.f;
        float wjf = (float)(wj < 0 ? 0 : (wj > LL - 1 ? LL - 1 : wj));
#pragma unroll
        for (int r = 0; r < 4; ++r) {
            float sim = (acc[nf][r] + 1.f) * 0.5f;
            float ts  = 1.f - fabsf(wif[r] - wjf) * (1.f / (float)LL);
            float m2  = vi[r] * vj;
            float df  = m2 * (sim - ts);
            csum += df * df;
            msum += m2;
        }
    }
    csum = breduce_sum<512>(csum, red);
    msum = breduce_sum<512>(msum, red);
    if (tid == 0) { rel_part[blk] = csum; vm2_part[blk] = msum; }
}

// ---------------------------------------------------------------------------
// Final deterministic fp64 reduction
// ---------------------------------------------------------------------------
__global__ __launch_bounds__(256)
void final_kernel(const float* __restrict__ klp, const float* __restrict__ relp,
                  const float* __restrict__ vmp, const int* __restrict__ wpos,
                  float* __restrict__ outs) {
    __shared__ double rd[256];
    const int tid = threadIdx.x;
    double kl = 0.0, rel = 0.0, vm = 0.0, nv = 0.0;
    for (int r = tid; r < MROWS; r += 256) {
        kl += (double)klp[r];
        nv += (wpos[r] != -1) ? 1.0 : 0.0;
    }
    if (tid < 256) {
        rel += (double)relp[tid];
        vm  += (double)vmp[tid];
    }
    kl  = breduce_sum_d256(kl, rd);
    rel = breduce_sum_d256(rel, rd);
    vm  = breduce_sum_d256(vm, rd);
    nv  = breduce_sum_d256(nv, rd);
    if (tid == 0) {
        float klf  = (float)(kl / (nv + 1e-12));
        float relf = (float)(rel / (vm + 1e-12));
        outs[0] = klf + 0.5f * relf;
        outs[1] = klf;
        outs[2] = relf;
    }
}

// ---------------------------------------------------------------------------
extern "C" void kernel_launch(void* const* d_in, const int* in_sizes, int n_in,
                              void* d_out, int out_size, void* d_ws, size_t ws_size,
                              hipStream_t stream) {
    (void)in_sizes; (void)n_in; (void)ws_size;

    const float* word_feat = (const float*)d_in[0];
    const float* text      = (const float*)d_in[1];
    const int*   wpos      = (const int*)d_in[2];
    const float* ctx_W     = (const float*)d_in[3];
    const float* ctx_b     = (const float*)d_in[4];
    const float* in_W      = (const float*)d_in[5];
    const float* in_b      = (const float*)d_in[6];
    const float* out_W     = (const float*)d_in[7];
    const float* out_b     = (const float*)d_in[8];
    const float* cn_g      = (const float*)d_in[9];
    const float* cn_b      = (const float*)d_in[10];
    const float* r1_W      = (const float*)d_in[11];
    const float* r1_b      = (const float*)d_in[12];
    const float* ln_g      = (const float*)d_in[13];
    const float* ln_b      = (const float*)d_in[14];
    const float* r2_W      = (const float*)d_in[15];
    const float* r2_b      = (const float*)d_in[16];
    const float* pos_emb   = (const float*)d_in[17];
    const float* pos_temp  = (const float*)d_in[18];

    char* W = (char*)d_ws;
    // --- weight/partials area [0, 12MB) ---
    u16*   ctx_Wt = (u16*)(W);
    u16*   in_Wt  = ctx_Wt + (size_t)768 * 2304;
    u16*   out_Wt = in_Wt  + (size_t)2304 * 768;
    u16*   r1_Wt  = out_Wt + (size_t)768 * 768;
    u16*   r2_Wt  = r1_Wt  + (size_t)256 * 768;
    u16*   clipb  = r2_Wt + (size_t)768 * 256;          // [256][768] bf16
    int*   cposb  = (int*)(clipb + (size_t)256 * DD);
    float* klp    = (float*)(cposb + MROWS);
    float* relp   = klp + MROWS;
    float* vmp    = relp + 256;
    float* zbias  = vmp + 256;                           // 256 zero floats
    // --- big regions (lifetimes audited) ---
    u16*   textb  = (u16*)(W + (size_t)12 * MB_);   // 12-58.5, dead after ctx GEMM
    u16*   atoutb = textb;                           // reuse 12-36 (step 5-6)
    float* logits = (float*)(W + (size_t)12 * MB_);  // reuse 12-28 (step 11-12)
    u16*   xb     = (u16*)(W + (size_t)36 * MB_);   // 36-60 (step 6-7)
    u16*   qb     = (u16*)(W + (size_t)60 * MB_);   // 60-84, live until ln768
    u16*   ctxa   = (u16*)(W + (size_t)86 * MB_);   // 86-110 (step 1-3)
    u16*   aob    = ctxa;                            // reuse (step 4-5)
    u16*   rnb    = ctxa;                            // reuse (step 10-13)
    u16*   qpb    = (u16*)(W + (size_t)112 * MB_);  // 112-136 (step 2-4)
    float* g1     = (float*)(W + (size_t)112 * MB_); // reuse 112-128 (step 7-8)
    u16*   hb     = (u16*)(W + (size_t)128 * MB_);  // 128-136.4 (step 8-9)
    u16*   kvb    = (u16*)(W + (size_t)138 * MB_);  // 138-186 (step 3-4)
    u16*   ropeb  = kvb;                             // reuse 138-162 (step 9-10)

    hipMemsetAsync(d_out, 0, (size_t)out_size * sizeof(float), stream);
    hipMemsetAsync(zbias, 0, 256 * sizeof(float), stream);

    dim3 blk(256);

    transposeAll_kernel<<<dim3(4416), blk, 0, stream>>>(
        ctx_W, ctx_Wt, in_W, in_Wt, out_W, out_Wt, r1_W, r1_Wt, r2_W, r2_Wt);
    prep_elem_kernel<<<dim3(2048), blk, 0, stream>>>(
        text, textb, word_feat, qb, wpos, cposb);
    clipb_kernel<<<dim3(256), blk, 0, stream>>>(pos_emb, clipb);

    dim3 g768(6, 128);
    dim3 g1536(12, 128);
    dim3 g256(2, 128);

    // 1. ctx_anchor = (gather(text) @ ctx_W + ctx_b) * vf
    gemm_bt<1, 1, 1><<<g768, blk, 0, stream>>>(
        nullptr, textb, cposb, ctx_Wt, ctx_b, ctxa, DD, 3 * DD, wpos);
    // 2. qp
    gemm_bt<0, 1, 0><<<g768, blk, 0, stream>>>(
        qb, nullptr, nullptr, in_Wt, in_b, qpb, DD, DD, nullptr);
    // 3. fused kp|vp
    gemm_bt<0, 1, 0><<<g1536, blk, 0, stream>>>(
        ctxa, nullptr, nullptr, in_Wt + (size_t)768 * 768, in_b + DD, kvb, KVLD, DD, nullptr);
    // 4. MFMA attention -> ao (overwrites ctxa)
    attn_mfma_kernel<<<dim3(BB * HH), dim3(512), 0, stream>>>(qpb, kvb, aob);
    // 5. attn_out = ao @ out_W + out_b (into old text region)
    gemm_bt<0, 1, 0><<<g768, blk, 0, stream>>>(
        aob, nullptr, nullptr, out_Wt, out_b, atoutb, DD, DD, nullptr);
    // 6. x = LN(q + attn_out)*vf  (reads qb bf16)
    ln768_kernel<<<dim3(MROWS), blk, 0, stream>>>(qb, atoutb, wpos, cn_g, cn_b, xb);
    // 7. g1 = x @ r1_W + r1_b
    gemm_bt<0, 0, 0><<<g256, blk, 0, stream>>>(
        xb, nullptr, nullptr, r1_Wt, r1_b, g1, HIDN, DD, nullptr);
    // 8. h = LN(gelu(g1))
    ln256_gelu_kernel<<<dim3(MROWS), blk, 0, stream>>>(g1, ln_g, ln_b, hb);
    // 9. rope = h @ r2_W + r2_b -> bf16 ropeb
    gemm_bt<0, 1, 0><<<g768, blk, 0, stream>>>(
        hb, nullptr, nullptr, r2_Wt, r2_b, ropeb, DD, HIDN, nullptr);
    // 10. fused normalize + scatter (rnb bf16 + emb)
    norm_scatter_kernel<<<dim3(MROWS), blk, 0, stream>>>(
        ropeb, pos_emb, wpos, rnb, (float*)d_out);
    // 11. logits = rope_n @ clip_n^T
    gemm_bt<0, 0, 0><<<g256, blk, 0, stream>>>(
        rnb, nullptr, nullptr, clipb, zbias, logits, 256, DD, nullptr);
    // 12. KL from logits
    kl_lite_kernel<<<dim3(MROWS / 4), blk, 0, stream>>>(logits, wpos, pos_temp, klp);
    // 13. rel via MFMA Gram
    rel_mfma_kernel<<<dim3(BB * 2), dim3(512), 0, stream>>>(rnb, wpos, relp, vmp);
    // 14. scalars
    final_kernel<<<dim3(1), blk, 0, stream>>>(
        klp, relp, vmp, wpos, (float*)d_out + (size_t)BB * LL * DD);
}

// Round 8
// 447.455 us; speedup vs baseline: 8.2654x; 1.0164x over previous
//
#include <hip/hip_runtime.h>
#include <math.h>

// Problem constants
#define BB   128
#define NN   128
#define LL   248
#define DD   768
#define HH   8
#define HDh  96
#define HIDN 256
#define MROWS (BB*NN)   // 16384
#define MB_   (1u<<20)
#define KVLD 1536       // fused K|V row stride (elements)

typedef unsigned short u16;
typedef unsigned int   u32;
typedef __attribute__((ext_vector_type(8))) short s16x8;
typedef __attribute__((ext_vector_type(4))) float f32x4;

// ---------------------------------------------------------------------------
// helpers
// ---------------------------------------------------------------------------
__device__ __forceinline__ u16 f2bf(float x) {
    u32 u = __float_as_uint(x);
    u32 r = u + 0x7fffu + ((u >> 16) & 1u);
    return (u16)(r >> 16);
}
__device__ __forceinline__ float bf2f(u16 h) {
    return __uint_as_float(((u32)h) << 16);
}
__device__ __forceinline__ void gload16(const void* g, void* l) {
    __builtin_amdgcn_global_load_lds(
        (const __attribute__((address_space(1))) void*)g,
        (__attribute__((address_space(3))) void*)l, 16, 0, 0);
}

template<int NT>
__device__ __forceinline__ float breduce_sum(float v, float* red) {
    const int tid = threadIdx.x;
    red[tid] = v; __syncthreads();
#pragma unroll
    for (int o = NT / 2; o > 0; o >>= 1) {
        if (tid < o) red[tid] += red[tid + o];
        __syncthreads();
    }
    float r = red[0]; __syncthreads();
    return r;
}
__device__ __forceinline__ double breduce_sum_d256(double v, double* red) {
    const int tid = threadIdx.x;
    red[tid] = v; __syncthreads();
#pragma unroll
    for (int o = 128; o > 0; o >>= 1) {
        if (tid < o) red[tid] += red[tid + o];
        __syncthreads();
    }
    double r = red[0]; __syncthreads();
    return r;
}

// ---------------------------------------------------------------------------
// ONE prep dispatch: 5 weight transposes (4416 blocks) | clip_n (256 blocks)
// | text/q/cpos elementwise (2048 virtual blocks, grid-stride)
// ---------------------------------------------------------------------------
#define TEXT_N8 (BB*LL*DD/8)     // 3047424
#define Q_N8    (MROWS*(DD/8))   // 1572864
__global__ __launch_bounds__(256)
void prep_all_kernel(const float* __restrict__ ctx_W, u16* __restrict__ ctx_Wt,
                     const float* __restrict__ in_W,  u16* __restrict__ in_Wt,
                     const float* __restrict__ out_W, u16* __restrict__ out_Wt,
                     const float* __restrict__ r1_W,  u16* __restrict__ r1_Wt,
                     const float* __restrict__ r2_W,  u16* __restrict__ r2_Wt,
                     const float* __restrict__ text,  u16* __restrict__ textb,
                     const float* __restrict__ wf,    u16* __restrict__ qb,
                     const int* __restrict__ wpos,    int* __restrict__ cpos,
                     const float* __restrict__ pe,    u16* __restrict__ clipb) {
    __shared__ float smem[32 * 33];
    int bid = blockIdx.x;
    const int tid = threadIdx.x;

    if (bid < 4416) {
        // ---- weight transposes ----
        const float* src; u16* dst; int C;
        if (bid < 1728)      { src = ctx_W; dst = ctx_Wt; C = 768;  }
        else if (bid < 3456) { src = in_W;  dst = in_Wt;  C = 2304; bid -= 1728; }
        else if (bid < 4032) { src = out_W; dst = out_Wt; C = 768;  bid -= 3456; }
        else if (bid < 4224) { src = r1_W;  dst = r1_Wt;  C = 256;  bid -= 4032; }
        else                 { src = r2_W;  dst = r2_Wt;  C = 768;  bid -= 4224; }
        const int R = (C == 768) ? ((dst == ctx_Wt) ? 2304 : ((dst == out_Wt) ? 768 : 256))
                                 : ((C == 2304) ? 768 : 768);
        const int ct = C >> 5;
        const int r0 = (bid / ct) * 32, c0 = (bid % ct) * 32;
        const int tx = tid & 31, ty = tid >> 5;
#pragma unroll
        for (int i = 0; i < 32; i += 8)
            smem[(ty + i) * 33 + tx] = src[(size_t)(r0 + ty + i) * C + c0 + tx];
        __syncthreads();
#pragma unroll
        for (int i = 0; i < 32; i += 8)
            dst[(size_t)(c0 + ty + i) * R + r0 + tx] = f2bf(smem[tx * 33 + ty + i]);
    } else if (bid < 4672) {
        // ---- clip_n bf16 [256][768], rows >= 248 zero ----
        const int l = bid - 4416;
        if (l >= LL) {
            for (int j = 0; j < 3; ++j) clipb[(size_t)l * DD + tid + j * 256] = 0;
            return;
        }
        float t[3]; float q = 0.f;
#pragma unroll
        for (int j = 0; j < 3; ++j) {
            t[j] = pe[(size_t)l * DD + tid + j * 256];
            q = fmaf(t[j], t[j], q);
        }
        q = breduce_sum<256>(q, smem);
        float inv = 1.f / fmaxf(sqrtf(q), 1e-12f);
#pragma unroll
        for (int j = 0; j < 3; ++j)
            clipb[(size_t)l * DD + tid + j * 256] = f2bf(t[j] * inv);
    } else {
        // ---- elementwise conversions ----
        const int TOT = TEXT_N8 + Q_N8 + MROWS;
        int i = (bid - 4672) * 256 + tid;
        const int stride = 2048 * 256;
        for (; i < TOT; i += stride) {
            if (i < TEXT_N8) {
                const float4* s = (const float4*)(text + (size_t)i * 8);
                float4 a = s[0], b = s[1];
                uint4 o;
                o.x = (u32)f2bf(a.x) | ((u32)f2bf(a.y) << 16);
                o.y = (u32)f2bf(a.z) | ((u32)f2bf(a.w) << 16);
                o.z = (u32)f2bf(b.x) | ((u32)f2bf(b.y) << 16);
                o.w = (u32)f2bf(b.z) | ((u32)f2bf(b.w) << 16);
                *(uint4*)(textb + (size_t)i * 8) = o;
            } else if (i < TEXT_N8 + Q_N8) {
                int c = i - TEXT_N8;
                int row = c / 96;
                float vf = (wpos[row] != -1) ? 1.f : 0.f;
                const float4* s = (const float4*)(wf + (size_t)c * 8);
                float4 a = s[0], b = s[1];
                uint4 o;
                o.x = (u32)f2bf(a.x * vf) | ((u32)f2bf(a.y * vf) << 16);
                o.y = (u32)f2bf(a.z * vf) | ((u32)f2bf(a.w * vf) << 16);
                o.z = (u32)f2bf(b.x * vf) | ((u32)f2bf(b.y * vf) << 16);
                o.w = (u32)f2bf(b.z * vf) | ((u32)f2bf(b.w * vf) << 16);
                *(uint4*)(qb + (size_t)c * 8) = o;
            } else {
                int r = i - TEXT_N8 - Q_N8;
                int w = wpos[r];
                cpos[r] = w < 0 ? 0 : (w > LL - 1 ? LL - 1 : w);
            }
        }
    }
}

// ---------------------------------------------------------------------------
// bf16 MFMA GEMM, BK=64: 128x128 tile, 256 threads (4 waves), 32 MFMA/K-step,
// HALF the barriers of BK=32. XCD-aware block swizzle (T1).
// Swizzle involution for 128B rows: write source chunk ce=((l&7)^(l>>3))<<3,
// read chunk (kk<<2)^lg^(la&7) — 2-way bank aliasing only (free).
// ---------------------------------------------------------------------------
template<int GATHER, int CBF16, int MASK>
__global__ __launch_bounds__(256)
void gemm_bt(const u16* __restrict__ A,
             const u16* __restrict__ TXT,
             const int* __restrict__ cpos,
             const u16* __restrict__ Bt,
             const float* __restrict__ bias,
             void* __restrict__ Cout, int ldc, int K,
             const int* __restrict__ wpos) {
    __shared__ __align__(16) u16 Alds[128 * 64];   // 16 KB
    __shared__ __align__(16) u16 Blds[128 * 64];   // 16 KB
    const int tid = threadIdx.x;
    const int l = tid & 63, wv = tid >> 6;

    // XCD swizzle
    const int gx  = gridDim.x;
    const int hw  = blockIdx.y * gx + blockIdx.x;
    const int nwg = gx * gridDim.y;
    const int cpx = nwg >> 3;
    const int lin = (hw & 7) * cpx + (hw >> 3);
    const int m0 = (lin / gx) * 128, n0 = (lin % gx) * 128;

    // staging geometry: issue i covers rows [i*32, i*32+32); this thread's row
    const int rw = wv * 8 + (l >> 3);              // 0..31 within issue
    const int ce = ((l & 7) ^ (l >> 3)) << 3;      // inverse-swizzled source col
    u16* Ad0 = Alds + wv * 512;                    // + i*2048 per issue
    u16* Bd0 = Blds + wv * 512;

    const int wm = (wv >> 1) * 64, wn = (wv & 1) * 64;
    const int la = l & 15, lg = l >> 4;

    // fragment element offsets (kk=0); XOR with 32 for kk=1
    int aoff[4], boff[4];
#pragma unroll
    for (int m = 0; m < 4; ++m) {
        int ra = wm + m * 16 + la;
        aoff[m] = ra * 64 + (((lg ^ (la & 7)) << 3));
        int rb = wn + m * 16 + la;
        boff[m] = rb * 64 + (((lg ^ (la & 7)) << 3));
    }

    // B source pointers (rows rw + i*32 of Bt tile)
    const u16* pb[4];
#pragma unroll
    for (int i = 0; i < 4; ++i)
        pb[i] = Bt + (size_t)(n0 + rw + i * 32) * K + ce;

    f32x4 acc[4][4] = {};

    auto do_step = [&](const u16* a0, const u16* a1, const u16* a2, const u16* a3,
                       const u16* b0, const u16* b1, const u16* b2, const u16* b3) {
        gload16(a0, Ad0);
        gload16(a1, Ad0 + 2048);
        gload16(a2, Ad0 + 4096);
        gload16(a3, Ad0 + 6144);
        gload16(b0, Bd0);
        gload16(b1, Bd0 + 2048);
        gload16(b2, Bd0 + 4096);
        gload16(b3, Bd0 + 6144);
        __syncthreads();
#pragma unroll
        for (int kk = 0; kk < 2; ++kk) {
            const int kx = kk << 5;
            s16x8 af[4], bf[4];
#pragma unroll
            for (int m = 0; m < 4; ++m) af[m] = *(const s16x8*)(Alds + (aoff[m] ^ kx));
#pragma unroll
            for (int n = 0; n < 4; ++n) bf[n] = *(const s16x8*)(Blds + (boff[n] ^ kx));
#pragma unroll
            for (int m = 0; m < 4; ++m)
#pragma unroll
                for (int n = 0; n < 4; ++n)
                    acc[m][n] = __builtin_amdgcn_mfma_f32_16x16x32_bf16(
                        af[m], bf[n], acc[m][n], 0, 0, 0);
        }
        __syncthreads();
    };

    if constexpr (GATHER) {
        int gb[4], gc[4];
#pragma unroll
        for (int i = 0; i < 4; ++i) {
            int g = m0 + rw + i * 32;
            gb[i] = g >> 7;
            gc[i] = cpos[g];
        }
#pragma unroll 1
        for (int w = 0; w < 3; ++w) {
            const u16* pa[4];
#pragma unroll
            for (int i = 0; i < 4; ++i) {
                int p = gc[i] + w - 1;
                p = p < 0 ? 0 : (p > LL - 1 ? LL - 1 : p);
                pa[i] = TXT + ((size_t)(gb[i] * LL + p)) * DD + ce;
            }
            const u16* b0 = pb[0] + w * DD; const u16* b1 = pb[1] + w * DD;
            const u16* b2 = pb[2] + w * DD; const u16* b3 = pb[3] + w * DD;
#pragma unroll 1
            for (int kt = 0; kt < 12; ++kt)
                do_step(pa[0] + kt * 64, pa[1] + kt * 64, pa[2] + kt * 64, pa[3] + kt * 64,
                        b0 + kt * 64, b1 + kt * 64, b2 + kt * 64, b3 + kt * 64);
        }
    } else {
        const u16* pa[4];
#pragma unroll
        for (int i = 0; i < 4; ++i)
            pa[i] = A + (size_t)(m0 + rw + i * 32) * K + ce;
        const int nk = K >> 6;
#pragma unroll 1
        for (int kt = 0; kt < nk; ++kt)
            do_step(pa[0] + kt * 64, pa[1] + kt * 64, pa[2] + kt * 64, pa[3] + kt * 64,
                    pb[0] + kt * 64, pb[1] + kt * 64, pb[2] + kt * 64, pb[3] + kt * 64);
    }

#pragma unroll
    for (int m = 0; m < 4; ++m) {
        const int rb = m0 + wm + m * 16 + lg * 4;
        float vf[4];
        if constexpr (MASK) {
#pragma unroll
            for (int r = 0; r < 4; ++r) vf[r] = (wpos[rb + r] != -1) ? 1.f : 0.f;
        }
#pragma unroll
        for (int n = 0; n < 4; ++n) {
            const int col = n0 + wn + n * 16 + la;
            const float bv = bias[col];
#pragma unroll
            for (int r = 0; r < 4; ++r) {
                float o = acc[m][n][r] + bv;
                if constexpr (MASK) o *= vf[r];
                if constexpr (CBF16)
                    ((u16*)Cout)[(size_t)(rb + r) * ldc + col] = f2bf(o);
                else
                    ((float*)Cout)[(size_t)(rb + r) * ldc + col] = o;
            }
        }
    }
}

// ---------------------------------------------------------------------------
// MFMA attention: one block per (b,h), 512 threads = 8 waves, 16 q-rows/wave.
// K/V from fused kv buffer (row stride KVLD; K cols [0,768), V cols [768,1536)).
// ---------------------------------------------------------------------------
__global__ __launch_bounds__(512)
void attn_mfma_kernel(const u16* __restrict__ qp, const u16* __restrict__ kvb,
                      u16* __restrict__ ao) {
    __shared__ __align__(16) u16 K_lds[128 * 96];    // 24 KB
    __shared__ __align__(16) u16 Vt_lds[96 * 128];   // 24 KB
    __shared__ __align__(16) u16 P_lds[128 * 128];   // 32 KB
    const int bh = blockIdx.x;
    const int b = bh >> 3, h = bh & 7;
    const int tid = threadIdx.x;
    const int l = tid & 63, wv = tid >> 6;
    const int la = l & 15, lg = l >> 4;
    const float scale = 0.10206207261596575f;  // 1/sqrt(96)

    const size_t qbase  = ((size_t)b * NN) * DD + h * HDh;
    const size_t kvbase = ((size_t)b * NN) * KVLD + h * HDh;

#pragma unroll
    for (int i = 0; i < 3; ++i) {
        int f = i * 8192 + wv * 1024 + l * 16;
        int row = f / 192;
        int inner = f - row * 192;
        gload16((const char*)(kvb + kvbase + (size_t)row * KVLD) + inner,
                (char*)K_lds + f);
    }

    uint4 vchunk[3]; int vkey[3], vd0[3];
#pragma unroll
    for (int i = 0; i < 3; ++i) {
        int c = tid + i * 512;
        int key = c / 12, dc = c - key * 12;
        vkey[i] = key; vd0[i] = dc * 8;
        vchunk[i] = *(const uint4*)(kvb + kvbase + (size_t)key * KVLD + DD + dc * 8);
    }

    const int q0 = wv * 16;
    s16x8 qf[3];
#pragma unroll
    for (int kt = 0; kt < 3; ++kt)
        qf[kt] = *(const s16x8*)(qp + qbase + (size_t)(q0 + la) * DD + kt * 32 + lg * 8);

#pragma unroll
    for (int i = 0; i < 3; ++i) {
        const u16* e = (const u16*)&vchunk[i];
#pragma unroll
        for (int j = 0; j < 8; ++j) {
            int d = vd0[i] + j;
            int byte = ((d * 128 + vkey[i]) * 2) ^ ((d & 7) << 4);
            *(u16*)((char*)Vt_lds + byte) = e[j];
        }
    }
    __syncthreads();

    f32x4 sacc[8] = {};
#pragma unroll
    for (int kt = 0; kt < 3; ++kt) {
#pragma unroll
        for (int nf = 0; nf < 8; ++nf) {
            s16x8 bfr = *(const s16x8*)(K_lds + (nf * 16 + la) * 96 + kt * 32 + lg * 8);
            sacc[nf] = __builtin_amdgcn_mfma_f32_16x16x32_bf16(qf[kt], bfr, sacc[nf], 0, 0, 0);
        }
    }

#pragma unroll
    for (int r = 0; r < 4; ++r) {
        float m = -1e30f;
#pragma unroll
        for (int nf = 0; nf < 8; ++nf) m = fmaxf(m, sacc[nf][r]);
#pragma unroll
        for (int o = 8; o > 0; o >>= 1) m = fmaxf(m, __shfl_xor(m, o, 64));
        m *= scale;
        float p[8]; float s = 0.f;
#pragma unroll
        for (int nf = 0; nf < 8; ++nf) { p[nf] = expf(sacc[nf][r] * scale - m); s += p[nf]; }
#pragma unroll
        for (int o = 8; o > 0; o >>= 1) s += __shfl_xor(s, o, 64);
        const float inv = 1.f / s;
        const int q = q0 + lg * 4 + r;
#pragma unroll
        for (int nf = 0; nf < 8; ++nf) {
            int byte = ((q * 128 + nf * 16 + la) * 2) ^ ((q & 7) << 4);
            *(u16*)((char*)P_lds + byte) = f2bf(p[nf] * inv);
        }
    }
    __syncthreads();

    f32x4 oacc[6] = {};
#pragma unroll
    for (int kk = 0; kk < 4; ++kk) {
        const int qrow = q0 + la;
        int abyte = ((qrow * 128 + kk * 32 + lg * 8) * 2) ^ ((qrow & 7) << 4);
        s16x8 af = *(const s16x8*)((char*)P_lds + abyte);
#pragma unroll
        for (int nf = 0; nf < 6; ++nf) {
            const int d = nf * 16 + la;
            int bbyte = ((d * 128 + kk * 32 + lg * 8) * 2) ^ ((d & 7) << 4);
            s16x8 bfr = *(const s16x8*)((char*)Vt_lds + bbyte);
            oacc[nf] = __builtin_amdgcn_mfma_f32_16x16x32_bf16(af, bfr, oacc[nf], 0, 0, 0);
        }
    }

#pragma unroll
    for (int nf = 0; nf < 6; ++nf) {
#pragma unroll
        for (int r = 0; r < 4; ++r) {
            const int q = q0 + lg * 4 + r;
            ao[qbase + (size_t)q * DD + nf * 16 + la] = f2bf(oacc[nf][r]);
        }
    }
}

// ---------------------------------------------------------------------------
// x = layernorm(q(bf16) + attn_out(bf16); cn_g, cn_b) * vf -> bf16
// ---------------------------------------------------------------------------
__global__ __launch_bounds__(256)
void ln768_kernel(const u16* __restrict__ qb, const u16* __restrict__ at,
                  const int* __restrict__ wpos, const float* __restrict__ g,
                  const float* __restrict__ bta, u16* __restrict__ xout) {
    __shared__ float red[256];
    const int r = blockIdx.x, tid = threadIdx.x;
    const float vf = (wpos[r] != -1) ? 1.f : 0.f;
    float t[3]; float s = 0.f, q = 0.f;
#pragma unroll
    for (int j = 0; j < 3; ++j) {
        int d = tid + j * 256;
        t[j] = bf2f(qb[(size_t)r * DD + d]) + bf2f(at[(size_t)r * DD + d]);
        s += t[j];
        q = fmaf(t[j], t[j], q);
    }
    s = breduce_sum<256>(s, red);
    q = breduce_sum<256>(q, red);
    float mean = s * (1.f / DD);
    float var  = q * (1.f / DD) - mean * mean;
    float inv  = 1.f / sqrtf(var + 1e-5f);
#pragma unroll
    for (int j = 0; j < 3; ++j) {
        int d = tid + j * 256;
        xout[(size_t)r * DD + d] = f2bf(((t[j] - mean) * inv * g[d] + bta[d]) * vf);
    }
}

// ---------------------------------------------------------------------------
// h = layernorm(gelu_exact(g1); ln_g, ln_b) -> bf16      (row = 256)
// ---------------------------------------------------------------------------
__global__ __launch_bounds__(256)
void ln256_gelu_kernel(const float* __restrict__ g1, const float* __restrict__ lg,
                       const float* __restrict__ lb, u16* __restrict__ hout) {
    __shared__ float red[256];
    const int r = blockIdx.x, tid = threadIdx.x;
    float v  = g1[(size_t)r * HIDN + tid];
    float ge = 0.5f * v * (1.f + erff(v * 0.7071067811865475f));
    float s = breduce_sum<256>(ge, red);
    float q = breduce_sum<256>(ge * ge, red);
    float mean = s * (1.f / HIDN);
    float var  = q * (1.f / HIDN) - mean * mean;
    float inv  = 1.f / sqrtf(var + 1e-5f);
    hout[(size_t)r * HIDN + tid] = f2bf((ge - mean) * inv * lg[tid] + lb[tid]);
}

// ---------------------------------------------------------------------------
// Fused: L2-normalize rope (bf16 in) -> rnb bf16, + scatter emb for valid rows
// ---------------------------------------------------------------------------
__global__ __launch_bounds__(256)
void norm_scatter_kernel(const u16* __restrict__ ropeb, const float* __restrict__ pe,
                         const int* __restrict__ wpos, u16* __restrict__ rnb,
                         float* __restrict__ emb) {
    __shared__ float red[256];
    const int r = blockIdx.x, tid = threadIdx.x;
    float t[3]; float q = 0.f;
#pragma unroll
    for (int j = 0; j < 3; ++j) {
        t[j] = bf2f(ropeb[(size_t)r * DD + tid + j * 256]);
        q = fmaf(t[j], t[j], q);
    }
    q = breduce_sum<256>(q, red);
    float inv = 1.f / fmaxf(sqrtf(q), 1e-12f);
    const int wr = wpos[r];
    const bool valid = (wr != -1);
    const int wp = wr < 0 ? 0 : (wr > LL - 1 ? LL - 1 : wr);
    const int b = r >> 7;
#pragma unroll
    for (int j = 0; j < 3; ++j) {
        int d = tid + j * 256;
        rnb[(size_t)r * DD + d] = f2bf(t[j] * inv);
        if (valid)
            emb[((size_t)b * LL + wp) * DD + d] =
                0.8f * pe[(size_t)wp * DD + d] + 0.2f * t[j];
    }
}

// ---------------------------------------------------------------------------
// KL from precomputed logits. One WAVE per row, 4 rows/block.
// ---------------------------------------------------------------------------
__global__ __launch_bounds__(256)
void kl_lite_kernel(const float* __restrict__ logits, const int* __restrict__ wpos,
                    const float* __restrict__ pos_temp, float* __restrict__ klp) {
    const int row = blockIdx.x * 4 + (threadIdx.x >> 6);
    const int l = threadIdx.x & 63;
    const float invt = 1.f / fmaxf(pos_temp[0], 0.001f);
    const float* lrow = logits + (size_t)row * 256;

    float lg[4];
#pragma unroll
    for (int q = 0; q < 4; ++q) {
        int c = l + q * 64;
        lg[q] = (c < LL) ? lrow[c] * invt : -1e30f;
    }
    float m = fmaxf(fmaxf(lg[0], lg[1]), fmaxf(lg[2], lg[3]));
#pragma unroll
    for (int o = 32; o > 0; o >>= 1) m = fmaxf(m, __shfl_xor(m, o, 64));

    float S = 0.f;
#pragma unroll
    for (int q = 0; q < 4; ++q) S += expf(lg[q] - m);
#pragma unroll
    for (int o = 32; o > 0; o >>= 1) S += __shfl_xor(S, o, 64);
    const float logZ = m + logf(S);

    const int wr = wpos[row];
    const bool valid = (wr != -1);
    const int wp = wr < 0 ? 0 : (wr > LL - 1 ? LL - 1 : wr);

    float targ[4]; float tsum = 0.f;
#pragma unroll
    for (int q = 0; q < 4; ++q) {
        int c = l + q * 64;
        float dl = (float)c - (float)wp;
        targ[q] = (c < LL) ? expf(-dl * dl * 0.125f) : 0.f;
        tsum += targ[q];
    }
#pragma unroll
    for (int o = 32; o > 0; o >>= 1) tsum += __shfl_xor(tsum, o, 64);
    const float tden = 1.f / (tsum + 1e-12f);

    float c_ = 0.f;
#pragma unroll
    for (int q = 0; q < 4; ++q) {
        float tn = targ[q] * tden;
        if (valid && tn > 0.f) c_ += tn * (logf(tn) - (lg[q] - logZ));
    }
#pragma unroll
    for (int o = 32; o > 0; o >>= 1) c_ += __shfl_xor(c_, o, 64);
    if (l == 0) klp[row] = c_;
}

// ---------------------------------------------------------------------------
// rel head via MFMA Gram: one block per (b, j-half). 512 threads = 8 waves.
// (BK=32 staging, unchanged from round 5 — proven correct)
// ---------------------------------------------------------------------------
__global__ __launch_bounds__(512)
void rel_mfma_kernel(const u16* __restrict__ rnb, const int* __restrict__ wpos,
                     float* __restrict__ rel_part, float* __restrict__ vm2_part) {
    __shared__ __align__(16) u16 T[128 * 32];   // 8 KB
    __shared__ float red[512];
    const int blk = blockIdx.x;
    const int b = blk >> 1, jh = blk & 1;
    const int tid = threadIdx.x;
    const int l = tid & 63, wv = tid >> 6;
    const int la = l & 15, lg = l >> 4;

    const int f = wv * 1024 + l * 16;
    const int rA = f >> 6;
    const int cb = (f & 63) ^ (((rA >> 1) & 3) << 4);
    const int ce = cb >> 1;
    const u16* src = rnb + ((size_t)(b * NN + rA)) * DD + ce;
    u16* dst = T + wv * 512;

    const int ra = wv * 16 + la;
    const int aoff = ra * 32 + ((lg * 8) ^ (((ra >> 1) & 3) << 3));
    int boff[4];
#pragma unroll
    for (int nf = 0; nf < 4; ++nf) {
        int rb = jh * 64 + nf * 16 + la;
        boff[nf] = rb * 32 + ((lg * 8) ^ (((rb >> 1) & 3) << 3));
    }

    f32x4 acc[4] = {};
    for (int kt = 0; kt < 24; ++kt) {
        gload16(src + kt * 32, dst);
        __syncthreads();
        s16x8 a = *(const s16x8*)(T + aoff);
        s16x8 bf_[4];
#pragma unroll
        for (int nf = 0; nf < 4; ++nf) bf_[nf] = *(const s16x8*)(T + boff[nf]);
#pragma unroll
        for (int nf = 0; nf < 4; ++nf)
            acc[nf] = __builtin_amdgcn_mfma_f32_16x16x32_bf16(a, bf_[nf], acc[nf], 0, 0, 0);
        __syncthreads();
    }

    float wif[4], vi[4];
#pragma unroll
    for (int r = 0; r < 4; ++r) {
        int wi = wpos[b * NN + wv * 16 + lg * 4 + r];
        vi[r] = (wi != -1) ? 1.f : 0.f;
        wif[r] = (float)(wi < 0 ? 0 : (wi > LL - 1 ? LL - 1 : wi));
    }
    float csum = 0.f, msum = 0.f;
#pragma unroll
    for (int nf = 0; nf < 4; ++nf) {
        int wj = wpos[b * NN + jh * 64 + nf * 16 + la];
        float vj = (wj != -1) ? 1.f : 0.f;
        float wjf = (float)(wj < 0 ? 0 : (wj > LL - 1 ? LL - 1 : wj));
#pragma unroll
        for (int r = 0; r < 4; ++r) {
            float sim = (acc[nf][r] + 1.f) * 0.5f;
            float ts  = 1.f - fabsf(wif[r] - wjf) * (1.f / (float)LL);
            float m2  = vi[r] * vj;
            float df  = m2 * (sim - ts);
            csum += df * df;
            msum += m2;
        }
    }
    csum = breduce_sum<512>(csum, red);
    msum = breduce_sum<512>(msum, red);
    if (tid == 0) { rel_part[blk] = csum; vm2_part[blk] = msum; }
}

// ---------------------------------------------------------------------------
// Final deterministic fp64 reduction
// ---------------------------------------------------------------------------
__global__ __launch_bounds__(256)
void final_kernel(const float* __restrict__ klp, const float* __restrict__ relp,
                  const float* __restrict__ vmp, const int* __restrict__ wpos,
                  float* __restrict__ outs) {
    __shared__ double rd[256];
    const int tid = threadIdx.x;
    double kl = 0.0, rel = 0.0, vm = 0.0, nv = 0.0;
    for (int r = tid; r < MROWS; r += 256) {
        kl += (double)klp[r];
        nv += (wpos[r] != -1) ? 1.0 : 0.0;
    }
    if (tid < 256) {
        rel += (double)relp[tid];
        vm  += (double)vmp[tid];
    }
    kl  = breduce_sum_d256(kl, rd);
    rel = breduce_sum_d256(rel, rd);
    vm  = breduce_sum_d256(vm, rd);
    nv  = breduce_sum_d256(nv, rd);
    if (tid == 0) {
        float klf  = (float)(kl / (nv + 1e-12));
        float relf = (float)(rel / (vm + 1e-12));
        outs[0] = klf + 0.5f * relf;
        outs[1] = klf;
        outs[2] = relf;
    }
}

// ---------------------------------------------------------------------------
extern "C" void kernel_launch(void* const* d_in, const int* in_sizes, int n_in,
                              void* d_out, int out_size, void* d_ws, size_t ws_size,
                              hipStream_t stream) {
    (void)in_sizes; (void)n_in; (void)ws_size;

    const float* word_feat = (const float*)d_in[0];
    const float* text      = (const float*)d_in[1];
    const int*   wpos      = (const int*)d_in[2];
    const float* ctx_W     = (const float*)d_in[3];
    const float* ctx_b     = (const float*)d_in[4];
    const float* in_W      = (const float*)d_in[5];
    const float* in_b      = (const float*)d_in[6];
    const float* out_W     = (const float*)d_in[7];
    const float* out_b     = (const float*)d_in[8];
    const float* cn_g      = (const float*)d_in[9];
    const float* cn_b      = (const float*)d_in[10];
    const float* r1_W      = (const float*)d_in[11];
    const float* r1_b      = (const float*)d_in[12];
    const float* ln_g      = (const float*)d_in[13];
    const float* ln_b      = (const float*)d_in[14];
    const float* r2_W      = (const float*)d_in[15];
    const float* r2_b      = (const float*)d_in[16];
    const float* pos_emb   = (const float*)d_in[17];
    const float* pos_temp  = (const float*)d_in[18];

    char* W = (char*)d_ws;
    // --- weight/partials area [0, 12MB) ---
    u16*   ctx_Wt = (u16*)(W);
    u16*   in_Wt  = ctx_Wt + (size_t)768 * 2304;
    u16*   out_Wt = in_Wt  + (size_t)2304 * 768;
    u16*   r1_Wt  = out_Wt + (size_t)768 * 768;
    u16*   r2_Wt  = r1_Wt  + (size_t)256 * 768;
    u16*   clipb  = r2_Wt + (size_t)768 * 256;          // [256][768] bf16
    int*   cposb  = (int*)(clipb + (size_t)256 * DD);
    float* klp    = (float*)(cposb + MROWS);
    float* relp   = klp + MROWS;
    float* vmp    = relp + 256;
    float* zbias  = vmp + 256;                           // 256 zero floats
    // --- big regions (lifetimes audited) ---
    u16*   textb  = (u16*)(W + (size_t)12 * MB_);   // 12-58.5, dead after ctx GEMM
    u16*   atoutb = textb;                           // reuse 12-36 (step 5-6)
    float* logits = (float*)(W + (size_t)12 * MB_);  // reuse 12-28 (step 11-12)
    u16*   xb     = (u16*)(W + (size_t)36 * MB_);   // 36-60 (step 6-7)
    u16*   qb     = (u16*)(W + (size_t)60 * MB_);   // 60-84, live until ln768
    u16*   ctxa   = (u16*)(W + (size_t)86 * MB_);   // 86-110 (step 1-3)
    u16*   aob    = ctxa;                            // reuse (step 4-5)
    u16*   rnb    = ctxa;                            // reuse (step 10-13)
    u16*   qpb    = (u16*)(W + (size_t)112 * MB_);  // 112-136 (step 2-4)
    float* g1     = (float*)(W + (size_t)112 * MB_); // reuse 112-128 (step 7-8)
    u16*   hb     = (u16*)(W + (size_t)128 * MB_);  // 128-136.4 (step 8-9)
    u16*   kvb    = (u16*)(W + (size_t)138 * MB_);  // 138-186 (step 3-4)
    u16*   ropeb  = kvb;                             // reuse 138-162 (step 9-10)

    hipMemsetAsync(d_out, 0, (size_t)out_size * sizeof(float), stream);
    hipMemsetAsync(zbias, 0, 256 * sizeof(float), stream);

    dim3 blk(256);

    // one prep dispatch: transposes + clip_n + elementwise conversions
    prep_all_kernel<<<dim3(4416 + 256 + 2048), blk, 0, stream>>>(
        ctx_W, ctx_Wt, in_W, in_Wt, out_W, out_Wt, r1_W, r1_Wt, r2_W, r2_Wt,
        text, textb, word_feat, qb, wpos, cposb, pos_emb, clipb);

    dim3 g768(6, 128);
    dim3 g1536(12, 128);
    dim3 g256(2, 128);

    // 1. ctx_anchor = (gather(text) @ ctx_W + ctx_b) * vf
    gemm_bt<1, 1, 1><<<g768, blk, 0, stream>>>(
        nullptr, textb, cposb, ctx_Wt, ctx_b, ctxa, DD, 3 * DD, wpos);
    // 2. qp
    gemm_bt<0, 1, 0><<<g768, blk, 0, stream>>>(
        qb, nullptr, nullptr, in_Wt, in_b, qpb, DD, DD, nullptr);
    // 3. fused kp|vp
    gemm_bt<0, 1, 0><<<g1536, blk, 0, stream>>>(
        ctxa, nullptr, nullptr, in_Wt + (size_t)768 * 768, in_b + DD, kvb, KVLD, DD, nullptr);
    // 4. MFMA attention -> ao (overwrites ctxa)
    attn_mfma_kernel<<<dim3(BB * HH), dim3(512), 0, stream>>>(qpb, kvb, aob);
    // 5. attn_out = ao @ out_W + out_b (into old text region)
    gemm_bt<0, 1, 0><<<g768, blk, 0, stream>>>(
        aob, nullptr, nullptr, out_Wt, out_b, atoutb, DD, DD, nullptr);
    // 6. x = LN(q + attn_out)*vf  (reads qb bf16)
    ln768_kernel<<<dim3(MROWS), blk, 0, stream>>>(qb, atoutb, wpos, cn_g, cn_b, xb);
    // 7. g1 = x @ r1_W + r1_b
    gemm_bt<0, 0, 0><<<g256, blk, 0, stream>>>(
        xb, nullptr, nullptr, r1_Wt, r1_b, g1, HIDN, DD, nullptr);
    // 8. h = LN(gelu(g1))
    ln256_gelu_kernel<<<dim3(MROWS), blk, 0, stream>>>(g1, ln_g, ln_b, hb);
    // 9. rope = h @ r2_W + r2_b -> bf16 ropeb
    gemm_bt<0, 1, 0><<<g768, blk, 0, stream>>>(
        hb, nullptr, nullptr, r2_Wt, r2_b, ropeb, DD, HIDN, nullptr);
    // 10. fused normalize + scatter (rnb bf16 + emb)
    norm_scatter_kernel<<<dim3(MROWS), blk, 0, stream>>>(
        ropeb, pos_emb, wpos, rnb, (float*)d_out);
    // 11. logits = rope_n @ clip_n^T
    gemm_bt<0, 0, 0><<<g256, blk, 0, stream>>>(
        rnb, nullptr, nullptr, clipb, zbias, logits, 256, DD, nullptr);
    // 12. KL from logits
    kl_lite_kernel<<<dim3(MROWS / 4), blk, 0, stream>>>(logits, wpos, pos_temp, klp);
    // 13. rel via MFMA Gram
    rel_mfma_kernel<<<dim3(BB * 2), dim3(512), 0, stream>>>(rnb, wpos, relp, vmp);
    // 14. scalars
    final_kernel<<<dim3(1), blk, 0, stream>>>(
        klp, relp, vmp, wpos, (float*)d_out + (size_t)BB * LL * DD);
}